// Round 1
// baseline (13832.573 us; speedup 1.0000x reference)
//
#include <hip/hip_runtime.h>
#include <hip/hip_bf16.h>
#include <math.h>

#define N_NODES 65536
#define N_EDGES 524288
#define CH 256

#define FMA4(A4, S, W4) \
  A4.x = fmaf((S), (W4).x, A4.x); A4.y = fmaf((S), (W4).y, A4.y); \
  A4.z = fmaf((S), (W4).z, A4.z); A4.w = fmaf((S), (W4).w, A4.w)

typedef __bf16 bf16x8 __attribute__((ext_vector_type(8)));
typedef float f32x4 __attribute__((ext_vector_type(4)));

__device__ inline bf16x8 pack_bf16_8(const float4 a, const float4 b) {
  union { __hip_bfloat162 h2[4]; bf16x8 v; } r;
  r.h2[0] = __float22bfloat162_rn(make_float2(a.x, a.y));
  r.h2[1] = __float22bfloat162_rn(make_float2(a.z, a.w));
  r.h2[2] = __float22bfloat162_rn(make_float2(b.x, b.y));
  r.h2[3] = __float22bfloat162_rn(make_float2(b.z, b.w));
  return r.v;
}

// ---------------------------------------------------------------------------
// Weight pre-convert: fp32 W -> bf16 k-panel layout P[(k>>3)*N + n][k&7].
// transposed=1 means logical B[k][n] = W[n*K+k] (for reference's @ W.T GEMMs).
// ---------------------------------------------------------------------------
__global__ __launch_bounds__(256) void wcvt_kernel(
    const float* __restrict__ W, unsigned short* __restrict__ P,
    int K, int Nn, int transposed)
{
  const int idx = blockIdx.x * 256 + threadIdx.x;
  const int k = idx / Nn;
  const int n = idx - k * Nn;
  const float v = transposed ? W[(size_t)n * K + k] : W[(size_t)k * Nn + n];
  unsigned int u = __float_as_uint(v);
  u = u + 0x7FFFu + ((u >> 16) & 1u);
  P[(((size_t)(k >> 3)) * Nn + n) * 8 + (k & 7)] = (unsigned short)(u >> 16);
}

// ---------------------------------------------------------------------------
// LDS-free bf16 MFMA GEMM: C[M,N] = A_f32[M,K] @ Bp + bias (+relu).
// ---------------------------------------------------------------------------
template <bool RELU>
__global__ __launch_bounds__(256, 3) void mgemm_kernel(
    const float* __restrict__ A, const unsigned short* __restrict__ Bp,
    const float* __restrict__ bias, float* __restrict__ Cmat,
    int M, int Nn, int K)
{
  const int tid = threadIdx.x;
  const int lane = tid & 63;
  const int w = tid >> 6;
  const int m_base = blockIdx.y * 128 + (w >> 1) * 64;
  const int n_base = blockIdx.x * 128 + (w & 1) * 64;
  const int lr = lane & 15;
  const int lq = lane >> 4;
  f32x4 acc[4][4];
#pragma unroll
  for (int i = 0; i < 4; ++i)
#pragma unroll
    for (int j = 0; j < 4; ++j) acc[i][j] = (f32x4){0.f, 0.f, 0.f, 0.f};

  for (int k0 = 0; k0 < K; k0 += 32) {
    const int ka = k0 + (lq << 3);
    bf16x8 af[4], bfv[4];
#pragma unroll
    for (int mt = 0; mt < 4; ++mt) {
      const float* ap = A + (size_t)(m_base + mt * 16 + lr) * K + ka;
      af[mt] = pack_bf16_8(*(const float4*)ap, *(const float4*)(ap + 4));
    }
#pragma unroll
    for (int nt = 0; nt < 4; ++nt) {
      const size_t off =
          (((size_t)(ka >> 3)) * Nn + (n_base + nt * 16 + lr)) << 3;
      union { uint4 u; bf16x8 b; } bu;
      bu.u = *(const uint4*)(Bp + off);
      bfv[nt] = bu.b;
    }
#pragma unroll
    for (int mt = 0; mt < 4; ++mt)
#pragma unroll
      for (int nt = 0; nt < 4; ++nt)
        acc[mt][nt] = __builtin_amdgcn_mfma_f32_16x16x32_bf16(
            af[mt], bfv[nt], acc[mt][nt], 0, 0, 0);
  }
#pragma unroll
  for (int nt = 0; nt < 4; ++nt) {
    const int col = n_base + nt * 16 + lr;
    const float bv = bias[col];
#pragma unroll
    for (int mt = 0; mt < 4; ++mt) {
      const int row0 = m_base + mt * 16 + (lq << 2);
#pragma unroll
      for (int r = 0; r < 4; ++r) {
        float v = acc[mt][nt][r] + bv;
        if (RELU) v = fmaxf(v, 0.f);
        Cmat[(size_t)(row0 + r) * Nn + col] = v;
      }
    }
  }
}

// ---------------------------------------------------------------------------
// fp32 tiled GEMM (kept for encoder K=771 and tiny classifier GEMMs).
// ---------------------------------------------------------------------------
template <bool BT, bool RELU>
__global__ __launch_bounds__(256, 4) void gemm_kernel(
    const float* __restrict__ A, const float* __restrict__ B,
    const float* __restrict__ bias, float* __restrict__ Cmat,
    int M, int Nn, int K)
{
  __shared__ float As[8][132];
  __shared__ float Bs[8][132];
  const int tid = threadIdx.x;
  const int bm = blockIdx.y * 128;
  const int bn = blockIdx.x * 128;
  const int tm = (tid >> 4) << 3;
  const int tn = (tid & 15) << 3;
  float acc[8][8];
#pragma unroll
  for (int i = 0; i < 8; ++i)
#pragma unroll
    for (int j = 0; j < 8; ++j) acc[i][j] = 0.f;

  const int nk = (K + 7) >> 3;
  const bool k4 = (K & 3) == 0;
  for (int kc = 0; kc < nk; ++kc) {
    const int k0 = kc << 3;
    {
      const int r = tid >> 1;
      const int kk = (tid & 1) << 2;
      const int gm = bm + r;
      float va[4] = {0.f, 0.f, 0.f, 0.f};
      if (gm < M) {
        const size_t base = (size_t)gm * K + k0 + kk;
        if (k4 && (k0 + kk + 4 <= K)) {
          const float4 v = *(const float4*)(A + base);
          va[0] = v.x; va[1] = v.y; va[2] = v.z; va[3] = v.w;
        } else {
#pragma unroll
          for (int j = 0; j < 4; ++j)
            if (k0 + kk + j < K) va[j] = A[base + j];
        }
      }
      As[kk + 0][r] = va[0]; As[kk + 1][r] = va[1];
      As[kk + 2][r] = va[2]; As[kk + 3][r] = va[3];
    }
    if (!BT) {
      const int r = tid >> 5;
      const int cb = (tid & 31) << 2;
      float4 v = make_float4(0.f, 0.f, 0.f, 0.f);
      if (k0 + r < K) v = *(const float4*)(B + (size_t)(k0 + r) * Nn + bn + cb);
      *(float4*)&Bs[r][cb] = v;
    } else {
      const int r = tid >> 1;
      const int kk = (tid & 1) << 2;
      float vb[4] = {0.f, 0.f, 0.f, 0.f};
      if (bn + r < Nn) {
        const size_t base = (size_t)(bn + r) * K + k0 + kk;
        if (k4 && (k0 + kk + 4 <= K)) {
          const float4 v = *(const float4*)(B + base);
          vb[0] = v.x; vb[1] = v.y; vb[2] = v.z; vb[3] = v.w;
        } else {
#pragma unroll
          for (int j = 0; j < 4; ++j)
            if (k0 + kk + j < K) vb[j] = B[base + j];
        }
      }
      Bs[kk + 0][r] = vb[0]; Bs[kk + 1][r] = vb[1];
      Bs[kk + 2][r] = vb[2]; Bs[kk + 3][r] = vb[3];
    }
    __syncthreads();
#pragma unroll
    for (int k = 0; k < 8; ++k) {
      const float4 a0 = *(const float4*)&As[k][tm];
      const float4 a1 = *(const float4*)&As[k][tm + 4];
      const float4 b0 = *(const float4*)&Bs[k][tn];
      const float4 b1 = *(const float4*)&Bs[k][tn + 4];
      const float av[8] = {a0.x, a0.y, a0.z, a0.w, a1.x, a1.y, a1.z, a1.w};
      const float bv[8] = {b0.x, b0.y, b0.z, b0.w, b1.x, b1.y, b1.z, b1.w};
#pragma unroll
      for (int i = 0; i < 8; ++i)
#pragma unroll
        for (int j = 0; j < 8; ++j)
          acc[i][j] = fmaf(av[i], bv[j], acc[i][j]);
    }
    __syncthreads();
  }
#pragma unroll
  for (int i = 0; i < 8; ++i) {
    const int gm = bm + tm + i;
    if (gm >= M) continue;
    float* crow = Cmat + (size_t)gm * Nn + bn + tn;
#pragma unroll
    for (int j = 0; j < 8; ++j) {
      const int gn = bn + tn + j;
      if (gn >= Nn) continue;
      float v = acc[i][j] + (bias ? bias[gn] : 0.f);
      if (RELU) v = fmaxf(v, 0.f);
      crow[j] = v;
    }
  }
}

// ---------------------------------------------------------------------------
// CSR build: histogram of dst -> exclusive scan -> scatter edge ids.
// ---------------------------------------------------------------------------
__global__ __launch_bounds__(256) void hist_kernel(
    const int* __restrict__ dst, int* __restrict__ deg)
{
  const int e = blockIdx.x * 256 + threadIdx.x;
  atomicAdd(&deg[dst[e]], 1);
}

__global__ __launch_bounds__(256) void scan_kernel(
    const int* __restrict__ deg, int* __restrict__ row_ptr,
    int* __restrict__ fill)
{
  __shared__ int part[256];
  const int t = threadIdx.x;
  const int base = t << 8;
  int s = 0;
  for (int j = 0; j < 256; ++j) s += deg[base + j];
  part[t] = s;
  __syncthreads();
  for (int off = 1; off < 256; off <<= 1) {
    int v = (t >= off) ? part[t - off] : 0;
    __syncthreads();
    part[t] += v;
    __syncthreads();
  }
  int run = (t == 0) ? 0 : part[t - 1];
  for (int j = 0; j < 256; ++j) {
    row_ptr[base + j] = run;
    fill[base + j] = run;
    run += deg[base + j];
  }
  if (t == 255) row_ptr[65536] = run;
}

__global__ __launch_bounds__(256) void scatter_kernel(
    const int* __restrict__ dst, int* __restrict__ fill,
    int* __restrict__ eid)
{
  const int e = blockIdx.x * 256 + threadIdx.x;
  const int pos = atomicAdd(&fill[dst[e]], 1);
  eid[pos] = e;
}

// ---------------------------------------------------------------------------
// CSR-ordered fused GINE kernel, MFMA edition.
// Block = 256 threads (4 waves), 16 dst nodes, edge chunks of 64.
// Per chunk:
//   1) edge encoder e = relu(edge_attr @ ee_w + ee_b) -> bf16 LDS tile
//      Es[64 edges][256 k], XOR-swizzled (k ^= (row&7)<<3) so A-fragment
//      ds_read_b128 at 512B row stride spreads over 8 bank groups.
//   2) ee = e @ elin_w via mfma_f32_16x16x32_bf16; B from pre-panelized
//      bf16 elin_w in global (L2-resident, same layout as mgemm).
//      Wave w owns cols [w*64, w*64+64), all 64 edges: 4x4 frags, K=256.
//   3) epilogue: msg = relu(acc + elin_b[col] + h[src][col]) from D-frags
//      (col = lane&15 -> 16-lane coalesced h segments, bank-conflict-free
//      LDS atomics into g_acc).
// ---------------------------------------------------------------------------
#define ES_IDX(r, k) (((r) << 8) + ((k) ^ (((r) & 7) << 3)))

__global__ __launch_bounds__(256, 3) void gine3_kernel(
    const float* __restrict__ edge_attr,
    const int* __restrict__ src_idx, const int* __restrict__ dst_idx,
    const int* __restrict__ row_ptr, const int* __restrict__ eid_sorted,
    const float* __restrict__ ee_w, const float* __restrict__ ee_b,
    const unsigned short* __restrict__ elin_p, const float* __restrict__ elin_b,
    const float* __restrict__ h, const float* __restrict__ eps, int layer,
    float* __restrict__ g1)
{
  __shared__ unsigned short Es[64 * 256];   // 32 KB bf16 e-tile (swizzled)
  __shared__ float g_acc[16][256];          // 16 KB dst accumulator
  __shared__ float ea_s[64][4];
  __shared__ int si_s[64];
  __shared__ int sl_s[64];

  const int tid = threadIdx.x;
  const int n0 = blockIdx.x << 4;
  const int lane = tid & 63;
  const int w = tid >> 6;
  const int lr = lane & 15;
  const int lq = lane >> 4;
  const int nb = w << 6;

#pragma unroll
  for (int i = 0; i < 4; ++i)
    ((float4*)g_acc)[(i << 8) + tid] = make_float4(0.f, 0.f, 0.f, 0.f);

  const int row_start = row_ptr[n0];
  const int row_end = row_ptr[n0 + 16];

  float bcol[4];
#pragma unroll
  for (int nt = 0; nt < 4; ++nt) bcol[nt] = elin_b[nb + nt * 16 + lr];

  for (int cs = row_start; cs < row_end; cs += 64) {
    __syncthreads();  // previous chunk's consumers done before overwrite
    if (tid < 64) {
      const int slot = cs + tid;
      float4 v = make_float4(0.f, 0.f, 0.f, 0.f);
      int s = 0, sl = -1;
      if (slot < row_end) {
        const int e = eid_sorted[slot];
        v = *(const float4*)(edge_attr + ((size_t)e << 2));
        s = src_idx[e];
        sl = dst_idx[e] - n0;
      }
      ea_s[tid][0] = v.x; ea_s[tid][1] = v.y;
      ea_s[tid][2] = v.z; ea_s[tid][3] = v.w;
      si_s[tid] = s; sl_s[tid] = sl;
    }
    __syncthreads();

    // ---- phase 1: edge encoder -> swizzled bf16 LDS tile ----
    {
      const int e = tid & 63;
      const int kb = (tid >> 6) << 6;
      const float a0 = ea_s[e][0], a1 = ea_s[e][1];
      const float a2 = ea_s[e][2], a3 = ea_s[e][3];
#pragma unroll
      for (int k8 = 0; k8 < 8; ++k8) {
        const int k = kb + (k8 << 3);
        float4 v0 = *(const float4*)(ee_b + k);
        float4 v1 = *(const float4*)(ee_b + k + 4);
        {
          const float4 wa = *(const float4*)(ee_w + k);
          const float4 wb = *(const float4*)(ee_w + k + 4);
          FMA4(v0, a0, wa); FMA4(v1, a0, wb);
        }
        {
          const float4 wa = *(const float4*)(ee_w + 256 + k);
          const float4 wb = *(const float4*)(ee_w + 256 + k + 4);
          FMA4(v0, a1, wa); FMA4(v1, a1, wb);
        }
        {
          const float4 wa = *(const float4*)(ee_w + 512 + k);
          const float4 wb = *(const float4*)(ee_w + 512 + k + 4);
          FMA4(v0, a2, wa); FMA4(v1, a2, wb);
        }
        {
          const float4 wa = *(const float4*)(ee_w + 768 + k);
          const float4 wb = *(const float4*)(ee_w + 768 + k + 4);
          FMA4(v0, a3, wa); FMA4(v1, a3, wb);
        }
        v0.x = fmaxf(v0.x, 0.f); v0.y = fmaxf(v0.y, 0.f);
        v0.z = fmaxf(v0.z, 0.f); v0.w = fmaxf(v0.w, 0.f);
        v1.x = fmaxf(v1.x, 0.f); v1.y = fmaxf(v1.y, 0.f);
        v1.z = fmaxf(v1.z, 0.f); v1.w = fmaxf(v1.w, 0.f);
        union { bf16x8 v; uint4 u; } pk;
        pk.v = pack_bf16_8(v0, v1);
        *(uint4*)&Es[ES_IDX(e, k)] = pk.u;
      }
    }
    __syncthreads();

    // ---- phase 2: ee = e @ elin_w via MFMA ----
    f32x4 acc[4][4];
#pragma unroll
    for (int i = 0; i < 4; ++i)
#pragma unroll
      for (int j = 0; j < 4; ++j) acc[i][j] = (f32x4){0.f, 0.f, 0.f, 0.f};

    for (int k0 = 0; k0 < 256; k0 += 32) {
      const int ka = k0 + (lq << 3);
      bf16x8 af[4], bfv[4];
#pragma unroll
      for (int mt = 0; mt < 4; ++mt) {
        union { uint4 u; bf16x8 v; } au;
        au.u = *(const uint4*)&Es[ES_IDX(mt * 16 + lr, ka)];
        af[mt] = au.v;
      }
#pragma unroll
      for (int nt = 0; nt < 4; ++nt) {
        const size_t off =
            (((size_t)(ka >> 3)) * 256 + (nb + nt * 16 + lr)) << 3;
        union { uint4 u; bf16x8 b; } bu;
        bu.u = *(const uint4*)(elin_p + off);
        bfv[nt] = bu.b;
      }
#pragma unroll
      for (int mt = 0; mt < 4; ++mt)
#pragma unroll
        for (int nt = 0; nt < 4; ++nt)
          acc[mt][nt] = __builtin_amdgcn_mfma_f32_16x16x32_bf16(
              af[mt], bfv[nt], acc[mt][nt], 0, 0, 0);
    }

    // ---- phase 3: msg = relu(ee + b + h[src]), scatter into g_acc ----
#pragma unroll
    for (int mt = 0; mt < 4; ++mt) {
#pragma unroll
      for (int r = 0; r < 4; ++r) {
        const int li = mt * 16 + (lq << 2) + r;
        const int sl = sl_s[li];
        if (sl < 0) continue;
        const int s = si_s[li];
        const float* hrow = h + (((size_t)s) << 8);
#pragma unroll
        for (int nt = 0; nt < 4; ++nt) {
          const int col = nb + nt * 16 + lr;
          const float v = acc[mt][nt][r] + bcol[nt] + hrow[col];
          atomicAdd(&g_acc[sl][col], fmaxf(v, 0.f));
        }
      }
    }
  }
  __syncthreads();

  const float f = 1.f + eps[layer];
  const int row = tid >> 4;
  const int c0 = (tid & 15) << 4;
  const size_t nbase = (((size_t)(n0 + row)) << 8) + c0;
#pragma unroll
  for (int j = 0; j < 4; ++j) {
    const float4 hv = *(const float4*)(h + nbase + (j << 2));
    const float4 av = *(const float4*)&g_acc[row][c0 + (j << 2)];
    float4 o;
    o.x = fmaf(f, hv.x, av.x);
    o.y = fmaf(f, hv.y, av.y);
    o.z = fmaf(f, hv.z, av.z);
    o.w = fmaf(f, hv.w, av.w);
    *(float4*)(g1 + nbase + (j << 2)) = o;
  }
}

// ---------------------------------------------------------------------------
// Streaming attention, one block per (graph, head).
// ---------------------------------------------------------------------------
__global__ __launch_bounds__(256, 2) void attn_kernel(
    const float* __restrict__ qkv, float* __restrict__ o)
{
  __shared__ float k_s[128][64];
  __shared__ float v_s[128][64];
  const int gh = blockIdx.x;
  const int g = gh >> 2;
  const int hh = gh & 3;
  const int p = threadIdx.x;
  const float scale = 0.125f;
  const float* qrow = qkv + ((size_t)(g * 256 + p)) * 768 + hh * 64;
  float4 q[16];
#pragma unroll
  for (int i = 0; i < 16; ++i) q[i] = *(const float4*)(qrow + (i << 2));
  float4 oa[16];
#pragma unroll
  for (int i = 0; i < 16; ++i) oa[i] = make_float4(0.f, 0.f, 0.f, 0.f);
  float l = 0.f;
  for (int kb = 0; kb < 256; kb += 128) {
    __syncthreads();
#pragma unroll
    for (int it = 0; it < 8; ++it) {
      const int idx = it * 256 + p;
      const int row = idx >> 4;
      const int c4 = (idx & 15) << 2;
      const float* base = qkv + ((size_t)(g * 256 + kb + row)) * 768 + hh * 64 + c4;
      *(float4*)&k_s[row][c4] = *(const float4*)(base + 256);
      *(float4*)&v_s[row][c4] = *(const float4*)(base + 512);
    }
    __syncthreads();
    for (int j = 0; j < 128; ++j) {
      const float* kr = k_s[j];
      float s = 0.f;
#pragma unroll
      for (int i = 0; i < 16; ++i) {
        const float4 kv = *(const float4*)(kr + (i << 2));
        s = fmaf(q[i].x, kv.x, s);
        s = fmaf(q[i].y, kv.y, s);
        s = fmaf(q[i].z, kv.z, s);
        s = fmaf(q[i].w, kv.w, s);
      }
      const float pe = __expf(s * scale);
      l += pe;
      const float* vr = v_s[j];
#pragma unroll
      for (int i = 0; i < 16; ++i) {
        const float4 vv = *(const float4*)(vr + (i << 2));
        FMA4(oa[i], pe, vv);
      }
    }
  }
  const float inv = 1.f / l;
  float* orow = o + ((size_t)(g * 256 + p)) * 256 + hh * 64;
#pragma unroll
  for (int i = 0; i < 16; ++i) {
    float4 t = oa[i];
    t.x *= inv; t.y *= inv; t.z *= inv; t.w *= inv;
    *(float4*)(orow + (i << 2)) = t;
  }
}

// ---------------------------------------------------------------------------
__global__ __launch_bounds__(256) void ln_kernel(
    const float* __restrict__ a, const float* __restrict__ res,
    const float* __restrict__ gam, const float* __restrict__ bet,
    float* __restrict__ out, int relu)
{
  __shared__ float2 red[256];
  const int t = threadIdx.x;
  const size_t base = (size_t)blockIdx.x * 256;
  float v = a[base + t];
  if (res) v += res[base + t];
  red[t] = make_float2(v, v * v);
  __syncthreads();
#pragma unroll
  for (int s = 128; s > 0; s >>= 1) {
    if (t < s) { red[t].x += red[t + s].x; red[t].y += red[t + s].y; }
    __syncthreads();
  }
  const float mu = red[0].x * (1.f / 256.f);
  const float var = red[0].y * (1.f / 256.f) - mu * mu;
  float r = (v - mu) * rsqrtf(var + 1e-5f) * gam[t] + bet[t];
  if (relu) r = fmaxf(r, 0.f);
  out[base + t] = r;
}

__global__ __launch_bounds__(256) void bn_stats_kernel(
    const float* __restrict__ y, float* __restrict__ stats)
{
  const int t = threadIdx.x;
  const size_t r0 = (size_t)blockIdx.x * 64;
  float s = 0.f, s2 = 0.f;
  for (int r = 0; r < 64; ++r) {
    const float v = y[(r0 + r) * 256 + t];
    s += v;
    s2 = fmaf(v, v, s2);
  }
  atomicAdd(&stats[t], s);
  atomicAdd(&stats[256 + t], s2);
}

__global__ __launch_bounds__(256) void bn_apply_kernel(
    float* __restrict__ y, const float* __restrict__ stats,
    const float* __restrict__ gam, const float* __restrict__ bet)
{
  const size_t i = ((size_t)blockIdx.x * 256 + threadIdx.x) << 2;
  const int c = (int)(i & 255);
  const float inv_n = 1.f / 65536.f;
  float4 v = *(float4*)(y + i);
  const float4 s4 = *(const float4*)(stats + c);
  const float4 q4 = *(const float4*)(stats + 256 + c);
  const float4 g4 = *(const float4*)(gam + c);
  const float4 b4 = *(const float4*)(bet + c);
  float mu, var, sc;
  mu = s4.x * inv_n; var = q4.x * inv_n - mu * mu; sc = g4.x * rsqrtf(var + 1e-5f);
  v.x = fmaxf((v.x - mu) * sc + b4.x, 0.f);
  mu = s4.y * inv_n; var = q4.y * inv_n - mu * mu; sc = g4.y * rsqrtf(var + 1e-5f);
  v.y = fmaxf((v.y - mu) * sc + b4.y, 0.f);
  mu = s4.z * inv_n; var = q4.z * inv_n - mu * mu; sc = g4.z * rsqrtf(var + 1e-5f);
  v.z = fmaxf((v.z - mu) * sc + b4.z, 0.f);
  mu = s4.w * inv_n; var = q4.w * inv_n - mu * mu; sc = g4.w * rsqrtf(var + 1e-5f);
  v.w = fmaxf((v.w - mu) * sc + b4.w, 0.f);
  *(float4*)(y + i) = v;
}

__global__ __launch_bounds__(256) void add_kernel(
    const float* __restrict__ a, const float* __restrict__ b,
    float* __restrict__ out)
{
  const size_t i = ((size_t)blockIdx.x * 256 + threadIdx.x) << 2;
  const float4 va = *(const float4*)(a + i);
  const float4 vb = *(const float4*)(b + i);
  float4 v;
  v.x = va.x + vb.x; v.y = va.y + vb.y; v.z = va.z + vb.z; v.w = va.w + vb.w;
  *(float4*)(out + i) = v;
}

__global__ __launch_bounds__(256) void pool_kernel(
    const float* __restrict__ h, const int* __restrict__ batch,
    float* __restrict__ sums, float* __restrict__ cnt)
{
  const int t = threadIdx.x;
  const int n0 = blockIdx.x * 256;
  float acc = 0.f, runc = 0.f;
  int cur = batch[n0];
  for (int r = 0; r < 256; ++r) {
    const int n = n0 + r;
    const int b = batch[n];
    if (b != cur) {
      atomicAdd(&sums[(size_t)cur * 256 + t], acc);
      if (t == 0) atomicAdd(&cnt[cur], runc);
      acc = 0.f; runc = 0.f; cur = b;
    }
    acc += h[(size_t)n * 256 + t];
    runc += 1.f;
  }
  atomicAdd(&sums[(size_t)cur * 256 + t], acc);
  if (t == 0) atomicAdd(&cnt[cur], runc);
}

__global__ __launch_bounds__(256) void gemb_kernel(
    const float* __restrict__ sums, const float* __restrict__ cnt,
    float* __restrict__ gemb)
{
  const int i = blockIdx.x * 256 + threadIdx.x;
  const int g = i >> 8;
  gemb[i] = sums[i] / fmaxf(cnt[g], 1.f);
}

__global__ __launch_bounds__(256) void head_kernel(
    const float* __restrict__ z2, const float* __restrict__ w3,
    const float* __restrict__ b3, float* __restrict__ out)
{
  __shared__ float w[128];
  const int t = threadIdx.x;
  if (t < 128) w[t] = w3[t];
  __syncthreads();
  float s = 0.f;
  const float* row = z2 + (size_t)t * 128;
#pragma unroll 4
  for (int d = 0; d < 128; ++d) s = fmaf(row[d], w[d], s);
  out[t] = s + b3[0];
}

// ---------------------------------------------------------------------------
extern "C" void kernel_launch(void* const* d_in, const int* in_sizes, int n_in,
                              void* d_out, int out_size, void* d_ws, size_t ws_size,
                              hipStream_t stream)
{
  const float* x          = (const float*)d_in[0];
  const int*   edge_index = (const int*)d_in[1];
  const int*   batch      = (const int*)d_in[2];
  const float* edge_attr  = (const float*)d_in[3];
  const float* ne_w   = (const float*)d_in[4];
  const float* ne_b   = (const float*)d_in[5];
  const float* ne_ln_g = (const float*)d_in[6];
  const float* ne_ln_b = (const float*)d_in[7];
  const float* ee_w   = (const float*)d_in[8];
  const float* ee_b   = (const float*)d_in[9];
  const float* eps    = (const float*)d_in[10];
  const float* elin_w = (const float*)d_in[11];
  const float* gin_w1 = (const float*)d_in[12];
  const float* gin_w2 = (const float*)d_in[13];
  const float* attn_in_w  = (const float*)d_in[14];
  const float* attn_out_w = (const float*)d_in[15];
  const float* mlp_w1 = (const float*)d_in[16];
  const float* mlp_w2 = (const float*)d_in[17];
  const float* elin_b = (const float*)d_in[18];
  const float* gin_b1 = (const float*)d_in[19];
  const float* gin_b2 = (const float*)d_in[20];
  const float* attn_in_b  = (const float*)d_in[21];
  const float* attn_out_b = (const float*)d_in[22];
  const float* mlp_b1 = (const float*)d_in[23];
  const float* mlp_b2 = (const float*)d_in[24];
  const float* gin_bn_g = (const float*)d_in[25];
  const float* ln1_g  = (const float*)d_in[26];
  const float* ln2_g  = (const float*)d_in[27];
  const float* ln3_g  = (const float*)d_in[28];
  const float* gin_bn_b = (const float*)d_in[29];
  const float* ln1_b  = (const float*)d_in[30];
  const float* ln2_b  = (const float*)d_in[31];
  const float* ln3_b  = (const float*)d_in[32];
  const float* cls_w1 = (const float*)d_in[33];
  const float* cls_b1 = (const float*)d_in[34];
  const float* cls_ln_g = (const float*)d_in[35];
  const float* cls_ln_b = (const float*)d_in[36];
  const float* cls_w2 = (const float*)d_in[37];
  const float* cls_b2 = (const float*)d_in[38];
  const float* cls_w3 = (const float*)d_in[39];
  const float* cls_b3 = (const float*)d_in[40];

  const int* src = edge_index;
  const int* dst = edge_index + N_EDGES;

  float* ws = (float*)d_ws;
  const size_t NC = (size_t)N_NODES * CH;       // 16,777,216
  float* h    = ws;
  float* bufA = ws + NC;
  float* bufB = ws + 2 * NC;
  float* bufC = ws + 3 * NC;
  float* bufQ = ws + 4 * NC;                    // qkv [N,768] -> m1 [N,512]
  float* stats = bufQ + (size_t)N_NODES * 768;  // 4*512
  int* ideg  = (int*)(stats + 2048);            // 65536
  int* ifill = ideg + 65536;                    // 65536
  int* irow  = ifill + 65536;                   // 65537 (padded to 65544)
  int* ieid  = irow + 65544;                    // 524288
  unsigned short* pan = (unsigned short*)(ieid + 524288);  // bf16 panels
  // post-loop scratch reuses bufA (dead after last layer):
  float* sums = bufA;
  float* cnt  = bufA + 65536;
  float* gemb = bufA + 65792;
  float* z1   = bufA + 131328;
  float* z2   = bufA + 196864;

  const dim3 blk(256);
  const size_t PL = 720896;  // panel elems per layer (now includes elin_w)

  // ---- CSR build + weight bf16 panelization (once) ----
  hipMemsetAsync(stats, 0, 2048 * sizeof(float), stream);
  hipMemsetAsync(ideg, 0, 65536 * sizeof(int), stream);
  hist_kernel<<<dim3(2048), blk, 0, stream>>>(dst, ideg);
  scan_kernel<<<dim3(1), blk, 0, stream>>>(ideg, irow, ifill);
  scatter_kernel<<<dim3(2048), blk, 0, stream>>>(dst, ifill, ieid);
  for (int l = 0; l < 4; ++l) {
    unsigned short* p = pan + l * PL;
    wcvt_kernel<<<dim3(256), blk, 0, stream>>>(gin_w1 + (size_t)l * 65536, p, 256, 256, 0);
    wcvt_kernel<<<dim3(256), blk, 0, stream>>>(gin_w2 + (size_t)l * 65536, p + 65536, 256, 256, 0);
    wcvt_kernel<<<dim3(768), blk, 0, stream>>>(attn_in_w + (size_t)l * 196608, p + 131072, 256, 768, 1);
    wcvt_kernel<<<dim3(256), blk, 0, stream>>>(attn_out_w + (size_t)l * 65536, p + 327680, 256, 256, 1);
    wcvt_kernel<<<dim3(512), blk, 0, stream>>>(mlp_w1 + (size_t)l * 131072, p + 393216, 256, 512, 0);
    wcvt_kernel<<<dim3(512), blk, 0, stream>>>(mlp_w2 + (size_t)l * 131072, p + 524288, 512, 256, 0);
    wcvt_kernel<<<dim3(256), blk, 0, stream>>>(elin_w + (size_t)l * 65536, p + 655360, 256, 256, 0);
  }

  // ---- encoders (K=771: stays fp32) ----
  gemm_kernel<false, false><<<dim3(2, 512), blk, 0, stream>>>(
      x, ne_w, ne_b, bufB, N_NODES, 256, 771);
  ln_kernel<<<dim3(N_NODES), blk, 0, stream>>>(bufB, nullptr, ne_ln_g, ne_ln_b, h, 1);

  for (int l = 0; l < 4; ++l) {
    unsigned short* p = pan + l * PL;
    // ---- GINEConv ----
    gine3_kernel<<<dim3(4096), blk, 0, stream>>>(
        edge_attr, src, dst, irow, ieid, ee_w, ee_b,
        p + 655360, elin_b + l * 256, h, eps, l, bufA);
    mgemm_kernel<false><<<dim3(2, 512), blk, 0, stream>>>(
        bufA, p, gin_b1 + l * 256, bufB, N_NODES, 256, 256);
    bn_stats_kernel<<<dim3(1024), blk, 0, stream>>>(bufB, stats + l * 512);
    bn_apply_kernel<<<dim3(16384), blk, 0, stream>>>(
        bufB, stats + l * 512, gin_bn_g + l * 256, gin_bn_b + l * 256);
    mgemm_kernel<false><<<dim3(2, 512), blk, 0, stream>>>(
        bufB, p + 65536, gin_b2 + l * 256, bufC, N_NODES, 256, 256);
    ln_kernel<<<dim3(N_NODES), blk, 0, stream>>>(
        bufC, h, ln1_g + l * 256, ln1_b + l * 256, bufC, 0);
    // ---- attention ----
    mgemm_kernel<false><<<dim3(6, 512), blk, 0, stream>>>(
        h, p + 131072, attn_in_b + l * 768, bufQ, N_NODES, 768, 256);
    attn_kernel<<<dim3(1024), blk, 0, stream>>>(bufQ, bufA);
    mgemm_kernel<false><<<dim3(2, 512), blk, 0, stream>>>(
        bufA, p + 327680, attn_out_b + l * 256, bufB, N_NODES, 256, 256);
    ln_kernel<<<dim3(N_NODES), blk, 0, stream>>>(
        bufB, h, ln2_g + l * 256, ln2_b + l * 256, bufB, 0);
    // ---- FFN ----
    add_kernel<<<dim3(16384), blk, 0, stream>>>(bufC, bufB, bufB);
    mgemm_kernel<true><<<dim3(4, 512), blk, 0, stream>>>(
        bufB, p + 393216, mlp_b1 + l * 512, bufQ, N_NODES, 512, 256);
    mgemm_kernel<false><<<dim3(2, 512), blk, 0, stream>>>(
        bufQ, p + 524288, mlp_b2 + l * 256, bufC, N_NODES, 256, 512);
    ln_kernel<<<dim3(N_NODES), blk, 0, stream>>>(
        bufC, bufB, ln3_g + l * 256, ln3_b + l * 256, h, 0);
  }

  // ---- pooling + classifier ----
  hipMemsetAsync(sums, 0, 65792 * sizeof(float), stream);
  pool_kernel<<<dim3(256), blk, 0, stream>>>(h, batch, sums, cnt);
  gemb_kernel<<<dim3(256), blk, 0, stream>>>(sums, cnt, gemb);
  gemm_kernel<false, false><<<dim3(2, 2), blk, 0, stream>>>(
      gemb, cls_w1, cls_b1, z1, 256, 256, 256);
  ln_kernel<<<dim3(256), blk, 0, stream>>>(z1, nullptr, cls_ln_g, cls_ln_b, z1, 1);
  gemm_kernel<false, true><<<dim3(1, 2), blk, 0, stream>>>(
      z1, cls_w2, cls_b2, z2, 256, 128, 256);
  head_kernel<<<dim3(1), blk, 0, stream>>>(z2, cls_w3, cls_b3, (float*)d_out);
}

// Round 2
// 10516.837 us; speedup vs baseline: 1.3153x; 1.3153x over previous
//
#include <hip/hip_runtime.h>
#include <hip/hip_bf16.h>
#include <math.h>

#define N_NODES 65536
#define N_EDGES 524288
#define CH 256

#define FMA4(A4, S, W4) \
  A4.x = fmaf((S), (W4).x, A4.x); A4.y = fmaf((S), (W4).y, A4.y); \
  A4.z = fmaf((S), (W4).z, A4.z); A4.w = fmaf((S), (W4).w, A4.w)

typedef __bf16 bf16x8 __attribute__((ext_vector_type(8)));
typedef float f32x4 __attribute__((ext_vector_type(4)));

__device__ inline bf16x8 pack_bf16_8(const float4 a, const float4 b) {
  union { __hip_bfloat162 h2[4]; bf16x8 v; } r;
  r.h2[0] = __float22bfloat162_rn(make_float2(a.x, a.y));
  r.h2[1] = __float22bfloat162_rn(make_float2(a.z, a.w));
  r.h2[2] = __float22bfloat162_rn(make_float2(b.x, b.y));
  r.h2[3] = __float22bfloat162_rn(make_float2(b.z, b.w));
  return r.v;
}

// ---------------------------------------------------------------------------
// Weight pre-convert: fp32 W -> bf16 k-panel layout P[(k>>3)*N + n][k&7].
// transposed=1 means logical B[k][n] = W[n*K+k] (for reference's @ W.T GEMMs).
// ---------------------------------------------------------------------------
__global__ __launch_bounds__(256) void wcvt_kernel(
    const float* __restrict__ W, unsigned short* __restrict__ P,
    int K, int Nn, int transposed)
{
  const int idx = blockIdx.x * 256 + threadIdx.x;
  const int k = idx / Nn;
  const int n = idx - k * Nn;
  const float v = transposed ? W[(size_t)n * K + k] : W[(size_t)k * Nn + n];
  unsigned int u = __float_as_uint(v);
  u = u + 0x7FFFu + ((u >> 16) & 1u);
  P[(((size_t)(k >> 3)) * Nn + n) * 8 + (k & 7)] = (unsigned short)(u >> 16);
}

// ---------------------------------------------------------------------------
// LDS-free bf16 MFMA GEMM: C[M,N] = A_f32[M,K] @ Bp + bias (+relu).
// ---------------------------------------------------------------------------
template <bool RELU>
__global__ __launch_bounds__(256, 3) void mgemm_kernel(
    const float* __restrict__ A, const unsigned short* __restrict__ Bp,
    const float* __restrict__ bias, float* __restrict__ Cmat,
    int M, int Nn, int K)
{
  const int tid = threadIdx.x;
  const int lane = tid & 63;
  const int w = tid >> 6;
  const int m_base = blockIdx.y * 128 + (w >> 1) * 64;
  const int n_base = blockIdx.x * 128 + (w & 1) * 64;
  const int lr = lane & 15;
  const int lq = lane >> 4;
  f32x4 acc[4][4];
#pragma unroll
  for (int i = 0; i < 4; ++i)
#pragma unroll
    for (int j = 0; j < 4; ++j) acc[i][j] = (f32x4){0.f, 0.f, 0.f, 0.f};

  for (int k0 = 0; k0 < K; k0 += 32) {
    const int ka = k0 + (lq << 3);
    bf16x8 af[4], bfv[4];
#pragma unroll
    for (int mt = 0; mt < 4; ++mt) {
      const float* ap = A + (size_t)(m_base + mt * 16 + lr) * K + ka;
      af[mt] = pack_bf16_8(*(const float4*)ap, *(const float4*)(ap + 4));
    }
#pragma unroll
    for (int nt = 0; nt < 4; ++nt) {
      const size_t off =
          (((size_t)(ka >> 3)) * Nn + (n_base + nt * 16 + lr)) << 3;
      union { uint4 u; bf16x8 b; } bu;
      bu.u = *(const uint4*)(Bp + off);
      bfv[nt] = bu.b;
    }
#pragma unroll
    for (int mt = 0; mt < 4; ++mt)
#pragma unroll
      for (int nt = 0; nt < 4; ++nt)
        acc[mt][nt] = __builtin_amdgcn_mfma_f32_16x16x32_bf16(
            af[mt], bfv[nt], acc[mt][nt], 0, 0, 0);
  }
#pragma unroll
  for (int nt = 0; nt < 4; ++nt) {
    const int col = n_base + nt * 16 + lr;
    const float bv = bias[col];
#pragma unroll
    for (int mt = 0; mt < 4; ++mt) {
      const int row0 = m_base + mt * 16 + (lq << 2);
#pragma unroll
      for (int r = 0; r < 4; ++r) {
        float v = acc[mt][nt][r] + bv;
        if (RELU) v = fmaxf(v, 0.f);
        Cmat[(size_t)(row0 + r) * Nn + col] = v;
      }
    }
  }
}

// ---------------------------------------------------------------------------
// eegemm: EE[slot,:] = relu(edge_attr[eid[slot]] @ ee_w + ee_b) @ elin_w
//         + elin_b, for sorted slots [row_ptr[node_base], row_ptr[node_base
//         +16384)). mgemm structure; A-fragments computed on the fly from
//         the 4 edge_attr scalars + encoder weights cached in LDS (5 KB).
//         EE rows indexed relative to slot_base (pass-local buffer).
// ---------------------------------------------------------------------------
__global__ __launch_bounds__(256, 3) void eegemm_kernel(
    const float* __restrict__ edge_attr,
    const int* __restrict__ eid_sorted,
    const int* __restrict__ row_ptr, int node_base,
    const float* __restrict__ ee_w, const float* __restrict__ ee_b,
    const unsigned short* __restrict__ elin_p, const float* __restrict__ elin_b,
    float* __restrict__ EE)
{
  __shared__ float wenc[4][256];
  __shared__ float benc[256];
  const int tid = threadIdx.x;
  const int slot_base = row_ptr[node_base];
  const int slot_end = row_ptr[node_base + 16384];
  const int m_rel = blockIdx.y * 128;
  if (slot_base + m_rel >= slot_end) return;  // block-uniform exit

  ((float4*)wenc)[tid] = ((const float4*)ee_w)[tid];
  if (tid < 64) ((float4*)benc)[tid] = ((const float4*)ee_b)[tid];
  __syncthreads();

  const int lane = tid & 63;
  const int w = tid >> 6;
  const int m_base = m_rel + (w >> 1) * 64;
  const int n_base = blockIdx.x * 128 + (w & 1) * 64;
  const int lr = lane & 15;
  const int lq = lane >> 4;

  // per-lane edge_attr for its 4 A-fragment rows (rows m_base+mt*16+lr)
  float4 ea_r[4];
#pragma unroll
  for (int mt = 0; mt < 4; ++mt) {
    const int abs_slot = slot_base + m_base + mt * 16 + lr;
    if (abs_slot < slot_end) {
      const int e = eid_sorted[abs_slot];
      ea_r[mt] = *(const float4*)(edge_attr + ((size_t)e << 2));
    } else {
      ea_r[mt] = make_float4(0.f, 0.f, 0.f, 0.f);
    }
  }

  f32x4 acc[4][4];
#pragma unroll
  for (int i = 0; i < 4; ++i)
#pragma unroll
    for (int j = 0; j < 4; ++j) acc[i][j] = (f32x4){0.f, 0.f, 0.f, 0.f};

  for (int k0 = 0; k0 < 256; k0 += 32) {
    const int ka = k0 + (lq << 3);
    const float4 b0 = *(const float4*)&benc[ka];
    const float4 b1 = *(const float4*)&benc[ka + 4];
    float4 w0[4], w1[4];
#pragma unroll
    for (int j = 0; j < 4; ++j) {
      w0[j] = *(const float4*)&wenc[j][ka];
      w1[j] = *(const float4*)&wenc[j][ka + 4];
    }
    bf16x8 af[4], bfv[4];
#pragma unroll
    for (int mt = 0; mt < 4; ++mt) {
      float4 v0 = b0, v1 = b1;
      FMA4(v0, ea_r[mt].x, w0[0]); FMA4(v1, ea_r[mt].x, w1[0]);
      FMA4(v0, ea_r[mt].y, w0[1]); FMA4(v1, ea_r[mt].y, w1[1]);
      FMA4(v0, ea_r[mt].z, w0[2]); FMA4(v1, ea_r[mt].z, w1[2]);
      FMA4(v0, ea_r[mt].w, w0[3]); FMA4(v1, ea_r[mt].w, w1[3]);
      v0.x = fmaxf(v0.x, 0.f); v0.y = fmaxf(v0.y, 0.f);
      v0.z = fmaxf(v0.z, 0.f); v0.w = fmaxf(v0.w, 0.f);
      v1.x = fmaxf(v1.x, 0.f); v1.y = fmaxf(v1.y, 0.f);
      v1.z = fmaxf(v1.z, 0.f); v1.w = fmaxf(v1.w, 0.f);
      af[mt] = pack_bf16_8(v0, v1);
    }
#pragma unroll
    for (int nt = 0; nt < 4; ++nt) {
      const size_t off =
          (((size_t)(ka >> 3)) * 256 + (n_base + nt * 16 + lr)) << 3;
      union { uint4 u; bf16x8 b; } bu;
      bu.u = *(const uint4*)(elin_p + off);
      bfv[nt] = bu.b;
    }
#pragma unroll
    for (int mt = 0; mt < 4; ++mt)
#pragma unroll
      for (int nt = 0; nt < 4; ++nt)
        acc[mt][nt] = __builtin_amdgcn_mfma_f32_16x16x32_bf16(
            af[mt], bfv[nt], acc[mt][nt], 0, 0, 0);
  }

#pragma unroll
  for (int nt = 0; nt < 4; ++nt) {
    const int col = n_base + nt * 16 + lr;
    const float bv = elin_b[col];
#pragma unroll
    for (int mt = 0; mt < 4; ++mt) {
      const int row0 = m_base + mt * 16 + (lq << 2);
#pragma unroll
      for (int r = 0; r < 4; ++r) {
        if (slot_base + row0 + r < slot_end)
          EE[(size_t)(row0 + r) * 256 + col] = acc[mt][nt][r] + bv;
      }
    }
  }
}

// ---------------------------------------------------------------------------
// gscat: CSR-ordered scatter-aggregate (gine2 skeleton minus all GEMM work).
// msg = relu(h[src] + EE[slot]); sum at dst; g1 = (1+eps)*h + aggr.
// ---------------------------------------------------------------------------
__global__ __launch_bounds__(256, 4) void gscat_kernel(
    const float* __restrict__ EE,
    const int* __restrict__ src_idx, const int* __restrict__ dst_idx,
    const int* __restrict__ row_ptr, const int* __restrict__ eid_sorted,
    int node_base,
    const float* __restrict__ h, const float* __restrict__ eps, int layer,
    float* __restrict__ g1)
{
  __shared__ float g_acc[16][256];
  __shared__ int si_s[64];
  __shared__ int sl_s[64];
  const int tid = threadIdx.x;
  const int n0 = node_base + (blockIdx.x << 4);
#pragma unroll
  for (int i = 0; i < 4; ++i)
    ((float4*)g_acc)[(i << 8) + tid] = make_float4(0.f, 0.f, 0.f, 0.f);
  const int slot_base = row_ptr[node_base];
  const int row_start = row_ptr[n0];
  const int row_end = row_ptr[n0 + 16];
  const int eg = (tid >> 6) << 4;
  const int cg = (tid & 63) << 2;

  for (int cs = row_start; cs < row_end; cs += 64) {
    __syncthreads();
    if (tid < 64) {
      const int slot = cs + tid;
      int s = 0, sl = -1;
      if (slot < row_end) {
        const int e = eid_sorted[slot];
        s = src_idx[e];
        sl = dst_idx[e] - n0;
      }
      si_s[tid] = s; sl_s[tid] = sl;
    }
    __syncthreads();
    const int er0 = cs - slot_base;
#pragma unroll
    for (int i = 0; i < 16; ++i) {
      const int li = eg + i;
      const int sl = sl_s[li];
      if (sl < 0) continue;
      const float4 e4 = *(const float4*)(EE + (size_t)(er0 + li) * 256 + cg);
      const float4 h4 = *(const float4*)(h + (((size_t)si_s[li]) << 8) + cg);
      atomicAdd(&g_acc[sl][cg + 0], fmaxf(h4.x + e4.x, 0.f));
      atomicAdd(&g_acc[sl][cg + 1], fmaxf(h4.y + e4.y, 0.f));
      atomicAdd(&g_acc[sl][cg + 2], fmaxf(h4.z + e4.z, 0.f));
      atomicAdd(&g_acc[sl][cg + 3], fmaxf(h4.w + e4.w, 0.f));
    }
  }
  __syncthreads();

  const float f = 1.f + eps[layer];
  const int row = tid >> 4;
  const int c0 = (tid & 15) << 4;
  const size_t nbase = (((size_t)(n0 + row)) << 8) + c0;
#pragma unroll
  for (int j = 0; j < 4; ++j) {
    const float4 hv = *(const float4*)(h + nbase + (j << 2));
    const float4 av = *(const float4*)&g_acc[row][c0 + (j << 2)];
    float4 o;
    o.x = fmaf(f, hv.x, av.x);
    o.y = fmaf(f, hv.y, av.y);
    o.z = fmaf(f, hv.z, av.z);
    o.w = fmaf(f, hv.w, av.w);
    *(float4*)(g1 + nbase + (j << 2)) = o;
  }
}

// ---------------------------------------------------------------------------
// fp32 tiled GEMM (kept for encoder K=771 and tiny classifier GEMMs).
// ---------------------------------------------------------------------------
template <bool BT, bool RELU>
__global__ __launch_bounds__(256, 4) void gemm_kernel(
    const float* __restrict__ A, const float* __restrict__ B,
    const float* __restrict__ bias, float* __restrict__ Cmat,
    int M, int Nn, int K)
{
  __shared__ float As[8][132];
  __shared__ float Bs[8][132];
  const int tid = threadIdx.x;
  const int bm = blockIdx.y * 128;
  const int bn = blockIdx.x * 128;
  const int tm = (tid >> 4) << 3;
  const int tn = (tid & 15) << 3;
  float acc[8][8];
#pragma unroll
  for (int i = 0; i < 8; ++i)
#pragma unroll
    for (int j = 0; j < 8; ++j) acc[i][j] = 0.f;

  const int nk = (K + 7) >> 3;
  const bool k4 = (K & 3) == 0;
  for (int kc = 0; kc < nk; ++kc) {
    const int k0 = kc << 3;
    {
      const int r = tid >> 1;
      const int kk = (tid & 1) << 2;
      const int gm = bm + r;
      float va[4] = {0.f, 0.f, 0.f, 0.f};
      if (gm < M) {
        const size_t base = (size_t)gm * K + k0 + kk;
        if (k4 && (k0 + kk + 4 <= K)) {
          const float4 v = *(const float4*)(A + base);
          va[0] = v.x; va[1] = v.y; va[2] = v.z; va[3] = v.w;
        } else {
#pragma unroll
          for (int j = 0; j < 4; ++j)
            if (k0 + kk + j < K) va[j] = A[base + j];
        }
      }
      As[kk + 0][r] = va[0]; As[kk + 1][r] = va[1];
      As[kk + 2][r] = va[2]; As[kk + 3][r] = va[3];
    }
    if (!BT) {
      const int r = tid >> 5;
      const int cb = (tid & 31) << 2;
      float4 v = make_float4(0.f, 0.f, 0.f, 0.f);
      if (k0 + r < K) v = *(const float4*)(B + (size_t)(k0 + r) * Nn + bn + cb);
      *(float4*)&Bs[r][cb] = v;
    } else {
      const int r = tid >> 1;
      const int kk = (tid & 1) << 2;
      float vb[4] = {0.f, 0.f, 0.f, 0.f};
      if (bn + r < Nn) {
        const size_t base = (size_t)(bn + r) * K + k0 + kk;
        if (k4 && (k0 + kk + 4 <= K)) {
          const float4 v = *(const float4*)(B + base);
          vb[0] = v.x; vb[1] = v.y; vb[2] = v.z; vb[3] = v.w;
        } else {
#pragma unroll
          for (int j = 0; j < 4; ++j)
            if (k0 + kk + j < K) vb[j] = B[base + j];
        }
      }
      Bs[kk + 0][r] = vb[0]; Bs[kk + 1][r] = vb[1];
      Bs[kk + 2][r] = vb[2]; Bs[kk + 3][r] = vb[3];
    }
    __syncthreads();
#pragma unroll
    for (int k = 0; k < 8; ++k) {
      const float4 a0 = *(const float4*)&As[k][tm];
      const float4 a1 = *(const float4*)&As[k][tm + 4];
      const float4 b0 = *(const float4*)&Bs[k][tn];
      const float4 b1 = *(const float4*)&Bs[k][tn + 4];
      const float av[8] = {a0.x, a0.y, a0.z, a0.w, a1.x, a1.y, a1.z, a1.w};
      const float bv[8] = {b0.x, b0.y, b0.z, b0.w, b1.x, b1.y, b1.z, b1.w};
#pragma unroll
      for (int i = 0; i < 8; ++i)
#pragma unroll
        for (int j = 0; j < 8; ++j)
          acc[i][j] = fmaf(av[i], bv[j], acc[i][j]);
    }
    __syncthreads();
  }
#pragma unroll
  for (int i = 0; i < 8; ++i) {
    const int gm = bm + tm + i;
    if (gm >= M) continue;
    float* crow = Cmat + (size_t)gm * Nn + bn + tn;
#pragma unroll
    for (int j = 0; j < 8; ++j) {
      const int gn = bn + tn + j;
      if (gn >= Nn) continue;
      float v = acc[i][j] + (bias ? bias[gn] : 0.f);
      if (RELU) v = fmaxf(v, 0.f);
      crow[j] = v;
    }
  }
}

// ---------------------------------------------------------------------------
// CSR build: histogram of dst -> exclusive scan -> scatter edge ids.
// ---------------------------------------------------------------------------
__global__ __launch_bounds__(256) void hist_kernel(
    const int* __restrict__ dst, int* __restrict__ deg)
{
  const int e = blockIdx.x * 256 + threadIdx.x;
  atomicAdd(&deg[dst[e]], 1);
}

__global__ __launch_bounds__(256) void scan_kernel(
    const int* __restrict__ deg, int* __restrict__ row_ptr,
    int* __restrict__ fill)
{
  __shared__ int part[256];
  const int t = threadIdx.x;
  const int base = t << 8;
  int s = 0;
  for (int j = 0; j < 256; ++j) s += deg[base + j];
  part[t] = s;
  __syncthreads();
  for (int off = 1; off < 256; off <<= 1) {
    int v = (t >= off) ? part[t - off] : 0;
    __syncthreads();
    part[t] += v;
    __syncthreads();
  }
  int run = (t == 0) ? 0 : part[t - 1];
  for (int j = 0; j < 256; ++j) {
    row_ptr[base + j] = run;
    fill[base + j] = run;
    run += deg[base + j];
  }
  if (t == 255) row_ptr[65536] = run;
}

__global__ __launch_bounds__(256) void scatter_kernel(
    const int* __restrict__ dst, int* __restrict__ fill,
    int* __restrict__ eid)
{
  const int e = blockIdx.x * 256 + threadIdx.x;
  const int pos = atomicAdd(&fill[dst[e]], 1);
  eid[pos] = e;
}

// ---------------------------------------------------------------------------
// Streaming attention, one block per (graph, head).
// ---------------------------------------------------------------------------
__global__ __launch_bounds__(256, 2) void attn_kernel(
    const float* __restrict__ qkv, float* __restrict__ o)
{
  __shared__ float k_s[128][64];
  __shared__ float v_s[128][64];
  const int gh = blockIdx.x;
  const int g = gh >> 2;
  const int hh = gh & 3;
  const int p = threadIdx.x;
  const float scale = 0.125f;
  const float* qrow = qkv + ((size_t)(g * 256 + p)) * 768 + hh * 64;
  float4 q[16];
#pragma unroll
  for (int i = 0; i < 16; ++i) q[i] = *(const float4*)(qrow + (i << 2));
  float4 oa[16];
#pragma unroll
  for (int i = 0; i < 16; ++i) oa[i] = make_float4(0.f, 0.f, 0.f, 0.f);
  float l = 0.f;
  for (int kb = 0; kb < 256; kb += 128) {
    __syncthreads();
#pragma unroll
    for (int it = 0; it < 8; ++it) {
      const int idx = it * 256 + p;
      const int row = idx >> 4;
      const int c4 = (idx & 15) << 2;
      const float* base = qkv + ((size_t)(g * 256 + kb + row)) * 768 + hh * 64 + c4;
      *(float4*)&k_s[row][c4] = *(const float4*)(base + 256);
      *(float4*)&v_s[row][c4] = *(const float4*)(base + 512);
    }
    __syncthreads();
    for (int j = 0; j < 128; ++j) {
      const float* kr = k_s[j];
      float s = 0.f;
#pragma unroll
      for (int i = 0; i < 16; ++i) {
        const float4 kv = *(const float4*)(kr + (i << 2));
        s = fmaf(q[i].x, kv.x, s);
        s = fmaf(q[i].y, kv.y, s);
        s = fmaf(q[i].z, kv.z, s);
        s = fmaf(q[i].w, kv.w, s);
      }
      const float pe = __expf(s * scale);
      l += pe;
      const float* vr = v_s[j];
#pragma unroll
      for (int i = 0; i < 16; ++i) {
        const float4 vv = *(const float4*)(vr + (i << 2));
        FMA4(oa[i], pe, vv);
      }
    }
  }
  const float inv = 1.f / l;
  float* orow = o + ((size_t)(g * 256 + p)) * 256 + hh * 64;
#pragma unroll
  for (int i = 0; i < 16; ++i) {
    float4 t = oa[i];
    t.x *= inv; t.y *= inv; t.z *= inv; t.w *= inv;
    *(float4*)(orow + (i << 2)) = t;
  }
}

// ---------------------------------------------------------------------------
__global__ __launch_bounds__(256) void ln_kernel(
    const float* __restrict__ a, const float* __restrict__ res,
    const float* __restrict__ gam, const float* __restrict__ bet,
    float* __restrict__ out, int relu)
{
  __shared__ float2 red[256];
  const int t = threadIdx.x;
  const size_t base = (size_t)blockIdx.x * 256;
  float v = a[base + t];
  if (res) v += res[base + t];
  red[t] = make_float2(v, v * v);
  __syncthreads();
#pragma unroll
  for (int s = 128; s > 0; s >>= 1) {
    if (t < s) { red[t].x += red[t + s].x; red[t].y += red[t + s].y; }
    __syncthreads();
  }
  const float mu = red[0].x * (1.f / 256.f);
  const float var = red[0].y * (1.f / 256.f) - mu * mu;
  float r = (v - mu) * rsqrtf(var + 1e-5f) * gam[t] + bet[t];
  if (relu) r = fmaxf(r, 0.f);
  out[base + t] = r;
}

__global__ __launch_bounds__(256) void bn_stats_kernel(
    const float* __restrict__ y, float* __restrict__ stats)
{
  const int t = threadIdx.x;
  const size_t r0 = (size_t)blockIdx.x * 64;
  float s = 0.f, s2 = 0.f;
  for (int r = 0; r < 64; ++r) {
    const float v = y[(r0 + r) * 256 + t];
    s += v;
    s2 = fmaf(v, v, s2);
  }
  atomicAdd(&stats[t], s);
  atomicAdd(&stats[256 + t], s2);
}

__global__ __launch_bounds__(256) void bn_apply_kernel(
    float* __restrict__ y, const float* __restrict__ stats,
    const float* __restrict__ gam, const float* __restrict__ bet)
{
  const size_t i = ((size_t)blockIdx.x * 256 + threadIdx.x) << 2;
  const int c = (int)(i & 255);
  const float inv_n = 1.f / 65536.f;
  float4 v = *(float4*)(y + i);
  const float4 s4 = *(const float4*)(stats + c);
  const float4 q4 = *(const float4*)(stats + 256 + c);
  const float4 g4 = *(const float4*)(gam + c);
  const float4 b4 = *(const float4*)(bet + c);
  float mu, var, sc;
  mu = s4.x * inv_n; var = q4.x * inv_n - mu * mu; sc = g4.x * rsqrtf(var + 1e-5f);
  v.x = fmaxf((v.x - mu) * sc + b4.x, 0.f);
  mu = s4.y * inv_n; var = q4.y * inv_n - mu * mu; sc = g4.y * rsqrtf(var + 1e-5f);
  v.y = fmaxf((v.y - mu) * sc + b4.y, 0.f);
  mu = s4.z * inv_n; var = q4.z * inv_n - mu * mu; sc = g4.z * rsqrtf(var + 1e-5f);
  v.z = fmaxf((v.z - mu) * sc + b4.z, 0.f);
  mu = s4.w * inv_n; var = q4.w * inv_n - mu * mu; sc = g4.w * rsqrtf(var + 1e-5f);
  v.w = fmaxf((v.w - mu) * sc + b4.w, 0.f);
  *(float4*)(y + i) = v;
}

__global__ __launch_bounds__(256) void add_kernel(
    const float* __restrict__ a, const float* __restrict__ b,
    float* __restrict__ out)
{
  const size_t i = ((size_t)blockIdx.x * 256 + threadIdx.x) << 2;
  const float4 va = *(const float4*)(a + i);
  const float4 vb = *(const float4*)(b + i);
  float4 v;
  v.x = va.x + vb.x; v.y = va.y + vb.y; v.z = va.z + vb.z; v.w = va.w + vb.w;
  *(float4*)(out + i) = v;
}

__global__ __launch_bounds__(256) void pool_kernel(
    const float* __restrict__ h, const int* __restrict__ batch,
    float* __restrict__ sums, float* __restrict__ cnt)
{
  const int t = threadIdx.x;
  const int n0 = blockIdx.x * 256;
  float acc = 0.f, runc = 0.f;
  int cur = batch[n0];
  for (int r = 0; r < 256; ++r) {
    const int n = n0 + r;
    const int b = batch[n];
    if (b != cur) {
      atomicAdd(&sums[(size_t)cur * 256 + t], acc);
      if (t == 0) atomicAdd(&cnt[cur], runc);
      acc = 0.f; runc = 0.f; cur = b;
    }
    acc += h[(size_t)n * 256 + t];
    runc += 1.f;
  }
  atomicAdd(&sums[(size_t)cur * 256 + t], acc);
  if (t == 0) atomicAdd(&cnt[cur], runc);
}

__global__ __launch_bounds__(256) void gemb_kernel(
    const float* __restrict__ sums, const float* __restrict__ cnt,
    float* __restrict__ gemb)
{
  const int i = blockIdx.x * 256 + threadIdx.x;
  const int g = i >> 8;
  gemb[i] = sums[i] / fmaxf(cnt[g], 1.f);
}

__global__ __launch_bounds__(256) void head_kernel(
    const float* __restrict__ z2, const float* __restrict__ w3,
    const float* __restrict__ b3, float* __restrict__ out)
{
  __shared__ float w[128];
  const int t = threadIdx.x;
  if (t < 128) w[t] = w3[t];
  __syncthreads();
  float s = 0.f;
  const float* row = z2 + (size_t)t * 128;
#pragma unroll 4
  for (int d = 0; d < 128; ++d) s = fmaf(row[d], w[d], s);
  out[t] = s + b3[0];
}

// ---------------------------------------------------------------------------
extern "C" void kernel_launch(void* const* d_in, const int* in_sizes, int n_in,
                              void* d_out, int out_size, void* d_ws, size_t ws_size,
                              hipStream_t stream)
{
  const float* x          = (const float*)d_in[0];
  const int*   edge_index = (const int*)d_in[1];
  const int*   batch      = (const int*)d_in[2];
  const float* edge_attr  = (const float*)d_in[3];
  const float* ne_w   = (const float*)d_in[4];
  const float* ne_b   = (const float*)d_in[5];
  const float* ne_ln_g = (const float*)d_in[6];
  const float* ne_ln_b = (const float*)d_in[7];
  const float* ee_w   = (const float*)d_in[8];
  const float* ee_b   = (const float*)d_in[9];
  const float* eps    = (const float*)d_in[10];
  const float* elin_w = (const float*)d_in[11];
  const float* gin_w1 = (const float*)d_in[12];
  const float* gin_w2 = (const float*)d_in[13];
  const float* attn_in_w  = (const float*)d_in[14];
  const float* attn_out_w = (const float*)d_in[15];
  const float* mlp_w1 = (const float*)d_in[16];
  const float* mlp_w2 = (const float*)d_in[17];
  const float* elin_b = (const float*)d_in[18];
  const float* gin_b1 = (const float*)d_in[19];
  const float* gin_b2 = (const float*)d_in[20];
  const float* attn_in_b  = (const float*)d_in[21];
  const float* attn_out_b = (const float*)d_in[22];
  const float* mlp_b1 = (const float*)d_in[23];
  const float* mlp_b2 = (const float*)d_in[24];
  const float* gin_bn_g = (const float*)d_in[25];
  const float* ln1_g  = (const float*)d_in[26];
  const float* ln2_g  = (const float*)d_in[27];
  const float* ln3_g  = (const float*)d_in[28];
  const float* gin_bn_b = (const float*)d_in[29];
  const float* ln1_b  = (const float*)d_in[30];
  const float* ln2_b  = (const float*)d_in[31];
  const float* ln3_b  = (const float*)d_in[32];
  const float* cls_w1 = (const float*)d_in[33];
  const float* cls_b1 = (const float*)d_in[34];
  const float* cls_ln_g = (const float*)d_in[35];
  const float* cls_ln_b = (const float*)d_in[36];
  const float* cls_w2 = (const float*)d_in[37];
  const float* cls_b2 = (const float*)d_in[38];
  const float* cls_w3 = (const float*)d_in[39];
  const float* cls_b3 = (const float*)d_in[40];

  const int* src = edge_index;
  const int* dst = edge_index + N_EDGES;

  float* ws = (float*)d_ws;
  const size_t NC = (size_t)N_NODES * CH;       // 16,777,216
  float* h    = ws;
  float* bufA = ws + NC;
  float* bufB = ws + 2 * NC;
  float* bufC = ws + 3 * NC;
  float* bufQ = ws + 4 * NC;                    // qkv [N,768] / m1 [N,512] / EE pass buffer
  float* stats = bufQ + (size_t)N_NODES * 768;  // 4*512
  int* ideg  = (int*)(stats + 2048);            // 65536
  int* ifill = ideg + 65536;                    // 65536
  int* irow  = ifill + 65536;                   // 65537 (padded to 65544)
  int* ieid  = irow + 65544;                    // 524288
  unsigned short* pan = (unsigned short*)(ieid + 524288);  // bf16 panels
  // post-loop scratch reuses bufA (dead after last layer):
  float* sums = bufA;
  float* cnt  = bufA + 65536;
  float* gemb = bufA + 65792;
  float* z1   = bufA + 131328;
  float* z2   = bufA + 196864;

  const dim3 blk(256);
  const size_t PL = 720896;  // panel elems per layer (incl elin_w)

  // ---- CSR build + weight bf16 panelization (once) ----
  hipMemsetAsync(stats, 0, 2048 * sizeof(float), stream);
  hipMemsetAsync(ideg, 0, 65536 * sizeof(int), stream);
  hist_kernel<<<dim3(2048), blk, 0, stream>>>(dst, ideg);
  scan_kernel<<<dim3(1), blk, 0, stream>>>(ideg, irow, ifill);
  scatter_kernel<<<dim3(2048), blk, 0, stream>>>(dst, ifill, ieid);
  for (int l = 0; l < 4; ++l) {
    unsigned short* p = pan + l * PL;
    wcvt_kernel<<<dim3(256), blk, 0, stream>>>(gin_w1 + (size_t)l * 65536, p, 256, 256, 0);
    wcvt_kernel<<<dim3(256), blk, 0, stream>>>(gin_w2 + (size_t)l * 65536, p + 65536, 256, 256, 0);
    wcvt_kernel<<<dim3(768), blk, 0, stream>>>(attn_in_w + (size_t)l * 196608, p + 131072, 256, 768, 1);
    wcvt_kernel<<<dim3(256), blk, 0, stream>>>(attn_out_w + (size_t)l * 65536, p + 327680, 256, 256, 1);
    wcvt_kernel<<<dim3(512), blk, 0, stream>>>(mlp_w1 + (size_t)l * 131072, p + 393216, 256, 512, 0);
    wcvt_kernel<<<dim3(512), blk, 0, stream>>>(mlp_w2 + (size_t)l * 131072, p + 524288, 512, 256, 0);
    wcvt_kernel<<<dim3(256), blk, 0, stream>>>(elin_w + (size_t)l * 65536, p + 655360, 256, 256, 0);
  }

  // ---- encoders (K=771: stays fp32) ----
  gemm_kernel<false, false><<<dim3(2, 512), blk, 0, stream>>>(
      x, ne_w, ne_b, bufB, N_NODES, 256, 771);
  ln_kernel<<<dim3(N_NODES), blk, 0, stream>>>(bufB, nullptr, ne_ln_g, ne_ln_b, h, 1);

  for (int l = 0; l < 4; ++l) {
    unsigned short* p = pan + l * PL;
    // ---- GINEConv: 4 node-range passes of (edge GEMM -> scatter) ----
    for (int q = 0; q < 4; ++q) {
      eegemm_kernel<<<dim3(2, 1056), blk, 0, stream>>>(
          edge_attr, ieid, irow, q * 16384, ee_w, ee_b,
          p + 655360, elin_b + l * 256, bufQ);
      gscat_kernel<<<dim3(1024), blk, 0, stream>>>(
          bufQ, src, dst, irow, ieid, q * 16384, h, eps, l, bufA);
    }
    mgemm_kernel<false><<<dim3(2, 512), blk, 0, stream>>>(
        bufA, p, gin_b1 + l * 256, bufB, N_NODES, 256, 256);
    bn_stats_kernel<<<dim3(1024), blk, 0, stream>>>(bufB, stats + l * 512);
    bn_apply_kernel<<<dim3(16384), blk, 0, stream>>>(
        bufB, stats + l * 512, gin_bn_g + l * 256, gin_bn_b + l * 256);
    mgemm_kernel<false><<<dim3(2, 512), blk, 0, stream>>>(
        bufB, p + 65536, gin_b2 + l * 256, bufC, N_NODES, 256, 256);
    ln_kernel<<<dim3(N_NODES), blk, 0, stream>>>(
        bufC, h, ln1_g + l * 256, ln1_b + l * 256, bufC, 0);
    // ---- attention ----
    mgemm_kernel<false><<<dim3(6, 512), blk, 0, stream>>>(
        h, p + 131072, attn_in_b + l * 768, bufQ, N_NODES, 768, 256);
    attn_kernel<<<dim3(1024), blk, 0, stream>>>(bufQ, bufA);
    mgemm_kernel<false><<<dim3(2, 512), blk, 0, stream>>>(
        bufA, p + 327680, attn_out_b + l * 256, bufB, N_NODES, 256, 256);
    ln_kernel<<<dim3(N_NODES), blk, 0, stream>>>(
        bufB, h, ln2_g + l * 256, ln2_b + l * 256, bufB, 0);
    // ---- FFN ----
    add_kernel<<<dim3(16384), blk, 0, stream>>>(bufC, bufB, bufB);
    mgemm_kernel<true><<<dim3(4, 512), blk, 0, stream>>>(
        bufB, p + 393216, mlp_b1 + l * 512, bufQ, N_NODES, 512, 256);
    mgemm_kernel<false><<<dim3(2, 512), blk, 0, stream>>>(
        bufQ, p + 524288, mlp_b2 + l * 256, bufC, N_NODES, 256, 512);
    ln_kernel<<<dim3(N_NODES), blk, 0, stream>>>(
        bufC, bufB, ln3_g + l * 256, ln3_b + l * 256, h, 0);
  }

  // ---- pooling + classifier ----
  hipMemsetAsync(sums, 0, 65792 * sizeof(float), stream);
  pool_kernel<<<dim3(256), blk, 0, stream>>>(h, batch, sums, cnt);
  gemb_kernel<<<dim3(256), blk, 0, stream>>>(sums, cnt, gemb);
  gemm_kernel<false, false><<<dim3(2, 2), blk, 0, stream>>>(
      gemb, cls_w1, cls_b1, z1, 256, 256, 256);
  ln_kernel<<<dim3(256), blk, 0, stream>>>(z1, nullptr, cls_ln_g, cls_ln_b, z1, 1);
  gemm_kernel<false, true><<<dim3(1, 2), blk, 0, stream>>>(
      z1, cls_w2, cls_b2, z2, 256, 128, 256);
  head_kernel<<<dim3(1), blk, 0, stream>>>(z2, cls_w3, cls_b3, (float*)d_out);
}

// Round 3
// 8599.023 us; speedup vs baseline: 1.6086x; 1.2230x over previous
//
#include <hip/hip_runtime.h>
#include <hip/hip_bf16.h>
#include <math.h>

#define N_NODES 65536
#define N_EDGES 524288
#define CH 256

#define FMA4(A4, S, W4) \
  A4.x = fmaf((S), (W4).x, A4.x); A4.y = fmaf((S), (W4).y, A4.y); \
  A4.z = fmaf((S), (W4).z, A4.z); A4.w = fmaf((S), (W4).w, A4.w)

typedef __bf16 bf16x8 __attribute__((ext_vector_type(8)));
typedef float f32x4 __attribute__((ext_vector_type(4)));

__device__ inline unsigned short bf16rn(float v) {
  unsigned int u = __float_as_uint(v);
  u = u + 0x7FFFu + ((u >> 16) & 1u);
  return (unsigned short)(u >> 16);
}

__device__ inline bf16x8 pack_bf16_8(const float4 a, const float4 b) {
  union { __hip_bfloat162 h2[4]; bf16x8 v; } r;
  r.h2[0] = __float22bfloat162_rn(make_float2(a.x, a.y));
  r.h2[1] = __float22bfloat162_rn(make_float2(a.z, a.w));
  r.h2[2] = __float22bfloat162_rn(make_float2(b.x, b.y));
  r.h2[3] = __float22bfloat162_rn(make_float2(b.z, b.w));
  return r.v;
}

// ---------------------------------------------------------------------------
// Weight pre-convert: fp32 W -> bf16 k-panel layout P[(k>>3)*N + n][k&7].
// transposed=1 means logical B[k][n] = W[n*K+k] (for reference's @ W.T GEMMs).
// ---------------------------------------------------------------------------
__global__ __launch_bounds__(256) void wcvt_kernel(
    const float* __restrict__ W, unsigned short* __restrict__ P,
    int K, int Nn, int transposed)
{
  const int idx = blockIdx.x * 256 + threadIdx.x;
  const int k = idx / Nn;
  const int n = idx - k * Nn;
  const float v = transposed ? W[(size_t)n * K + k] : W[(size_t)k * Nn + n];
  P[(((size_t)(k >> 3)) * Nn + n) * 8 + (k & 7)] = bf16rn(v);
}

// ---------------------------------------------------------------------------
// LDS-free bf16 MFMA GEMM: C[M,N] = A_f32[M,K] @ Bp + bias (+relu).
// ---------------------------------------------------------------------------
template <bool RELU>
__global__ __launch_bounds__(256, 3) void mgemm_kernel(
    const float* __restrict__ A, const unsigned short* __restrict__ Bp,
    const float* __restrict__ bias, float* __restrict__ Cmat,
    int M, int Nn, int K)
{
  const int tid = threadIdx.x;
  const int lane = tid & 63;
  const int w = tid >> 6;
  const int m_base = blockIdx.y * 128 + (w >> 1) * 64;
  const int n_base = blockIdx.x * 128 + (w & 1) * 64;
  const int lr = lane & 15;
  const int lq = lane >> 4;
  f32x4 acc[4][4];
#pragma unroll
  for (int i = 0; i < 4; ++i)
#pragma unroll
    for (int j = 0; j < 4; ++j) acc[i][j] = (f32x4){0.f, 0.f, 0.f, 0.f};

  for (int k0 = 0; k0 < K; k0 += 32) {
    const int ka = k0 + (lq << 3);
    bf16x8 af[4], bfv[4];
#pragma unroll
    for (int mt = 0; mt < 4; ++mt) {
      const float* ap = A + (size_t)(m_base + mt * 16 + lr) * K + ka;
      af[mt] = pack_bf16_8(*(const float4*)ap, *(const float4*)(ap + 4));
    }
#pragma unroll
    for (int nt = 0; nt < 4; ++nt) {
      const size_t off =
          (((size_t)(ka >> 3)) * Nn + (n_base + nt * 16 + lr)) << 3;
      union { uint4 u; bf16x8 b; } bu;
      bu.u = *(const uint4*)(Bp + off);
      bfv[nt] = bu.b;
    }
#pragma unroll
    for (int mt = 0; mt < 4; ++mt)
#pragma unroll
      for (int nt = 0; nt < 4; ++nt)
        acc[mt][nt] = __builtin_amdgcn_mfma_f32_16x16x32_bf16(
            af[mt], bfv[nt], acc[mt][nt], 0, 0, 0);
  }
#pragma unroll
  for (int nt = 0; nt < 4; ++nt) {
    const int col = n_base + nt * 16 + lr;
    const float bv = bias[col];
#pragma unroll
    for (int mt = 0; mt < 4; ++mt) {
      const int row0 = m_base + mt * 16 + (lq << 2);
#pragma unroll
      for (int r = 0; r < 4; ++r) {
        float v = acc[mt][nt][r] + bv;
        if (RELU) v = fmaxf(v, 0.f);
        Cmat[(size_t)(row0 + r) * Nn + col] = v;
      }
    }
  }
}

// ---------------------------------------------------------------------------
// eegemm: EE[slot,:] = relu(edge_attr[eid[slot]] @ ee_w + ee_b) @ elin_w
//         + elin_b, for sorted slots (pass-local). mgemm structure; A-frags
//         built on the fly from 4 edge_attr scalars + enc weights in LDS.
// ---------------------------------------------------------------------------
__global__ __launch_bounds__(256, 3) void eegemm_kernel(
    const float* __restrict__ edge_attr,
    const int* __restrict__ eid_sorted,
    const int* __restrict__ row_ptr, int node_base,
    const float* __restrict__ ee_w, const float* __restrict__ ee_b,
    const unsigned short* __restrict__ elin_p, const float* __restrict__ elin_b,
    float* __restrict__ EE)
{
  __shared__ float wenc[4][256];
  __shared__ float benc[256];
  const int tid = threadIdx.x;
  const int slot_base = row_ptr[node_base];
  const int slot_end = row_ptr[node_base + 16384];
  const int m_rel = blockIdx.y * 128;
  if (slot_base + m_rel >= slot_end) return;  // block-uniform exit

  ((float4*)wenc)[tid] = ((const float4*)ee_w)[tid];
  if (tid < 64) ((float4*)benc)[tid] = ((const float4*)ee_b)[tid];
  __syncthreads();

  const int lane = tid & 63;
  const int w = tid >> 6;
  const int m_base = m_rel + (w >> 1) * 64;
  const int n_base = blockIdx.x * 128 + (w & 1) * 64;
  const int lr = lane & 15;
  const int lq = lane >> 4;

  float4 ea_r[4];
#pragma unroll
  for (int mt = 0; mt < 4; ++mt) {
    const int abs_slot = slot_base + m_base + mt * 16 + lr;
    if (abs_slot < slot_end) {
      const int e = eid_sorted[abs_slot];
      ea_r[mt] = *(const float4*)(edge_attr + ((size_t)e << 2));
    } else {
      ea_r[mt] = make_float4(0.f, 0.f, 0.f, 0.f);
    }
  }

  f32x4 acc[4][4];
#pragma unroll
  for (int i = 0; i < 4; ++i)
#pragma unroll
    for (int j = 0; j < 4; ++j) acc[i][j] = (f32x4){0.f, 0.f, 0.f, 0.f};

  for (int k0 = 0; k0 < 256; k0 += 32) {
    const int ka = k0 + (lq << 3);
    const float4 b0 = *(const float4*)&benc[ka];
    const float4 b1 = *(const float4*)&benc[ka + 4];
    float4 w0[4], w1[4];
#pragma unroll
    for (int j = 0; j < 4; ++j) {
      w0[j] = *(const float4*)&wenc[j][ka];
      w1[j] = *(const float4*)&wenc[j][ka + 4];
    }
    bf16x8 af[4], bfv[4];
#pragma unroll
    for (int mt = 0; mt < 4; ++mt) {
      float4 v0 = b0, v1 = b1;
      FMA4(v0, ea_r[mt].x, w0[0]); FMA4(v1, ea_r[mt].x, w1[0]);
      FMA4(v0, ea_r[mt].y, w0[1]); FMA4(v1, ea_r[mt].y, w1[1]);
      FMA4(v0, ea_r[mt].z, w0[2]); FMA4(v1, ea_r[mt].z, w1[2]);
      FMA4(v0, ea_r[mt].w, w0[3]); FMA4(v1, ea_r[mt].w, w1[3]);
      v0.x = fmaxf(v0.x, 0.f); v0.y = fmaxf(v0.y, 0.f);
      v0.z = fmaxf(v0.z, 0.f); v0.w = fmaxf(v0.w, 0.f);
      v1.x = fmaxf(v1.x, 0.f); v1.y = fmaxf(v1.y, 0.f);
      v1.z = fmaxf(v1.z, 0.f); v1.w = fmaxf(v1.w, 0.f);
      af[mt] = pack_bf16_8(v0, v1);
    }
#pragma unroll
    for (int nt = 0; nt < 4; ++nt) {
      const size_t off =
          (((size_t)(ka >> 3)) * 256 + (n_base + nt * 16 + lr)) << 3;
      union { uint4 u; bf16x8 b; } bu;
      bu.u = *(const uint4*)(elin_p + off);
      bfv[nt] = bu.b;
    }
#pragma unroll
    for (int mt = 0; mt < 4; ++mt)
#pragma unroll
      for (int nt = 0; nt < 4; ++nt)
        acc[mt][nt] = __builtin_amdgcn_mfma_f32_16x16x32_bf16(
            af[mt], bfv[nt], acc[mt][nt], 0, 0, 0);
  }

#pragma unroll
  for (int nt = 0; nt < 4; ++nt) {
    const int col = n_base + nt * 16 + lr;
    const float bv = elin_b[col];
#pragma unroll
    for (int mt = 0; mt < 4; ++mt) {
      const int row0 = m_base + mt * 16 + (lq << 2);
#pragma unroll
      for (int r = 0; r < 4; ++r) {
        if (slot_base + row0 + r < slot_end)
          EE[(size_t)(row0 + r) * 256 + col] = acc[mt][nt][r] + bv;
      }
    }
  }
}

// ---------------------------------------------------------------------------
// gscat: CSR-ordered scatter-aggregate.
// msg = relu(h[src] + EE[slot]); sum at dst; g1 = (1+eps)*h + aggr.
// ---------------------------------------------------------------------------
__global__ __launch_bounds__(256, 4) void gscat_kernel(
    const float* __restrict__ EE,
    const int* __restrict__ src_idx, const int* __restrict__ dst_idx,
    const int* __restrict__ row_ptr, const int* __restrict__ eid_sorted,
    int node_base,
    const float* __restrict__ h, const float* __restrict__ eps, int layer,
    float* __restrict__ g1)
{
  __shared__ float g_acc[16][256];
  __shared__ int si_s[64];
  __shared__ int sl_s[64];
  const int tid = threadIdx.x;
  const int n0 = node_base + (blockIdx.x << 4);
#pragma unroll
  for (int i = 0; i < 4; ++i)
    ((float4*)g_acc)[(i << 8) + tid] = make_float4(0.f, 0.f, 0.f, 0.f);
  const int slot_base = row_ptr[node_base];
  const int row_start = row_ptr[n0];
  const int row_end = row_ptr[n0 + 16];
  const int eg = (tid >> 6) << 4;
  const int cg = (tid & 63) << 2;

  for (int cs = row_start; cs < row_end; cs += 64) {
    __syncthreads();
    if (tid < 64) {
      const int slot = cs + tid;
      int s = 0, sl = -1;
      if (slot < row_end) {
        const int e = eid_sorted[slot];
        s = src_idx[e];
        sl = dst_idx[e] - n0;
      }
      si_s[tid] = s; sl_s[tid] = sl;
    }
    __syncthreads();
    const int er0 = cs - slot_base;
#pragma unroll
    for (int i = 0; i < 16; ++i) {
      const int li = eg + i;
      const int sl = sl_s[li];
      if (sl < 0) continue;
      const float4 e4 = *(const float4*)(EE + (size_t)(er0 + li) * 256 + cg);
      const float4 h4 = *(const float4*)(h + (((size_t)si_s[li]) << 8) + cg);
      atomicAdd(&g_acc[sl][cg + 0], fmaxf(h4.x + e4.x, 0.f));
      atomicAdd(&g_acc[sl][cg + 1], fmaxf(h4.y + e4.y, 0.f));
      atomicAdd(&g_acc[sl][cg + 2], fmaxf(h4.z + e4.z, 0.f));
      atomicAdd(&g_acc[sl][cg + 3], fmaxf(h4.w + e4.w, 0.f));
    }
  }
  __syncthreads();

  const float f = 1.f + eps[layer];
  const int row = tid >> 4;
  const int c0 = (tid & 15) << 4;
  const size_t nbase = (((size_t)(n0 + row)) << 8) + c0;
#pragma unroll
  for (int j = 0; j < 4; ++j) {
    const float4 hv = *(const float4*)(h + nbase + (j << 2));
    const float4 av = *(const float4*)&g_acc[row][c0 + (j << 2)];
    float4 o;
    o.x = fmaf(f, hv.x, av.x);
    o.y = fmaf(f, hv.y, av.y);
    o.z = fmaf(f, hv.z, av.z);
    o.w = fmaf(f, hv.w, av.w);
    *(float4*)(g1 + nbase + (j << 2)) = o;
  }
}

// ---------------------------------------------------------------------------
// fp32 tiled GEMM (kept for encoder K=771 and tiny classifier GEMMs).
// ---------------------------------------------------------------------------
template <bool BT, bool RELU>
__global__ __launch_bounds__(256, 4) void gemm_kernel(
    const float* __restrict__ A, const float* __restrict__ B,
    const float* __restrict__ bias, float* __restrict__ Cmat,
    int M, int Nn, int K)
{
  __shared__ float As[8][132];
  __shared__ float Bs[8][132];
  const int tid = threadIdx.x;
  const int bm = blockIdx.y * 128;
  const int bn = blockIdx.x * 128;
  const int tm = (tid >> 4) << 3;
  const int tn = (tid & 15) << 3;
  float acc[8][8];
#pragma unroll
  for (int i = 0; i < 8; ++i)
#pragma unroll
    for (int j = 0; j < 8; ++j) acc[i][j] = 0.f;

  const int nk = (K + 7) >> 3;
  const bool k4 = (K & 3) == 0;
  for (int kc = 0; kc < nk; ++kc) {
    const int k0 = kc << 3;
    {
      const int r = tid >> 1;
      const int kk = (tid & 1) << 2;
      const int gm = bm + r;
      float va[4] = {0.f, 0.f, 0.f, 0.f};
      if (gm < M) {
        const size_t base = (size_t)gm * K + k0 + kk;
        if (k4 && (k0 + kk + 4 <= K)) {
          const float4 v = *(const float4*)(A + base);
          va[0] = v.x; va[1] = v.y; va[2] = v.z; va[3] = v.w;
        } else {
#pragma unroll
          for (int j = 0; j < 4; ++j)
            if (k0 + kk + j < K) va[j] = A[base + j];
        }
      }
      As[kk + 0][r] = va[0]; As[kk + 1][r] = va[1];
      As[kk + 2][r] = va[2]; As[kk + 3][r] = va[3];
    }
    if (!BT) {
      const int r = tid >> 5;
      const int cb = (tid & 31) << 2;
      float4 v = make_float4(0.f, 0.f, 0.f, 0.f);
      if (k0 + r < K) v = *(const float4*)(B + (size_t)(k0 + r) * Nn + bn + cb);
      *(float4*)&Bs[r][cb] = v;
    } else {
      const int r = tid >> 1;
      const int kk = (tid & 1) << 2;
      float vb[4] = {0.f, 0.f, 0.f, 0.f};
      if (bn + r < Nn) {
        const size_t base = (size_t)(bn + r) * K + k0 + kk;
        if (k4 && (k0 + kk + 4 <= K)) {
          const float4 v = *(const float4*)(B + base);
          vb[0] = v.x; vb[1] = v.y; vb[2] = v.z; vb[3] = v.w;
        } else {
#pragma unroll
          for (int j = 0; j < 4; ++j)
            if (k0 + kk + j < K) vb[j] = B[base + j];
        }
      }
      Bs[kk + 0][r] = vb[0]; Bs[kk + 1][r] = vb[1];
      Bs[kk + 2][r] = vb[2]; Bs[kk + 3][r] = vb[3];
    }
    __syncthreads();
#pragma unroll
    for (int k = 0; k < 8; ++k) {
      const float4 a0 = *(const float4*)&As[k][tm];
      const float4 a1 = *(const float4*)&As[k][tm + 4];
      const float4 b0 = *(const float4*)&Bs[k][tn];
      const float4 b1 = *(const float4*)&Bs[k][tn + 4];
      const float av[8] = {a0.x, a0.y, a0.z, a0.w, a1.x, a1.y, a1.z, a1.w};
      const float bv[8] = {b0.x, b0.y, b0.z, b0.w, b1.x, b1.y, b1.z, b1.w};
#pragma unroll
      for (int i = 0; i < 8; ++i)
#pragma unroll
        for (int j = 0; j < 8; ++j)
          acc[i][j] = fmaf(av[i], bv[j], acc[i][j]);
    }
    __syncthreads();
  }
#pragma unroll
  for (int i = 0; i < 8; ++i) {
    const int gm = bm + tm + i;
    if (gm >= M) continue;
    float* crow = Cmat + (size_t)gm * Nn + bn + tn;
#pragma unroll
    for (int j = 0; j < 8; ++j) {
      const int gn = bn + tn + j;
      if (gn >= Nn) continue;
      float v = acc[i][j] + (bias ? bias[gn] : 0.f);
      if (RELU) v = fmaxf(v, 0.f);
      crow[j] = v;
    }
  }
}

// ---------------------------------------------------------------------------
// CSR build: histogram of dst -> exclusive scan -> scatter edge ids.
// ---------------------------------------------------------------------------
__global__ __launch_bounds__(256) void hist_kernel(
    const int* __restrict__ dst, int* __restrict__ deg)
{
  const int e = blockIdx.x * 256 + threadIdx.x;
  atomicAdd(&deg[dst[e]], 1);
}

__global__ __launch_bounds__(256) void scan_kernel(
    const int* __restrict__ deg, int* __restrict__ row_ptr,
    int* __restrict__ fill)
{
  __shared__ int part[256];
  const int t = threadIdx.x;
  const int base = t << 8;
  int s = 0;
  for (int j = 0; j < 256; ++j) s += deg[base + j];
  part[t] = s;
  __syncthreads();
  for (int off = 1; off < 256; off <<= 1) {
    int v = (t >= off) ? part[t - off] : 0;
    __syncthreads();
    part[t] += v;
    __syncthreads();
  }
  int run = (t == 0) ? 0 : part[t - 1];
  for (int j = 0; j < 256; ++j) {
    row_ptr[base + j] = run;
    fill[base + j] = run;
    run += deg[base + j];
  }
  if (t == 255) row_ptr[65536] = run;
}

__global__ __launch_bounds__(256) void scatter_kernel(
    const int* __restrict__ dst, int* __restrict__ fill,
    int* __restrict__ eid)
{
  const int e = blockIdx.x * 256 + threadIdx.x;
  const int pos = atomicAdd(&fill[dst[e]], 1);
  eid[pos] = e;
}

// ---------------------------------------------------------------------------
// MFMA attention, one block per (graph, head), 4 waves x 64 q-rows.
// Exact softmax over all 256 keys (no max-subtraction, same math as the
// fp32 version that passed). K staged as bf16 rows Ks[256][72]; V staged
// transposed Vt[64][258] (pad chosen for conflict-free b16 scatter writes);
// per-wave P chunk Ps[64][72] bf16 for the C-frag -> A-frag transpose.
// ---------------------------------------------------------------------------
__global__ __launch_bounds__(256, 1) void mattn_kernel(
    const float* __restrict__ qkv, float* __restrict__ o)
{
  __shared__ __attribute__((aligned(16))) unsigned short Ks[256 * 72];
  __shared__ __attribute__((aligned(16))) unsigned short Vt[64 * 258];
  __shared__ __attribute__((aligned(16))) unsigned short Ps[4][64 * 72];
  const int tid = threadIdx.x;
  const int gh = blockIdx.x;
  const int g = gh >> 2;
  const int hh = gh & 3;
  const int lane = tid & 63;
  const int w = tid >> 6;
  const int lr = lane & 15;
  const int lq = lane >> 4;
  const float scale = 0.125f;

  // ---- stage K rows (bf16) and V^T (bf16) ----
  {
    const int key0 = tid >> 4;
    const int c0 = (tid & 15) << 2;
#pragma unroll
    for (int it = 0; it < 16; ++it) {
      const int key = it * 16 + key0;
      const float* base = qkv + ((size_t)(g * 256 + key)) * 768 + hh * 64 + c0;
      const float4 kv = *(const float4*)(base + 256);
      const float4 vv = *(const float4*)(base + 512);
      union { __hip_bfloat162 h2[2]; ushort4 u; } pk;
      pk.h2[0] = __float22bfloat162_rn(make_float2(kv.x, kv.y));
      pk.h2[1] = __float22bfloat162_rn(make_float2(kv.z, kv.w));
      *(ushort4*)&Ks[key * 72 + c0] = pk.u;
      Vt[(c0 + 0) * 258 + key] = bf16rn(vv.x);
      Vt[(c0 + 1) * 258 + key] = bf16rn(vv.y);
      Vt[(c0 + 2) * 258 + key] = bf16rn(vv.z);
      Vt[(c0 + 3) * 258 + key] = bf16rn(vv.w);
    }
  }

  // ---- Q fragments (pre-scaled by 1/8), kept in registers ----
  const int m0 = w * 64;
  bf16x8 qf[2][4];
#pragma unroll
  for (int ks = 0; ks < 2; ++ks)
#pragma unroll
    for (int mt = 0; mt < 4; ++mt) {
      const float* ap = qkv +
          ((size_t)(g * 256 + m0 + mt * 16 + lr)) * 768 + hh * 64 +
          ks * 32 + (lq << 3);
      float4 a = *(const float4*)ap;
      float4 b = *(const float4*)(ap + 4);
      a.x *= scale; a.y *= scale; a.z *= scale; a.w *= scale;
      b.x *= scale; b.y *= scale; b.z *= scale; b.w *= scale;
      qf[ks][mt] = pack_bf16_8(a, b);
    }
  __syncthreads();

  f32x4 oacc[4][4];
#pragma unroll
  for (int i = 0; i < 4; ++i)
#pragma unroll
    for (int j = 0; j < 4; ++j) oacc[i][j] = (f32x4){0.f, 0.f, 0.f, 0.f};
  float lpart[4][4];
#pragma unroll
  for (int i = 0; i < 4; ++i)
#pragma unroll
    for (int j = 0; j < 4; ++j) lpart[i][j] = 0.f;

  unsigned short* Pw = Ps[w];

  for (int kb = 0; kb < 4; ++kb) {
    // ---- S chunk = Q @ K^T (64 q x 64 keys) ----
    f32x4 sacc[4][4];
#pragma unroll
    for (int i = 0; i < 4; ++i)
#pragma unroll
      for (int j = 0; j < 4; ++j) sacc[i][j] = (f32x4){0.f, 0.f, 0.f, 0.f};
#pragma unroll
    for (int ks = 0; ks < 2; ++ks) {
      bf16x8 bfv[4];
#pragma unroll
      for (int nt = 0; nt < 4; ++nt) {
        union { uint4 u; bf16x8 b; } bu;
        bu.u = *(const uint4*)&Ks[(kb * 64 + nt * 16 + lr) * 72 +
                                  ks * 32 + (lq << 3)];
        bfv[nt] = bu.b;
      }
#pragma unroll
      for (int mt = 0; mt < 4; ++mt)
#pragma unroll
        for (int nt = 0; nt < 4; ++nt)
          sacc[mt][nt] = __builtin_amdgcn_mfma_f32_16x16x32_bf16(
              qf[ks][mt], bfv[nt], sacc[mt][nt], 0, 0, 0);
    }
    // ---- p = exp(s); accumulate row sums; write bf16 P chunk ----
#pragma unroll
    for (int mt = 0; mt < 4; ++mt)
#pragma unroll
      for (int nt = 0; nt < 4; ++nt) {
#pragma unroll
        for (int rr = 0; rr < 4; ++rr) {
          const float p = __expf(sacc[mt][nt][rr]);
          lpart[mt][rr] += p;
          Pw[(mt * 16 + (lq << 2) + rr) * 72 + nt * 16 + lr] = bf16rn(p);
        }
      }
    asm volatile("s_waitcnt lgkmcnt(0)" ::: "memory");
    __builtin_amdgcn_sched_barrier(0);
    // ---- O += P_chunk @ V_chunk ----
#pragma unroll
    for (int ks = 0; ks < 2; ++ks) {
      bf16x8 pa[4], vb[4];
#pragma unroll
      for (int mt = 0; mt < 4; ++mt) {
        union { uint4 u; bf16x8 b; } au;
        au.u = *(const uint4*)&Pw[(mt * 16 + lr) * 72 + ks * 32 + (lq << 3)];
        pa[mt] = au.b;
      }
#pragma unroll
      for (int nt = 0; nt < 4; ++nt) {
        const unsigned short* vp =
            &Vt[(nt * 16 + lr) * 258 + kb * 64 + ks * 32 + (lq << 3)];
        union { unsigned int u4[4]; bf16x8 b; } vu;
        vu.u4[0] = *(const unsigned int*)(vp + 0);
        vu.u4[1] = *(const unsigned int*)(vp + 2);
        vu.u4[2] = *(const unsigned int*)(vp + 4);
        vu.u4[3] = *(const unsigned int*)(vp + 6);
        vb[nt] = vu.b;
      }
#pragma unroll
      for (int mt = 0; mt < 4; ++mt)
#pragma unroll
        for (int nt = 0; nt < 4; ++nt)
          oacc[mt][nt] = __builtin_amdgcn_mfma_f32_16x16x32_bf16(
              pa[mt], vb[nt], oacc[mt][nt], 0, 0, 0);
    }
  }

  // ---- row sums -> 1/l (reduce across the 16 lr lanes) ----
#pragma unroll
  for (int mt = 0; mt < 4; ++mt)
#pragma unroll
    for (int rr = 0; rr < 4; ++rr) {
      float v = lpart[mt][rr];
      v += __shfl_xor(v, 1);
      v += __shfl_xor(v, 2);
      v += __shfl_xor(v, 4);
      v += __shfl_xor(v, 8);
      lpart[mt][rr] = 1.f / v;
    }

  // ---- normalize + store O ----
#pragma unroll
  for (int mt = 0; mt < 4; ++mt) {
#pragma unroll
    for (int nt = 0; nt < 4; ++nt) {
#pragma unroll
      for (int rr = 0; rr < 4; ++rr) {
        const int row = m0 + mt * 16 + (lq << 2) + rr;
        o[((size_t)(g * 256 + row)) * 256 + hh * 64 + nt * 16 + lr] =
            oacc[mt][nt][rr] * lpart[mt][rr];
      }
    }
  }
}

// ---------------------------------------------------------------------------
__global__ __launch_bounds__(256) void ln_kernel(
    const float* __restrict__ a, const float* __restrict__ res,
    const float* __restrict__ gam, const float* __restrict__ bet,
    float* __restrict__ out, int relu)
{
  __shared__ float2 red[256];
  const int t = threadIdx.x;
  const size_t base = (size_t)blockIdx.x * 256;
  float v = a[base + t];
  if (res) v += res[base + t];
  red[t] = make_float2(v, v * v);
  __syncthreads();
#pragma unroll
  for (int s = 128; s > 0; s >>= 1) {
    if (t < s) { red[t].x += red[t + s].x; red[t].y += red[t + s].y; }
    __syncthreads();
  }
  const float mu = red[0].x * (1.f / 256.f);
  const float var = red[0].y * (1.f / 256.f) - mu * mu;
  float r = (v - mu) * rsqrtf(var + 1e-5f) * gam[t] + bet[t];
  if (relu) r = fmaxf(r, 0.f);
  out[base + t] = r;
}

__global__ __launch_bounds__(256) void bn_stats_kernel(
    const float* __restrict__ y, float* __restrict__ stats)
{
  const int t = threadIdx.x;
  const size_t r0 = (size_t)blockIdx.x * 64;
  float s = 0.f, s2 = 0.f;
  for (int r = 0; r < 64; ++r) {
    const float v = y[(r0 + r) * 256 + t];
    s += v;
    s2 = fmaf(v, v, s2);
  }
  atomicAdd(&stats[t], s);
  atomicAdd(&stats[256 + t], s2);
}

__global__ __launch_bounds__(256) void bn_apply_kernel(
    float* __restrict__ y, const float* __restrict__ stats,
    const float* __restrict__ gam, const float* __restrict__ bet)
{
  const size_t i = ((size_t)blockIdx.x * 256 + threadIdx.x) << 2;
  const int c = (int)(i & 255);
  const float inv_n = 1.f / 65536.f;
  float4 v = *(float4*)(y + i);
  const float4 s4 = *(const float4*)(stats + c);
  const float4 q4 = *(const float4*)(stats + 256 + c);
  const float4 g4 = *(const float4*)(gam + c);
  const float4 b4 = *(const float4*)(bet + c);
  float mu, var, sc;
  mu = s4.x * inv_n; var = q4.x * inv_n - mu * mu; sc = g4.x * rsqrtf(var + 1e-5f);
  v.x = fmaxf((v.x - mu) * sc + b4.x, 0.f);
  mu = s4.y * inv_n; var = q4.y * inv_n - mu * mu; sc = g4.y * rsqrtf(var + 1e-5f);
  v.y = fmaxf((v.y - mu) * sc + b4.y, 0.f);
  mu = s4.z * inv_n; var = q4.z * inv_n - mu * mu; sc = g4.z * rsqrtf(var + 1e-5f);
  v.z = fmaxf((v.z - mu) * sc + b4.z, 0.f);
  mu = s4.w * inv_n; var = q4.w * inv_n - mu * mu; sc = g4.w * rsqrtf(var + 1e-5f);
  v.w = fmaxf((v.w - mu) * sc + b4.w, 0.f);
  *(float4*)(y + i) = v;
}

__global__ __launch_bounds__(256) void add_kernel(
    const float* __restrict__ a, const float* __restrict__ b,
    float* __restrict__ out)
{
  const size_t i = ((size_t)blockIdx.x * 256 + threadIdx.x) << 2;
  const float4 va = *(const float4*)(a + i);
  const float4 vb = *(const float4*)(b + i);
  float4 v;
  v.x = va.x + vb.x; v.y = va.y + vb.y; v.z = va.z + vb.z; v.w = va.w + vb.w;
  *(float4*)(out + i) = v;
}

__global__ __launch_bounds__(256) void pool_kernel(
    const float* __restrict__ h, const int* __restrict__ batch,
    float* __restrict__ sums, float* __restrict__ cnt)
{
  const int t = threadIdx.x;
  const int n0 = blockIdx.x * 256;
  float acc = 0.f, runc = 0.f;
  int cur = batch[n0];
  for (int r = 0; r < 256; ++r) {
    const int n = n0 + r;
    const int b = batch[n];
    if (b != cur) {
      atomicAdd(&sums[(size_t)cur * 256 + t], acc);
      if (t == 0) atomicAdd(&cnt[cur], runc);
      acc = 0.f; runc = 0.f; cur = b;
    }
    acc += h[(size_t)n * 256 + t];
    runc += 1.f;
  }
  atomicAdd(&sums[(size_t)cur * 256 + t], acc);
  if (t == 0) atomicAdd(&cnt[cur], runc);
}

__global__ __launch_bounds__(256) void gemb_kernel(
    const float* __restrict__ sums, const float* __restrict__ cnt,
    float* __restrict__ gemb)
{
  const int i = blockIdx.x * 256 + threadIdx.x;
  const int g = i >> 8;
  gemb[i] = sums[i] / fmaxf(cnt[g], 1.f);
}

__global__ __launch_bounds__(256) void head_kernel(
    const float* __restrict__ z2, const float* __restrict__ w3,
    const float* __restrict__ b3, float* __restrict__ out)
{
  __shared__ float w[128];
  const int t = threadIdx.x;
  if (t < 128) w[t] = w3[t];
  __syncthreads();
  float s = 0.f;
  const float* row = z2 + (size_t)t * 128;
#pragma unroll 4
  for (int d = 0; d < 128; ++d) s = fmaf(row[d], w[d], s);
  out[t] = s + b3[0];
}

// ---------------------------------------------------------------------------
extern "C" void kernel_launch(void* const* d_in, const int* in_sizes, int n_in,
                              void* d_out, int out_size, void* d_ws, size_t ws_size,
                              hipStream_t stream)
{
  const float* x          = (const float*)d_in[0];
  const int*   edge_index = (const int*)d_in[1];
  const int*   batch      = (const int*)d_in[2];
  const float* edge_attr  = (const float*)d_in[3];
  const float* ne_w   = (const float*)d_in[4];
  const float* ne_b   = (const float*)d_in[5];
  const float* ne_ln_g = (const float*)d_in[6];
  const float* ne_ln_b = (const float*)d_in[7];
  const float* ee_w   = (const float*)d_in[8];
  const float* ee_b   = (const float*)d_in[9];
  const float* eps    = (const float*)d_in[10];
  const float* elin_w = (const float*)d_in[11];
  const float* gin_w1 = (const float*)d_in[12];
  const float* gin_w2 = (const float*)d_in[13];
  const float* attn_in_w  = (const float*)d_in[14];
  const float* attn_out_w = (const float*)d_in[15];
  const float* mlp_w1 = (const float*)d_in[16];
  const float* mlp_w2 = (const float*)d_in[17];
  const float* elin_b = (const float*)d_in[18];
  const float* gin_b1 = (const float*)d_in[19];
  const float* gin_b2 = (const float*)d_in[20];
  const float* attn_in_b  = (const float*)d_in[21];
  const float* attn_out_b = (const float*)d_in[22];
  const float* mlp_b1 = (const float*)d_in[23];
  const float* mlp_b2 = (const float*)d_in[24];
  const float* gin_bn_g = (const float*)d_in[25];
  const float* ln1_g  = (const float*)d_in[26];
  const float* ln2_g  = (const float*)d_in[27];
  const float* ln3_g  = (const float*)d_in[28];
  const float* gin_bn_b = (const float*)d_in[29];
  const float* ln1_b  = (const float*)d_in[30];
  const float* ln2_b  = (const float*)d_in[31];
  const float* ln3_b  = (const float*)d_in[32];
  const float* cls_w1 = (const float*)d_in[33];
  const float* cls_b1 = (const float*)d_in[34];
  const float* cls_ln_g = (const float*)d_in[35];
  const float* cls_ln_b = (const float*)d_in[36];
  const float* cls_w2 = (const float*)d_in[37];
  const float* cls_b2 = (const float*)d_in[38];
  const float* cls_w3 = (const float*)d_in[39];
  const float* cls_b3 = (const float*)d_in[40];

  const int* src = edge_index;
  const int* dst = edge_index + N_EDGES;

  float* ws = (float*)d_ws;
  const size_t NC = (size_t)N_NODES * CH;       // 16,777,216
  float* h    = ws;
  float* bufA = ws + NC;
  float* bufB = ws + 2 * NC;
  float* bufC = ws + 3 * NC;
  float* bufQ = ws + 4 * NC;                    // qkv [N,768] / m1 [N,512] / EE pass buffer
  float* stats = bufQ + (size_t)N_NODES * 768;  // 4*512
  int* ideg  = (int*)(stats + 2048);            // 65536
  int* ifill = ideg + 65536;                    // 65536
  int* irow  = ifill + 65536;                   // 65537 (padded to 65544)
  int* ieid  = irow + 65544;                    // 524288
  unsigned short* pan = (unsigned short*)(ieid + 524288);  // bf16 panels
  // post-loop scratch reuses bufA (dead after last layer):
  float* sums = bufA;
  float* cnt  = bufA + 65536;
  float* gemb = bufA + 65792;
  float* z1   = bufA + 131328;
  float* z2   = bufA + 196864;

  const dim3 blk(256);
  const size_t PL = 720896;  // panel elems per layer (incl elin_w)

  // ---- CSR build + weight bf16 panelization (once) ----
  hipMemsetAsync(stats, 0, 2048 * sizeof(float), stream);
  hipMemsetAsync(ideg, 0, 65536 * sizeof(int), stream);
  hist_kernel<<<dim3(2048), blk, 0, stream>>>(dst, ideg);
  scan_kernel<<<dim3(1), blk, 0, stream>>>(ideg, irow, ifill);
  scatter_kernel<<<dim3(2048), blk, 0, stream>>>(dst, ifill, ieid);
  for (int l = 0; l < 4; ++l) {
    unsigned short* p = pan + l * PL;
    wcvt_kernel<<<dim3(256), blk, 0, stream>>>(gin_w1 + (size_t)l * 65536, p, 256, 256, 0);
    wcvt_kernel<<<dim3(256), blk, 0, stream>>>(gin_w2 + (size_t)l * 65536, p + 65536, 256, 256, 0);
    wcvt_kernel<<<dim3(768), blk, 0, stream>>>(attn_in_w + (size_t)l * 196608, p + 131072, 256, 768, 1);
    wcvt_kernel<<<dim3(256), blk, 0, stream>>>(attn_out_w + (size_t)l * 65536, p + 327680, 256, 256, 1);
    wcvt_kernel<<<dim3(512), blk, 0, stream>>>(mlp_w1 + (size_t)l * 131072, p + 393216, 256, 512, 0);
    wcvt_kernel<<<dim3(512), blk, 0, stream>>>(mlp_w2 + (size_t)l * 131072, p + 524288, 512, 256, 0);
    wcvt_kernel<<<dim3(256), blk, 0, stream>>>(elin_w + (size_t)l * 65536, p + 655360, 256, 256, 0);
  }

  // ---- encoders (K=771: stays fp32) ----
  gemm_kernel<false, false><<<dim3(2, 512), blk, 0, stream>>>(
      x, ne_w, ne_b, bufB, N_NODES, 256, 771);
  ln_kernel<<<dim3(N_NODES), blk, 0, stream>>>(bufB, nullptr, ne_ln_g, ne_ln_b, h, 1);

  for (int l = 0; l < 4; ++l) {
    unsigned short* p = pan + l * PL;
    // ---- GINEConv: 4 node-range passes of (edge GEMM -> scatter) ----
    for (int q = 0; q < 4; ++q) {
      eegemm_kernel<<<dim3(2, 1056), blk, 0, stream>>>(
          edge_attr, ieid, irow, q * 16384, ee_w, ee_b,
          p + 655360, elin_b + l * 256, bufQ);
      gscat_kernel<<<dim3(1024), blk, 0, stream>>>(
          bufQ, src, dst, irow, ieid, q * 16384, h, eps, l, bufA);
    }
    mgemm_kernel<false><<<dim3(2, 512), blk, 0, stream>>>(
        bufA, p, gin_b1 + l * 256, bufB, N_NODES, 256, 256);
    bn_stats_kernel<<<dim3(1024), blk, 0, stream>>>(bufB, stats + l * 512);
    bn_apply_kernel<<<dim3(16384), blk, 0, stream>>>(
        bufB, stats + l * 512, gin_bn_g + l * 256, gin_bn_b + l * 256);
    mgemm_kernel<false><<<dim3(2, 512), blk, 0, stream>>>(
        bufB, p + 65536, gin_b2 + l * 256, bufC, N_NODES, 256, 256);
    ln_kernel<<<dim3(N_NODES), blk, 0, stream>>>(
        bufC, h, ln1_g + l * 256, ln1_b + l * 256, bufC, 0);
    // ---- attention ----
    mgemm_kernel<false><<<dim3(6, 512), blk, 0, stream>>>(
        h, p + 131072, attn_in_b + l * 768, bufQ, N_NODES, 768, 256);
    mattn_kernel<<<dim3(1024), blk, 0, stream>>>(bufQ, bufA);
    mgemm_kernel<false><<<dim3(2, 512), blk, 0, stream>>>(
        bufA, p + 327680, attn_out_b + l * 256, bufB, N_NODES, 256, 256);
    ln_kernel<<<dim3(N_NODES), blk, 0, stream>>>(
        bufB, h, ln2_g + l * 256, ln2_b + l * 256, bufB, 0);
    // ---- FFN ----
    add_kernel<<<dim3(16384), blk, 0, stream>>>(bufC, bufB, bufB);
    mgemm_kernel<true><<<dim3(4, 512), blk, 0, stream>>>(
        bufB, p + 393216, mlp_b1 + l * 512, bufQ, N_NODES, 512, 256);
    mgemm_kernel<false><<<dim3(2, 512), blk, 0, stream>>>(
        bufQ, p + 524288, mlp_b2 + l * 256, bufC, N_NODES, 256, 512);
    ln_kernel<<<dim3(N_NODES), blk, 0, stream>>>(
        bufC, bufB, ln3_g + l * 256, ln3_b + l * 256, h, 0);
  }

  // ---- pooling + classifier ----
  hipMemsetAsync(sums, 0, 65792 * sizeof(float), stream);
  pool_kernel<<<dim3(256), blk, 0, stream>>>(h, batch, sums, cnt);
  gemb_kernel<<<dim3(256), blk, 0, stream>>>(sums, cnt, gemb);
  gemm_kernel<false, false><<<dim3(2, 2), blk, 0, stream>>>(
      gemb, cls_w1, cls_b1, z1, 256, 256, 256);
  ln_kernel<<<dim3(256), blk, 0, stream>>>(z1, nullptr, cls_ln_g, cls_ln_b, z1, 1);
  gemm_kernel<false, true><<<dim3(1, 2), blk, 0, stream>>>(
      z1, cls_w2, cls_b2, z2, 256, 128, 256);
  head_kernel<<<dim3(1), blk, 0, stream>>>(z2, cls_w3, cls_b3, (float*)d_out);
}

// Round 4
// 8438.844 us; speedup vs baseline: 1.6392x; 1.0190x over previous
//
#include <hip/hip_runtime.h>
#include <hip/hip_bf16.h>
#include <math.h>

#define N_NODES 65536
#define N_EDGES 524288
#define CH 256

#define FMA4(A4, S, W4) \
  A4.x = fmaf((S), (W4).x, A4.x); A4.y = fmaf((S), (W4).y, A4.y); \
  A4.z = fmaf((S), (W4).z, A4.z); A4.w = fmaf((S), (W4).w, A4.w)

typedef __bf16 bf16x8 __attribute__((ext_vector_type(8)));
typedef float f32x4 __attribute__((ext_vector_type(4)));

__device__ inline unsigned short bf16rn(float v) {
  unsigned int u = __float_as_uint(v);
  u = u + 0x7FFFu + ((u >> 16) & 1u);
  return (unsigned short)(u >> 16);
}

__device__ inline bf16x8 pack_bf16_8(const float4 a, const float4 b) {
  union { __hip_bfloat162 h2[4]; bf16x8 v; } r;
  r.h2[0] = __float22bfloat162_rn(make_float2(a.x, a.y));
  r.h2[1] = __float22bfloat162_rn(make_float2(a.z, a.w));
  r.h2[2] = __float22bfloat162_rn(make_float2(b.x, b.y));
  r.h2[3] = __float22bfloat162_rn(make_float2(b.z, b.w));
  return r.v;
}

// ---------------------------------------------------------------------------
// Weight pre-convert: fp32 W -> bf16 k-panel layout P[(k>>3)*N + n][k&7].
// transposed=1 means logical B[k][n] = W[n*K+k] (for reference's @ W.T GEMMs).
// ---------------------------------------------------------------------------
__global__ __launch_bounds__(256) void wcvt_kernel(
    const float* __restrict__ W, unsigned short* __restrict__ P,
    int K, int Nn, int transposed)
{
  const int idx = blockIdx.x * 256 + threadIdx.x;
  const int k = idx / Nn;
  const int n = idx - k * Nn;
  const float v = transposed ? W[(size_t)n * K + k] : W[(size_t)k * Nn + n];
  P[(((size_t)(k >> 3)) * Nn + n) * 8 + (k & 7)] = bf16rn(v);
}

// ---------------------------------------------------------------------------
// xcvt: x fp32 [65536,771] -> xs bf16 [65536,1568] = [hi(784-pad) | lo(784)].
// hi = bf16(x), lo = bf16(x - float(hi)); split-bf16 so x_hi@W + x_lo@W
// reproduces fp32-x precision (error reduced to weight rounding only).
// ---------------------------------------------------------------------------
__global__ __launch_bounds__(256) void xcvt_kernel(
    const float* __restrict__ x, unsigned short* __restrict__ xs)
{
  const int t = blockIdx.x * 256 + threadIdx.x;  // 65536*98 total
  const int row = t / 98;
  const int c = t - row * 98;
  const int k0 = c << 3;
  unsigned short hi[8], lo[8];
#pragma unroll
  for (int j = 0; j < 8; ++j) {
    const int k = k0 + j;
    const float v = (k < 771) ? x[(size_t)row * 771 + k] : 0.f;
    const unsigned short h16 = bf16rn(v);
    const float hf = __uint_as_float(((unsigned int)h16) << 16);
    hi[j] = h16;
    lo[j] = bf16rn(v - hf);
  }
  unsigned short* base = xs + (size_t)row * 1568 + k0;
  *(uint4*)base = *(const uint4*)hi;
  *(uint4*)(base + 784) = *(const uint4*)lo;
}

// ---------------------------------------------------------------------------
// LDS-free bf16 MFMA GEMM: C[M,N] = A[M,K] @ Bp + bias (+relu).
// Block = 4 waves arranged 1x4: 64 rows x 256 cols (A read Nn/256 times).
// ABF16: A already bf16 (row stride K, 16B-aligned); else fp32, packed
// on the fly. M%64==0, Nn%256==0, K%32==0.
// ---------------------------------------------------------------------------
template <bool RELU, bool ABF16>
__global__ __launch_bounds__(256, 3) void mgemm_kernel(
    const void* __restrict__ Av, const unsigned short* __restrict__ Bp,
    const float* __restrict__ bias, float* __restrict__ Cmat,
    int M, int Nn, int K)
{
  const int tid = threadIdx.x;
  const int lane = tid & 63;
  const int w = tid >> 6;
  const int m_base = blockIdx.y * 64;
  const int n_base = blockIdx.x * 256 + w * 64;
  const int lr = lane & 15;
  const int lq = lane >> 4;
  f32x4 acc[4][4];
#pragma unroll
  for (int i = 0; i < 4; ++i)
#pragma unroll
    for (int j = 0; j < 4; ++j) acc[i][j] = (f32x4){0.f, 0.f, 0.f, 0.f};

  for (int k0 = 0; k0 < K; k0 += 32) {
    const int ka = k0 + (lq << 3);
    bf16x8 af[4], bfv[4];
#pragma unroll
    for (int mt = 0; mt < 4; ++mt) {
      if (ABF16) {
        const unsigned short* ap =
            (const unsigned short*)Av + (size_t)(m_base + mt * 16 + lr) * K + ka;
        union { uint4 u; bf16x8 b; } au;
        au.u = *(const uint4*)ap;
        af[mt] = au.b;
      } else {
        const float* ap = (const float*)Av + (size_t)(m_base + mt * 16 + lr) * K + ka;
        af[mt] = pack_bf16_8(*(const float4*)ap, *(const float4*)(ap + 4));
      }
    }
#pragma unroll
    for (int nt = 0; nt < 4; ++nt) {
      const size_t off =
          (((size_t)(ka >> 3)) * Nn + (n_base + nt * 16 + lr)) << 3;
      union { uint4 u; bf16x8 b; } bu;
      bu.u = *(const uint4*)(Bp + off);
      bfv[nt] = bu.b;
    }
#pragma unroll
    for (int mt = 0; mt < 4; ++mt)
#pragma unroll
      for (int nt = 0; nt < 4; ++nt)
        acc[mt][nt] = __builtin_amdgcn_mfma_f32_16x16x32_bf16(
            af[mt], bfv[nt], acc[mt][nt], 0, 0, 0);
  }
#pragma unroll
  for (int nt = 0; nt < 4; ++nt) {
    const int col = n_base + nt * 16 + lr;
    const float bv = bias[col];
#pragma unroll
    for (int mt = 0; mt < 4; ++mt) {
      const int row0 = m_base + mt * 16 + (lq << 2);
#pragma unroll
      for (int r = 0; r < 4; ++r) {
        float v = acc[mt][nt][r] + bv;
        if (RELU) v = fmaxf(v, 0.f);
        Cmat[(size_t)(row0 + r) * Nn + col] = v;
      }
    }
  }
}

// ---------------------------------------------------------------------------
// eegemm: EE[slot,:] = relu(edge_attr[eid[slot]] @ ee_w + ee_b) @ elin_w
//         + elin_b, for sorted slots (pass-local). A-frags built on the fly
//         from 4 edge_attr scalars + enc weights in LDS.
// ---------------------------------------------------------------------------
__global__ __launch_bounds__(256, 3) void eegemm_kernel(
    const float* __restrict__ edge_attr,
    const int* __restrict__ eid_sorted,
    const int* __restrict__ row_ptr, int node_base,
    const float* __restrict__ ee_w, const float* __restrict__ ee_b,
    const unsigned short* __restrict__ elin_p, const float* __restrict__ elin_b,
    float* __restrict__ EE)
{
  __shared__ float wenc[4][256];
  __shared__ float benc[256];
  const int tid = threadIdx.x;
  const int slot_base = row_ptr[node_base];
  const int slot_end = row_ptr[node_base + 16384];
  const int m_rel = blockIdx.y * 128;
  if (slot_base + m_rel >= slot_end) return;  // block-uniform exit

  ((float4*)wenc)[tid] = ((const float4*)ee_w)[tid];
  if (tid < 64) ((float4*)benc)[tid] = ((const float4*)ee_b)[tid];
  __syncthreads();

  const int lane = tid & 63;
  const int w = tid >> 6;
  const int m_base = m_rel + (w >> 1) * 64;
  const int n_base = blockIdx.x * 128 + (w & 1) * 64;
  const int lr = lane & 15;
  const int lq = lane >> 4;

  float4 ea_r[4];
#pragma unroll
  for (int mt = 0; mt < 4; ++mt) {
    const int abs_slot = slot_base + m_base + mt * 16 + lr;
    if (abs_slot < slot_end) {
      const int e = eid_sorted[abs_slot];
      ea_r[mt] = *(const float4*)(edge_attr + ((size_t)e << 2));
    } else {
      ea_r[mt] = make_float4(0.f, 0.f, 0.f, 0.f);
    }
  }

  f32x4 acc[4][4];
#pragma unroll
  for (int i = 0; i < 4; ++i)
#pragma unroll
    for (int j = 0; j < 4; ++j) acc[i][j] = (f32x4){0.f, 0.f, 0.f, 0.f};

  for (int k0 = 0; k0 < 256; k0 += 32) {
    const int ka = k0 + (lq << 3);
    const float4 b0 = *(const float4*)&benc[ka];
    const float4 b1 = *(const float4*)&benc[ka + 4];
    float4 w0[4], w1[4];
#pragma unroll
    for (int j = 0; j < 4; ++j) {
      w0[j] = *(const float4*)&wenc[j][ka];
      w1[j] = *(const float4*)&wenc[j][ka + 4];
    }
    bf16x8 af[4], bfv[4];
#pragma unroll
    for (int mt = 0; mt < 4; ++mt) {
      float4 v0 = b0, v1 = b1;
      FMA4(v0, ea_r[mt].x, w0[0]); FMA4(v1, ea_r[mt].x, w1[0]);
      FMA4(v0, ea_r[mt].y, w0[1]); FMA4(v1, ea_r[mt].y, w1[1]);
      FMA4(v0, ea_r[mt].z, w0[2]); FMA4(v1, ea_r[mt].z, w1[2]);
      FMA4(v0, ea_r[mt].w, w0[3]); FMA4(v1, ea_r[mt].w, w1[3]);
      v0.x = fmaxf(v0.x, 0.f); v0.y = fmaxf(v0.y, 0.f);
      v0.z = fmaxf(v0.z, 0.f); v0.w = fmaxf(v0.w, 0.f);
      v1.x = fmaxf(v1.x, 0.f); v1.y = fmaxf(v1.y, 0.f);
      v1.z = fmaxf(v1.z, 0.f); v1.w = fmaxf(v1.w, 0.f);
      af[mt] = pack_bf16_8(v0, v1);
    }
#pragma unroll
    for (int nt = 0; nt < 4; ++nt) {
      const size_t off =
          (((size_t)(ka >> 3)) * 256 + (n_base + nt * 16 + lr)) << 3;
      union { uint4 u; bf16x8 b; } bu;
      bu.u = *(const uint4*)(elin_p + off);
      bfv[nt] = bu.b;
    }
#pragma unroll
    for (int mt = 0; mt < 4; ++mt)
#pragma unroll
      for (int nt = 0; nt < 4; ++nt)
        acc[mt][nt] = __builtin_amdgcn_mfma_f32_16x16x32_bf16(
            af[mt], bfv[nt], acc[mt][nt], 0, 0, 0);
  }

#pragma unroll
  for (int nt = 0; nt < 4; ++nt) {
    const int col = n_base + nt * 16 + lr;
    const float bv = elin_b[col];
#pragma unroll
    for (int mt = 0; mt < 4; ++mt) {
      const int row0 = m_base + mt * 16 + (lq << 2);
#pragma unroll
      for (int r = 0; r < 4; ++r) {
        if (slot_base + row0 + r < slot_end)
          EE[(size_t)(row0 + r) * 256 + col] = acc[mt][nt][r] + bv;
      }
    }
  }
}

// ---------------------------------------------------------------------------
// gscat: CSR-ordered scatter-aggregate.
// msg = relu(h[src] + EE[slot]); sum at dst; g1 = (1+eps)*h + aggr.
// ---------------------------------------------------------------------------
__global__ __launch_bounds__(256, 4) void gscat_kernel(
    const float* __restrict__ EE,
    const int* __restrict__ src_idx, const int* __restrict__ dst_idx,
    const int* __restrict__ row_ptr, const int* __restrict__ eid_sorted,
    int node_base,
    const float* __restrict__ h, const float* __restrict__ eps, int layer,
    float* __restrict__ g1)
{
  __shared__ float g_acc[16][256];
  __shared__ int si_s[64];
  __shared__ int sl_s[64];
  const int tid = threadIdx.x;
  const int n0 = node_base + (blockIdx.x << 4);
#pragma unroll
  for (int i = 0; i < 4; ++i)
    ((float4*)g_acc)[(i << 8) + tid] = make_float4(0.f, 0.f, 0.f, 0.f);
  const int slot_base = row_ptr[node_base];
  const int row_start = row_ptr[n0];
  const int row_end = row_ptr[n0 + 16];
  const int eg = (tid >> 6) << 4;
  const int cg = (tid & 63) << 2;

  for (int cs = row_start; cs < row_end; cs += 64) {
    __syncthreads();
    if (tid < 64) {
      const int slot = cs + tid;
      int s = 0, sl = -1;
      if (slot < row_end) {
        const int e = eid_sorted[slot];
        s = src_idx[e];
        sl = dst_idx[e] - n0;
      }
      si_s[tid] = s; sl_s[tid] = sl;
    }
    __syncthreads();
    const int er0 = cs - slot_base;
#pragma unroll
    for (int i = 0; i < 16; ++i) {
      const int li = eg + i;
      const int sl = sl_s[li];
      if (sl < 0) continue;
      const float4 e4 = *(const float4*)(EE + (size_t)(er0 + li) * 256 + cg);
      const float4 h4 = *(const float4*)(h + (((size_t)si_s[li]) << 8) + cg);
      atomicAdd(&g_acc[sl][cg + 0], fmaxf(h4.x + e4.x, 0.f));
      atomicAdd(&g_acc[sl][cg + 1], fmaxf(h4.y + e4.y, 0.f));
      atomicAdd(&g_acc[sl][cg + 2], fmaxf(h4.z + e4.z, 0.f));
      atomicAdd(&g_acc[sl][cg + 3], fmaxf(h4.w + e4.w, 0.f));
    }
  }
  __syncthreads();

  const float f = 1.f + eps[layer];
  const int row = tid >> 4;
  const int c0 = (tid & 15) << 4;
  const size_t nbase = (((size_t)(n0 + row)) << 8) + c0;
#pragma unroll
  for (int j = 0; j < 4; ++j) {
    const float4 hv = *(const float4*)(h + nbase + (j << 2));
    const float4 av = *(const float4*)&g_acc[row][c0 + (j << 2)];
    float4 o;
    o.x = fmaf(f, hv.x, av.x);
    o.y = fmaf(f, hv.y, av.y);
    o.z = fmaf(f, hv.z, av.z);
    o.w = fmaf(f, hv.w, av.w);
    *(float4*)(g1 + nbase + (j << 2)) = o;
  }
}

// ---------------------------------------------------------------------------
// fp32 tiled GEMM (kept for tiny classifier GEMMs).
// ---------------------------------------------------------------------------
template <bool BT, bool RELU>
__global__ __launch_bounds__(256, 4) void gemm_kernel(
    const float* __restrict__ A, const float* __restrict__ B,
    const float* __restrict__ bias, float* __restrict__ Cmat,
    int M, int Nn, int K)
{
  __shared__ float As[8][132];
  __shared__ float Bs[8][132];
  const int tid = threadIdx.x;
  const int bm = blockIdx.y * 128;
  const int bn = blockIdx.x * 128;
  const int tm = (tid >> 4) << 3;
  const int tn = (tid & 15) << 3;
  float acc[8][8];
#pragma unroll
  for (int i = 0; i < 8; ++i)
#pragma unroll
    for (int j = 0; j < 8; ++j) acc[i][j] = 0.f;

  const int nk = (K + 7) >> 3;
  const bool k4 = (K & 3) == 0;
  for (int kc = 0; kc < nk; ++kc) {
    const int k0 = kc << 3;
    {
      const int r = tid >> 1;
      const int kk = (tid & 1) << 2;
      const int gm = bm + r;
      float va[4] = {0.f, 0.f, 0.f, 0.f};
      if (gm < M) {
        const size_t base = (size_t)gm * K + k0 + kk;
        if (k4 && (k0 + kk + 4 <= K)) {
          const float4 v = *(const float4*)(A + base);
          va[0] = v.x; va[1] = v.y; va[2] = v.z; va[3] = v.w;
        } else {
#pragma unroll
          for (int j = 0; j < 4; ++j)
            if (k0 + kk + j < K) va[j] = A[base + j];
        }
      }
      As[kk + 0][r] = va[0]; As[kk + 1][r] = va[1];
      As[kk + 2][r] = va[2]; As[kk + 3][r] = va[3];
    }
    if (!BT) {
      const int r = tid >> 5;
      const int cb = (tid & 31) << 2;
      float4 v = make_float4(0.f, 0.f, 0.f, 0.f);
      if (k0 + r < K) v = *(const float4*)(B + (size_t)(k0 + r) * Nn + bn + cb);
      *(float4*)&Bs[r][cb] = v;
    } else {
      const int r = tid >> 1;
      const int kk = (tid & 1) << 2;
      float vb[4] = {0.f, 0.f, 0.f, 0.f};
      if (bn + r < Nn) {
        const size_t base = (size_t)(bn + r) * K + k0 + kk;
        if (k4 && (k0 + kk + 4 <= K)) {
          const float4 v = *(const float4*)(B + base);
          vb[0] = v.x; vb[1] = v.y; vb[2] = v.z; vb[3] = v.w;
        } else {
#pragma unroll
          for (int j = 0; j < 4; ++j)
            if (k0 + kk + j < K) vb[j] = B[base + j];
        }
      }
      Bs[kk + 0][r] = vb[0]; Bs[kk + 1][r] = vb[1];
      Bs[kk + 2][r] = vb[2]; Bs[kk + 3][r] = vb[3];
    }
    __syncthreads();
#pragma unroll
    for (int k = 0; k < 8; ++k) {
      const float4 a0 = *(const float4*)&As[k][tm];
      const float4 a1 = *(const float4*)&As[k][tm + 4];
      const float4 b0 = *(const float4*)&Bs[k][tn];
      const float4 b1 = *(const float4*)&Bs[k][tn + 4];
      const float av[8] = {a0.x, a0.y, a0.z, a0.w, a1.x, a1.y, a1.z, a1.w};
      const float bv[8] = {b0.x, b0.y, b0.z, b0.w, b1.x, b1.y, b1.z, b1.w};
#pragma unroll
      for (int i = 0; i < 8; ++i)
#pragma unroll
        for (int j = 0; j < 8; ++j)
          acc[i][j] = fmaf(av[i], bv[j], acc[i][j]);
    }
    __syncthreads();
  }
#pragma unroll
  for (int i = 0; i < 8; ++i) {
    const int gm = bm + tm + i;
    if (gm >= M) continue;
    float* crow = Cmat + (size_t)gm * Nn + bn + tn;
#pragma unroll
    for (int j = 0; j < 8; ++j) {
      const int gn = bn + tn + j;
      if (gn >= Nn) continue;
      float v = acc[i][j] + (bias ? bias[gn] : 0.f);
      if (RELU) v = fmaxf(v, 0.f);
      crow[j] = v;
    }
  }
}

// ---------------------------------------------------------------------------
// CSR build: histogram of dst -> exclusive scan -> scatter edge ids.
// ---------------------------------------------------------------------------
__global__ __launch_bounds__(256) void hist_kernel(
    const int* __restrict__ dst, int* __restrict__ deg)
{
  const int e = blockIdx.x * 256 + threadIdx.x;
  atomicAdd(&deg[dst[e]], 1);
}

__global__ __launch_bounds__(256) void scan_kernel(
    const int* __restrict__ deg, int* __restrict__ row_ptr,
    int* __restrict__ fill)
{
  __shared__ int part[256];
  const int t = threadIdx.x;
  const int base = t << 8;
  int s = 0;
  for (int j = 0; j < 256; ++j) s += deg[base + j];
  part[t] = s;
  __syncthreads();
  for (int off = 1; off < 256; off <<= 1) {
    int v = (t >= off) ? part[t - off] : 0;
    __syncthreads();
    part[t] += v;
    __syncthreads();
  }
  int run = (t == 0) ? 0 : part[t - 1];
  for (int j = 0; j < 256; ++j) {
    row_ptr[base + j] = run;
    fill[base + j] = run;
    run += deg[base + j];
  }
  if (t == 255) row_ptr[65536] = run;
}

__global__ __launch_bounds__(256) void scatter_kernel(
    const int* __restrict__ dst, int* __restrict__ fill,
    int* __restrict__ eid)
{
  const int e = blockIdx.x * 256 + threadIdx.x;
  const int pos = atomicAdd(&fill[dst[e]], 1);
  eid[pos] = e;
}

// ---------------------------------------------------------------------------
// MFMA attention, one block per (graph, head), 4 waves x 64 q-rows.
// Exact softmax over all 256 keys.
// ---------------------------------------------------------------------------
__global__ __launch_bounds__(256, 1) void mattn_kernel(
    const float* __restrict__ qkv, float* __restrict__ o)
{
  __shared__ __attribute__((aligned(16))) unsigned short Ks[256 * 72];
  __shared__ __attribute__((aligned(16))) unsigned short Vt[64 * 258];
  __shared__ __attribute__((aligned(16))) unsigned short Ps[4][64 * 72];
  const int tid = threadIdx.x;
  const int gh = blockIdx.x;
  const int g = gh >> 2;
  const int hh = gh & 3;
  const int lane = tid & 63;
  const int w = tid >> 6;
  const int lr = lane & 15;
  const int lq = lane >> 4;
  const float scale = 0.125f;

  // ---- stage K rows (bf16) and V^T (bf16) ----
  {
    const int key0 = tid >> 4;
    const int c0 = (tid & 15) << 2;
#pragma unroll
    for (int it = 0; it < 16; ++it) {
      const int key = it * 16 + key0;
      const float* base = qkv + ((size_t)(g * 256 + key)) * 768 + hh * 64 + c0;
      const float4 kv = *(const float4*)(base + 256);
      const float4 vv = *(const float4*)(base + 512);
      union { __hip_bfloat162 h2[2]; ushort4 u; } pk;
      pk.h2[0] = __float22bfloat162_rn(make_float2(kv.x, kv.y));
      pk.h2[1] = __float22bfloat162_rn(make_float2(kv.z, kv.w));
      *(ushort4*)&Ks[key * 72 + c0] = pk.u;
      Vt[(c0 + 0) * 258 + key] = bf16rn(vv.x);
      Vt[(c0 + 1) * 258 + key] = bf16rn(vv.y);
      Vt[(c0 + 2) * 258 + key] = bf16rn(vv.z);
      Vt[(c0 + 3) * 258 + key] = bf16rn(vv.w);
    }
  }

  // ---- Q fragments (pre-scaled by 1/8), kept in registers ----
  const int m0 = w * 64;
  bf16x8 qf[2][4];
#pragma unroll
  for (int ks = 0; ks < 2; ++ks)
#pragma unroll
    for (int mt = 0; mt < 4; ++mt) {
      const float* ap = qkv +
          ((size_t)(g * 256 + m0 + mt * 16 + lr)) * 768 + hh * 64 +
          ks * 32 + (lq << 3);
      float4 a = *(const float4*)ap;
      float4 b = *(const float4*)(ap + 4);
      a.x *= scale; a.y *= scale; a.z *= scale; a.w *= scale;
      b.x *= scale; b.y *= scale; b.z *= scale; b.w *= scale;
      qf[ks][mt] = pack_bf16_8(a, b);
    }
  __syncthreads();

  f32x4 oacc[4][4];
#pragma unroll
  for (int i = 0; i < 4; ++i)
#pragma unroll
    for (int j = 0; j < 4; ++j) oacc[i][j] = (f32x4){0.f, 0.f, 0.f, 0.f};
  float lpart[4][4];
#pragma unroll
  for (int i = 0; i < 4; ++i)
#pragma unroll
    for (int j = 0; j < 4; ++j) lpart[i][j] = 0.f;

  unsigned short* Pw = Ps[w];

  for (int kb = 0; kb < 4; ++kb) {
    // ---- S chunk = Q @ K^T (64 q x 64 keys) ----
    f32x4 sacc[4][4];
#pragma unroll
    for (int i = 0; i < 4; ++i)
#pragma unroll
      for (int j = 0; j < 4; ++j) sacc[i][j] = (f32x4){0.f, 0.f, 0.f, 0.f};
#pragma unroll
    for (int ks = 0; ks < 2; ++ks) {
      bf16x8 bfv[4];
#pragma unroll
      for (int nt = 0; nt < 4; ++nt) {
        union { uint4 u; bf16x8 b; } bu;
        bu.u = *(const uint4*)&Ks[(kb * 64 + nt * 16 + lr) * 72 +
                                  ks * 32 + (lq << 3)];
        bfv[nt] = bu.b;
      }
#pragma unroll
      for (int mt = 0; mt < 4; ++mt)
#pragma unroll
        for (int nt = 0; nt < 4; ++nt)
          sacc[mt][nt] = __builtin_amdgcn_mfma_f32_16x16x32_bf16(
              qf[ks][mt], bfv[nt], sacc[mt][nt], 0, 0, 0);
    }
    // ---- p = exp(s); accumulate row sums; write bf16 P chunk ----
#pragma unroll
    for (int mt = 0; mt < 4; ++mt)
#pragma unroll
      for (int nt = 0; nt < 4; ++nt) {
#pragma unroll
        for (int rr = 0; rr < 4; ++rr) {
          const float p = __expf(sacc[mt][nt][rr]);
          lpart[mt][rr] += p;
          Pw[(mt * 16 + (lq << 2) + rr) * 72 + nt * 16 + lr] = bf16rn(p);
        }
      }
    asm volatile("s_waitcnt lgkmcnt(0)" ::: "memory");
    __builtin_amdgcn_sched_barrier(0);
    // ---- O += P_chunk @ V_chunk ----
#pragma unroll
    for (int ks = 0; ks < 2; ++ks) {
      bf16x8 pa[4], vb[4];
#pragma unroll
      for (int mt = 0; mt < 4; ++mt) {
        union { uint4 u; bf16x8 b; } au;
        au.u = *(const uint4*)&Pw[(mt * 16 + lr) * 72 + ks * 32 + (lq << 3)];
        pa[mt] = au.b;
      }
#pragma unroll
      for (int nt = 0; nt < 4; ++nt) {
        const unsigned short* vp =
            &Vt[(nt * 16 + lr) * 258 + kb * 64 + ks * 32 + (lq << 3)];
        union { unsigned int u4[4]; bf16x8 b; } vu;
        vu.u4[0] = *(const unsigned int*)(vp + 0);
        vu.u4[1] = *(const unsigned int*)(vp + 2);
        vu.u4[2] = *(const unsigned int*)(vp + 4);
        vu.u4[3] = *(const unsigned int*)(vp + 6);
        vb[nt] = vu.b;
      }
#pragma unroll
      for (int mt = 0; mt < 4; ++mt)
#pragma unroll
        for (int nt = 0; nt < 4; ++nt)
          oacc[mt][nt] = __builtin_amdgcn_mfma_f32_16x16x32_bf16(
              pa[mt], vb[nt], oacc[mt][nt], 0, 0, 0);
    }
  }

  // ---- row sums -> 1/l (reduce across the 16 lr lanes) ----
#pragma unroll
  for (int mt = 0; mt < 4; ++mt)
#pragma unroll
    for (int rr = 0; rr < 4; ++rr) {
      float v = lpart[mt][rr];
      v += __shfl_xor(v, 1);
      v += __shfl_xor(v, 2);
      v += __shfl_xor(v, 4);
      v += __shfl_xor(v, 8);
      lpart[mt][rr] = 1.f / v;
    }

  // ---- normalize + store O ----
#pragma unroll
  for (int mt = 0; mt < 4; ++mt) {
#pragma unroll
    for (int nt = 0; nt < 4; ++nt) {
#pragma unroll
      for (int rr = 0; rr < 4; ++rr) {
        const int row = m0 + mt * 16 + (lq << 2) + rr;
        o[((size_t)(g * 256 + row)) * 256 + hh * 64 + nt * 16 + lr] =
            oacc[mt][nt][rr] * lpart[mt][rr];
      }
    }
  }
}

// ---------------------------------------------------------------------------
__global__ __launch_bounds__(256) void ln_kernel(
    const float* __restrict__ a, const float* __restrict__ res,
    const float* __restrict__ gam, const float* __restrict__ bet,
    float* __restrict__ out, int relu)
{
  __shared__ float2 red[256];
  const int t = threadIdx.x;
  const size_t base = (size_t)blockIdx.x * 256;
  float v = a[base + t];
  if (res) v += res[base + t];
  red[t] = make_float2(v, v * v);
  __syncthreads();
#pragma unroll
  for (int s = 128; s > 0; s >>= 1) {
    if (t < s) { red[t].x += red[t + s].x; red[t].y += red[t + s].y; }
    __syncthreads();
  }
  const float mu = red[0].x * (1.f / 256.f);
  const float var = red[0].y * (1.f / 256.f) - mu * mu;
  float r = (v - mu) * rsqrtf(var + 1e-5f) * gam[t] + bet[t];
  if (relu) r = fmaxf(r, 0.f);
  out[base + t] = r;
}

__global__ __launch_bounds__(256) void bn_stats_kernel(
    const float* __restrict__ y, float* __restrict__ stats)
{
  const int t = threadIdx.x;
  const size_t r0 = (size_t)blockIdx.x * 64;
  float s = 0.f, s2 = 0.f;
  for (int r = 0; r < 64; ++r) {
    const float v = y[(r0 + r) * 256 + t];
    s += v;
    s2 = fmaf(v, v, s2);
  }
  atomicAdd(&stats[t], s);
  atomicAdd(&stats[256 + t], s2);
}

__global__ __launch_bounds__(256) void bn_apply_kernel(
    float* __restrict__ y, const float* __restrict__ stats,
    const float* __restrict__ gam, const float* __restrict__ bet)
{
  const size_t i = ((size_t)blockIdx.x * 256 + threadIdx.x) << 2;
  const int c = (int)(i & 255);
  const float inv_n = 1.f / 65536.f;
  float4 v = *(float4*)(y + i);
  const float4 s4 = *(const float4*)(stats + c);
  const float4 q4 = *(const float4*)(stats + 256 + c);
  const float4 g4 = *(const float4*)(gam + c);
  const float4 b4 = *(const float4*)(bet + c);
  float mu, var, sc;
  mu = s4.x * inv_n; var = q4.x * inv_n - mu * mu; sc = g4.x * rsqrtf(var + 1e-5f);
  v.x = fmaxf((v.x - mu) * sc + b4.x, 0.f);
  mu = s4.y * inv_n; var = q4.y * inv_n - mu * mu; sc = g4.y * rsqrtf(var + 1e-5f);
  v.y = fmaxf((v.y - mu) * sc + b4.y, 0.f);
  mu = s4.z * inv_n; var = q4.z * inv_n - mu * mu; sc = g4.z * rsqrtf(var + 1e-5f);
  v.z = fmaxf((v.z - mu) * sc + b4.z, 0.f);
  mu = s4.w * inv_n; var = q4.w * inv_n - mu * mu; sc = g4.w * rsqrtf(var + 1e-5f);
  v.w = fmaxf((v.w - mu) * sc + b4.w, 0.f);
  *(float4*)(y + i) = v;
}

__global__ __launch_bounds__(256) void add_kernel(
    const float* __restrict__ a, const float* __restrict__ b,
    float* __restrict__ out)
{
  const size_t i = ((size_t)blockIdx.x * 256 + threadIdx.x) << 2;
  const float4 va = *(const float4*)(a + i);
  const float4 vb = *(const float4*)(b + i);
  float4 v;
  v.x = va.x + vb.x; v.y = va.y + vb.y; v.z = va.z + vb.z; v.w = va.w + vb.w;
  *(float4*)(out + i) = v;
}

__global__ __launch_bounds__(256) void pool_kernel(
    const float* __restrict__ h, const int* __restrict__ batch,
    float* __restrict__ sums, float* __restrict__ cnt)
{
  const int t = threadIdx.x;
  const int n0 = blockIdx.x * 256;
  float acc = 0.f, runc = 0.f;
  int cur = batch[n0];
  for (int r = 0; r < 256; ++r) {
    const int n = n0 + r;
    const int b = batch[n];
    if (b != cur) {
      atomicAdd(&sums[(size_t)cur * 256 + t], acc);
      if (t == 0) atomicAdd(&cnt[cur], runc);
      acc = 0.f; runc = 0.f; cur = b;
    }
    acc += h[(size_t)n * 256 + t];
    runc += 1.f;
  }
  atomicAdd(&sums[(size_t)cur * 256 + t], acc);
  if (t == 0) atomicAdd(&cnt[cur], runc);
}

__global__ __launch_bounds__(256) void gemb_kernel(
    const float* __restrict__ sums, const float* __restrict__ cnt,
    float* __restrict__ gemb)
{
  const int i = blockIdx.x * 256 + threadIdx.x;
  const int g = i >> 8;
  gemb[i] = sums[i] / fmaxf(cnt[g], 1.f);
}

__global__ __launch_bounds__(256) void head_kernel(
    const float* __restrict__ z2, const float* __restrict__ w3,
    const float* __restrict__ b3, float* __restrict__ out)
{
  __shared__ float w[128];
  const int t = threadIdx.x;
  if (t < 128) w[t] = w3[t];
  __syncthreads();
  float s = 0.f;
  const float* row = z2 + (size_t)t * 128;
#pragma unroll 4
  for (int d = 0; d < 128; ++d) s = fmaf(row[d], w[d], s);
  out[t] = s + b3[0];
}

// ---------------------------------------------------------------------------
extern "C" void kernel_launch(void* const* d_in, const int* in_sizes, int n_in,
                              void* d_out, int out_size, void* d_ws, size_t ws_size,
                              hipStream_t stream)
{
  const float* x          = (const float*)d_in[0];
  const int*   edge_index = (const int*)d_in[1];
  const int*   batch      = (const int*)d_in[2];
  const float* edge_attr  = (const float*)d_in[3];
  const float* ne_w   = (const float*)d_in[4];
  const float* ne_b   = (const float*)d_in[5];
  const float* ne_ln_g = (const float*)d_in[6];
  const float* ne_ln_b = (const float*)d_in[7];
  const float* ee_w   = (const float*)d_in[8];
  const float* ee_b   = (const float*)d_in[9];
  const float* eps    = (const float*)d_in[10];
  const float* elin_w = (const float*)d_in[11];
  const float* gin_w1 = (const float*)d_in[12];
  const float* gin_w2 = (const float*)d_in[13];
  const float* attn_in_w  = (const float*)d_in[14];
  const float* attn_out_w = (const float*)d_in[15];
  const float* mlp_w1 = (const float*)d_in[16];
  const float* mlp_w2 = (const float*)d_in[17];
  const float* elin_b = (const float*)d_in[18];
  const float* gin_b1 = (const float*)d_in[19];
  const float* gin_b2 = (const float*)d_in[20];
  const float* attn_in_b  = (const float*)d_in[21];
  const float* attn_out_b = (const float*)d_in[22];
  const float* mlp_b1 = (const float*)d_in[23];
  const float* mlp_b2 = (const float*)d_in[24];
  const float* gin_bn_g = (const float*)d_in[25];
  const float* ln1_g  = (const float*)d_in[26];
  const float* ln2_g  = (const float*)d_in[27];
  const float* ln3_g  = (const float*)d_in[28];
  const float* gin_bn_b = (const float*)d_in[29];
  const float* ln1_b  = (const float*)d_in[30];
  const float* ln2_b  = (const float*)d_in[31];
  const float* ln3_b  = (const float*)d_in[32];
  const float* cls_w1 = (const float*)d_in[33];
  const float* cls_b1 = (const float*)d_in[34];
  const float* cls_ln_g = (const float*)d_in[35];
  const float* cls_ln_b = (const float*)d_in[36];
  const float* cls_w2 = (const float*)d_in[37];
  const float* cls_b2 = (const float*)d_in[38];
  const float* cls_w3 = (const float*)d_in[39];
  const float* cls_b3 = (const float*)d_in[40];

  const int* src = edge_index;
  const int* dst = edge_index + N_EDGES;

  float* ws = (float*)d_ws;
  const size_t NC = (size_t)N_NODES * CH;       // 16,777,216
  float* h    = ws;
  float* bufA = ws + NC;
  float* bufB = ws + 2 * NC;
  float* bufC = ws + 3 * NC;
  float* bufQ = ws + 4 * NC;                    // qkv [N,768] / m1 [N,512] / EE pass buffer
  float* stats = bufQ + (size_t)N_NODES * 768;  // 4*512
  int* ideg  = (int*)(stats + 2048);            // 65536
  int* ifill = ideg + 65536;                    // 65536
  int* irow  = ifill + 65536;                   // 65537 (padded to 65544)
  int* ieid  = irow + 65544;                    // 524288
  unsigned short* pan = (unsigned short*)(ieid + 524288);  // bf16 panels
  // encoder split-bf16 x buffer: reuses bufC+bufQ (dead before layer loop)
  unsigned short* xs = (unsigned short*)bufC;   // [65536][1568] bf16 = 205 MB
  // post-loop scratch reuses bufA (dead after last layer):
  float* sums = bufA;
  float* cnt  = bufA + 65536;
  float* gemb = bufA + 65792;
  float* z1   = bufA + 131328;
  float* z2   = bufA + 196864;

  const dim3 blk(256);
  const size_t PL = 720896;        // panel elems per layer (incl elin_w)
  unsigned short* panNE = pan + 4 * PL;  // [1568/8 groups][256][8] = 401,408

  // ---- CSR build + weight bf16 panelization (once) ----
  hipMemsetAsync(stats, 0, 2048 * sizeof(float), stream);
  hipMemsetAsync(ideg, 0, 65536 * sizeof(int), stream);
  hipMemsetAsync(panNE, 0, 401408 * sizeof(unsigned short), stream);
  hist_kernel<<<dim3(2048), blk, 0, stream>>>(dst, ideg);
  scan_kernel<<<dim3(1), blk, 0, stream>>>(ideg, irow, ifill);
  scatter_kernel<<<dim3(2048), blk, 0, stream>>>(dst, ifill, ieid);
  for (int l = 0; l < 4; ++l) {
    unsigned short* p = pan + l * PL;
    wcvt_kernel<<<dim3(256), blk, 0, stream>>>(gin_w1 + (size_t)l * 65536, p, 256, 256, 0);
    wcvt_kernel<<<dim3(256), blk, 0, stream>>>(gin_w2 + (size_t)l * 65536, p + 65536, 256, 256, 0);
    wcvt_kernel<<<dim3(768), blk, 0, stream>>>(attn_in_w + (size_t)l * 196608, p + 131072, 256, 768, 1);
    wcvt_kernel<<<dim3(256), blk, 0, stream>>>(attn_out_w + (size_t)l * 65536, p + 327680, 256, 256, 1);
    wcvt_kernel<<<dim3(512), blk, 0, stream>>>(mlp_w1 + (size_t)l * 131072, p + 393216, 256, 512, 0);
    wcvt_kernel<<<dim3(512), blk, 0, stream>>>(mlp_w2 + (size_t)l * 131072, p + 524288, 512, 256, 0);
    wcvt_kernel<<<dim3(256), blk, 0, stream>>>(elin_w + (size_t)l * 65536, p + 655360, 256, 256, 0);
  }
  // ne_w panel twice (K rows 0..770 and 784..1554): hi and lo halves share W
  wcvt_kernel<<<dim3(771), blk, 0, stream>>>(ne_w, panNE, 771, 256, 0);
  wcvt_kernel<<<dim3(771), blk, 0, stream>>>(ne_w, panNE + (size_t)98 * 256 * 8, 771, 256, 0);

  // ---- encoder: split-bf16 x, then MFMA GEMM (K=1568 = hi|lo) ----
  xcvt_kernel<<<dim3(25088), blk, 0, stream>>>(x, xs);
  mgemm_kernel<false, true><<<dim3(1, 1024), blk, 0, stream>>>(
      xs, panNE, ne_b, bufB, N_NODES, 256, 1568);
  ln_kernel<<<dim3(N_NODES), blk, 0, stream>>>(bufB, nullptr, ne_ln_g, ne_ln_b, h, 1);

  for (int l = 0; l < 4; ++l) {
    unsigned short* p = pan + l * PL;
    // ---- GINEConv: 4 node-range passes of (edge GEMM -> scatter) ----
    for (int q = 0; q < 4; ++q) {
      eegemm_kernel<<<dim3(2, 1056), blk, 0, stream>>>(
          edge_attr, ieid, irow, q * 16384, ee_w, ee_b,
          p + 655360, elin_b + l * 256, bufQ);
      gscat_kernel<<<dim3(1024), blk, 0, stream>>>(
          bufQ, src, dst, irow, ieid, q * 16384, h, eps, l, bufA);
    }
    mgemm_kernel<false, false><<<dim3(1, 1024), blk, 0, stream>>>(
        bufA, p, gin_b1 + l * 256, bufB, N_NODES, 256, 256);
    bn_stats_kernel<<<dim3(1024), blk, 0, stream>>>(bufB, stats + l * 512);
    bn_apply_kernel<<<dim3(16384), blk, 0, stream>>>(
        bufB, stats + l * 512, gin_bn_g + l * 256, gin_bn_b + l * 256);
    mgemm_kernel<false, false><<<dim3(1, 1024), blk, 0, stream>>>(
        bufB, p + 65536, gin_b2 + l * 256, bufC, N_NODES, 256, 256);
    ln_kernel<<<dim3(N_NODES), blk, 0, stream>>>(
        bufC, h, ln1_g + l * 256, ln1_b + l * 256, bufC, 0);
    // ---- attention ----
    mgemm_kernel<false, false><<<dim3(3, 1024), blk, 0, stream>>>(
        h, p + 131072, attn_in_b + l * 768, bufQ, N_NODES, 768, 256);
    mattn_kernel<<<dim3(1024), blk, 0, stream>>>(bufQ, bufA);
    mgemm_kernel<false, false><<<dim3(1, 1024), blk, 0, stream>>>(
        bufA, p + 327680, attn_out_b + l * 256, bufB, N_NODES, 256, 256);
    ln_kernel<<<dim3(N_NODES), blk, 0, stream>>>(
        bufB, h, ln2_g + l * 256, ln2_b + l * 256, bufB, 0);
    // ---- FFN ----
    add_kernel<<<dim3(16384), blk, 0, stream>>>(bufC, bufB, bufB);
    mgemm_kernel<true, false><<<dim3(2, 1024), blk, 0, stream>>>(
        bufB, p + 393216, mlp_b1 + l * 512, bufQ, N_NODES, 512, 256);
    mgemm_kernel<false, false><<<dim3(1, 1024), blk, 0, stream>>>(
        bufQ, p + 524288, mlp_b2 + l * 256, bufC, N_NODES, 256, 512);
    ln_kernel<<<dim3(N_NODES), blk, 0, stream>>>(
        bufC, bufB, ln3_g + l * 256, ln3_b + l * 256, h, 0);
  }

  // ---- pooling + classifier ----
  hipMemsetAsync(sums, 0, 65792 * sizeof(float), stream);
  pool_kernel<<<dim3(256), blk, 0, stream>>>(h, batch, sums, cnt);
  gemb_kernel<<<dim3(256), blk, 0, stream>>>(sums, cnt, gemb);
  gemm_kernel<false, false><<<dim3(2, 2), blk, 0, stream>>>(
      gemb, cls_w1, cls_b1, z1, 256, 256, 256);
  ln_kernel<<<dim3(256), blk, 0, stream>>>(z1, nullptr, cls_ln_g, cls_ln_b, z1, 1);
  gemm_kernel<false, true><<<dim3(1, 2), blk, 0, stream>>>(
      z1, cls_w2, cls_b2, z2, 256, 128, 256);
  head_kernel<<<dim3(1), blk, 0, stream>>>(z2, cls_w3, cls_b3, (float*)d_out);
}

// Round 5
// 6039.892 us; speedup vs baseline: 2.2902x; 1.3972x over previous
//
#include <hip/hip_runtime.h>
#include <hip/hip_bf16.h>
#include <math.h>

#define N_NODES 65536
#define N_EDGES 524288
#define CH 256

#define FMA4(A4, S, W4) \
  A4.x = fmaf((S), (W4).x, A4.x); A4.y = fmaf((S), (W4).y, A4.y); \
  A4.z = fmaf((S), (W4).z, A4.z); A4.w = fmaf((S), (W4).w, A4.w)

typedef __bf16 bf16x8 __attribute__((ext_vector_type(8)));
typedef float f32x4 __attribute__((ext_vector_type(4)));

__device__ inline unsigned short bf16rn(float v) {
  unsigned int u = __float_as_uint(v);
  u = u + 0x7FFFu + ((u >> 16) & 1u);
  return (unsigned short)(u >> 16);
}

__device__ inline bf16x8 pack_bf16_8(const float4 a, const float4 b) {
  union { __hip_bfloat162 h2[4]; bf16x8 v; } r;
  r.h2[0] = __float22bfloat162_rn(make_float2(a.x, a.y));
  r.h2[1] = __float22bfloat162_rn(make_float2(a.z, a.w));
  r.h2[2] = __float22bfloat162_rn(make_float2(b.x, b.y));
  r.h2[3] = __float22bfloat162_rn(make_float2(b.z, b.w));
  return r.v;
}

// ---------------------------------------------------------------------------
// Weight pre-convert: fp32 W -> bf16 k-panel layout P[(k>>3)*N + n][k&7].
// transposed=1 means logical B[k][n] = W[n*K+k] (for reference's @ W.T GEMMs).
// ---------------------------------------------------------------------------
__global__ __launch_bounds__(256) void wcvt_kernel(
    const float* __restrict__ W, unsigned short* __restrict__ P,
    int K, int Nn, int transposed)
{
  const int idx = blockIdx.x * 256 + threadIdx.x;
  const int k = idx / Nn;
  const int n = idx - k * Nn;
  const float v = transposed ? W[(size_t)n * K + k] : W[(size_t)k * Nn + n];
  P[(((size_t)(k >> 3)) * Nn + n) * 8 + (k & 7)] = bf16rn(v);
}

// ---------------------------------------------------------------------------
// xcvt: x fp32 [65536,771] -> xs bf16 [65536,1568] = [hi(784-pad) | lo(784)].
// hi = bf16(x), lo = bf16(x - float(hi)); split-bf16 so x_hi@W + x_lo@W
// reproduces fp32-x precision (error reduced to weight rounding only).
// ---------------------------------------------------------------------------
__global__ __launch_bounds__(256) void xcvt_kernel(
    const float* __restrict__ x, unsigned short* __restrict__ xs)
{
  const int t = blockIdx.x * 256 + threadIdx.x;  // 65536*98 total
  const int row = t / 98;
  const int c = t - row * 98;
  const int k0 = c << 3;
  unsigned short hi[8], lo[8];
#pragma unroll
  for (int j = 0; j < 8; ++j) {
    const int k = k0 + j;
    const float v = (k < 771) ? x[(size_t)row * 771 + k] : 0.f;
    const unsigned short h16 = bf16rn(v);
    const float hf = __uint_as_float(((unsigned int)h16) << 16);
    hi[j] = h16;
    lo[j] = bf16rn(v - hf);
  }
  unsigned short* base = xs + (size_t)row * 1568 + k0;
  *(uint4*)base = *(const uint4*)hi;
  *(uint4*)(base + 784) = *(const uint4*)lo;
}

// ---------------------------------------------------------------------------
// LDS-free bf16 MFMA GEMM: C[M,N] = A[M,K] @ Bp + bias (+relu).
// Block = 4 waves arranged 1x4: 64 rows x 256 cols (A read Nn/256 times).
// ---------------------------------------------------------------------------
template <bool RELU, bool ABF16>
__global__ __launch_bounds__(256, 3) void mgemm_kernel(
    const void* __restrict__ Av, const unsigned short* __restrict__ Bp,
    const float* __restrict__ bias, float* __restrict__ Cmat,
    int M, int Nn, int K)
{
  const int tid = threadIdx.x;
  const int lane = tid & 63;
  const int w = tid >> 6;
  const int m_base = blockIdx.y * 64;
  const int n_base = blockIdx.x * 256 + w * 64;
  const int lr = lane & 15;
  const int lq = lane >> 4;
  f32x4 acc[4][4];
#pragma unroll
  for (int i = 0; i < 4; ++i)
#pragma unroll
    for (int j = 0; j < 4; ++j) acc[i][j] = (f32x4){0.f, 0.f, 0.f, 0.f};

  for (int k0 = 0; k0 < K; k0 += 32) {
    const int ka = k0 + (lq << 3);
    bf16x8 af[4], bfv[4];
#pragma unroll
    for (int mt = 0; mt < 4; ++mt) {
      if (ABF16) {
        const unsigned short* ap =
            (const unsigned short*)Av + (size_t)(m_base + mt * 16 + lr) * K + ka;
        union { uint4 u; bf16x8 b; } au;
        au.u = *(const uint4*)ap;
        af[mt] = au.b;
      } else {
        const float* ap = (const float*)Av + (size_t)(m_base + mt * 16 + lr) * K + ka;
        af[mt] = pack_bf16_8(*(const float4*)ap, *(const float4*)(ap + 4));
      }
    }
#pragma unroll
    for (int nt = 0; nt < 4; ++nt) {
      const size_t off =
          (((size_t)(ka >> 3)) * Nn + (n_base + nt * 16 + lr)) << 3;
      union { uint4 u; bf16x8 b; } bu;
      bu.u = *(const uint4*)(Bp + off);
      bfv[nt] = bu.b;
    }
#pragma unroll
    for (int mt = 0; mt < 4; ++mt)
#pragma unroll
      for (int nt = 0; nt < 4; ++nt)
        acc[mt][nt] = __builtin_amdgcn_mfma_f32_16x16x32_bf16(
            af[mt], bfv[nt], acc[mt][nt], 0, 0, 0);
  }
#pragma unroll
  for (int nt = 0; nt < 4; ++nt) {
    const int col = n_base + nt * 16 + lr;
    const float bv = bias[col];
#pragma unroll
    for (int mt = 0; mt < 4; ++mt) {
      const int row0 = m_base + mt * 16 + (lq << 2);
#pragma unroll
      for (int r = 0; r < 4; ++r) {
        float v = acc[mt][nt][r] + bv;
        if (RELU) v = fmaxf(v, 0.f);
        Cmat[(size_t)(row0 + r) * Nn + col] = v;
      }
    }
  }
}

// ---------------------------------------------------------------------------
// eegemm: EE[slot,:] = relu(edge_attr[eid[slot]] @ ee_w + ee_b) @ elin_w
//         + elin_b, for sorted slots (pass-local). A-frags built on the fly
//         from 4 edge_attr scalars + enc weights in LDS.
// ---------------------------------------------------------------------------
__global__ __launch_bounds__(256, 3) void eegemm_kernel(
    const float* __restrict__ edge_attr,
    const int* __restrict__ eid_sorted,
    const int* __restrict__ row_ptr, int node_base,
    const float* __restrict__ ee_w, const float* __restrict__ ee_b,
    const unsigned short* __restrict__ elin_p, const float* __restrict__ elin_b,
    float* __restrict__ EE)
{
  __shared__ float wenc[4][256];
  __shared__ float benc[256];
  const int tid = threadIdx.x;
  const int slot_base = row_ptr[node_base];
  const int slot_end = row_ptr[node_base + 16384];
  const int m_rel = blockIdx.y * 128;
  if (slot_base + m_rel >= slot_end) return;  // block-uniform exit

  ((float4*)wenc)[tid] = ((const float4*)ee_w)[tid];
  if (tid < 64) ((float4*)benc)[tid] = ((const float4*)ee_b)[tid];
  __syncthreads();

  const int lane = tid & 63;
  const int w = tid >> 6;
  const int m_base = m_rel + (w >> 1) * 64;
  const int n_base = blockIdx.x * 128 + (w & 1) * 64;
  const int lr = lane & 15;
  const int lq = lane >> 4;

  float4 ea_r[4];
#pragma unroll
  for (int mt = 0; mt < 4; ++mt) {
    const int abs_slot = slot_base + m_base + mt * 16 + lr;
    if (abs_slot < slot_end) {
      const int e = eid_sorted[abs_slot];
      ea_r[mt] = *(const float4*)(edge_attr + ((size_t)e << 2));
    } else {
      ea_r[mt] = make_float4(0.f, 0.f, 0.f, 0.f);
    }
  }

  f32x4 acc[4][4];
#pragma unroll
  for (int i = 0; i < 4; ++i)
#pragma unroll
    for (int j = 0; j < 4; ++j) acc[i][j] = (f32x4){0.f, 0.f, 0.f, 0.f};

  for (int k0 = 0; k0 < 256; k0 += 32) {
    const int ka = k0 + (lq << 3);
    const float4 b0 = *(const float4*)&benc[ka];
    const float4 b1 = *(const float4*)&benc[ka + 4];
    float4 w0[4], w1[4];
#pragma unroll
    for (int j = 0; j < 4; ++j) {
      w0[j] = *(const float4*)&wenc[j][ka];
      w1[j] = *(const float4*)&wenc[j][ka + 4];
    }
    bf16x8 af[4], bfv[4];
#pragma unroll
    for (int mt = 0; mt < 4; ++mt) {
      float4 v0 = b0, v1 = b1;
      FMA4(v0, ea_r[mt].x, w0[0]); FMA4(v1, ea_r[mt].x, w1[0]);
      FMA4(v0, ea_r[mt].y, w0[1]); FMA4(v1, ea_r[mt].y, w1[1]);
      FMA4(v0, ea_r[mt].z, w0[2]); FMA4(v1, ea_r[mt].z, w1[2]);
      FMA4(v0, ea_r[mt].w, w0[3]); FMA4(v1, ea_r[mt].w, w1[3]);
      v0.x = fmaxf(v0.x, 0.f); v0.y = fmaxf(v0.y, 0.f);
      v0.z = fmaxf(v0.z, 0.f); v0.w = fmaxf(v0.w, 0.f);
      v1.x = fmaxf(v1.x, 0.f); v1.y = fmaxf(v1.y, 0.f);
      v1.z = fmaxf(v1.z, 0.f); v1.w = fmaxf(v1.w, 0.f);
      af[mt] = pack_bf16_8(v0, v1);
    }
#pragma unroll
    for (int nt = 0; nt < 4; ++nt) {
      const size_t off =
          (((size_t)(ka >> 3)) * 256 + (n_base + nt * 16 + lr)) << 3;
      union { uint4 u; bf16x8 b; } bu;
      bu.u = *(const uint4*)(elin_p + off);
      bfv[nt] = bu.b;
    }
#pragma unroll
    for (int mt = 0; mt < 4; ++mt)
#pragma unroll
      for (int nt = 0; nt < 4; ++nt)
        acc[mt][nt] = __builtin_amdgcn_mfma_f32_16x16x32_bf16(
            af[mt], bfv[nt], acc[mt][nt], 0, 0, 0);
  }

#pragma unroll
  for (int nt = 0; nt < 4; ++nt) {
    const int col = n_base + nt * 16 + lr;
    const float bv = elin_b[col];
#pragma unroll
    for (int mt = 0; mt < 4; ++mt) {
      const int row0 = m_base + mt * 16 + (lq << 2);
#pragma unroll
      for (int r = 0; r < 4; ++r) {
        if (slot_base + row0 + r < slot_end)
          EE[(size_t)(row0 + r) * 256 + col] = acc[mt][nt][r] + bv;
      }
    }
  }
}

// ---------------------------------------------------------------------------
// gscat2: atomic-free CSR aggregate. One WAVE per dst node (4 nodes/block);
// lane owns 4 columns; walks the node's dst-sorted slot range accumulating
// relu(h[src] + EE[slot]) in registers. 2-edge unroll for MLP.
// g1 = (1+eps)*h + aggr.
// ---------------------------------------------------------------------------
__global__ __launch_bounds__(256, 8) void gscat2_kernel(
    const float* __restrict__ EE,
    const int* __restrict__ src_sorted,
    const int* __restrict__ row_ptr, int node_base,
    const float* __restrict__ h, const float* __restrict__ eps, int layer,
    float* __restrict__ g1)
{
  const int tid = threadIdx.x;
  const int w = tid >> 6;
  const int lane = tid & 63;
  const int n = node_base + (blockIdx.x << 2) + w;
  const int cg = lane << 2;
  const int slot_base = row_ptr[node_base];
  const int row_start = row_ptr[n];
  const int row_end = row_ptr[n + 1];

  float4 acc0 = make_float4(0.f, 0.f, 0.f, 0.f);
  float4 acc1 = make_float4(0.f, 0.f, 0.f, 0.f);
  int slot = row_start;
  for (; slot + 2 <= row_end; slot += 2) {
    const int s0 = src_sorted[slot];
    const int s1 = src_sorted[slot + 1];
    const float4 e0 = *(const float4*)(EE + (size_t)(slot - slot_base) * 256 + cg);
    const float4 e1 = *(const float4*)(EE + (size_t)(slot + 1 - slot_base) * 256 + cg);
    const float4 h0 = *(const float4*)(h + (((size_t)s0) << 8) + cg);
    const float4 h1 = *(const float4*)(h + (((size_t)s1) << 8) + cg);
    acc0.x += fmaxf(h0.x + e0.x, 0.f);
    acc0.y += fmaxf(h0.y + e0.y, 0.f);
    acc0.z += fmaxf(h0.z + e0.z, 0.f);
    acc0.w += fmaxf(h0.w + e0.w, 0.f);
    acc1.x += fmaxf(h1.x + e1.x, 0.f);
    acc1.y += fmaxf(h1.y + e1.y, 0.f);
    acc1.z += fmaxf(h1.z + e1.z, 0.f);
    acc1.w += fmaxf(h1.w + e1.w, 0.f);
  }
  if (slot < row_end) {
    const int s0 = src_sorted[slot];
    const float4 e0 = *(const float4*)(EE + (size_t)(slot - slot_base) * 256 + cg);
    const float4 h0 = *(const float4*)(h + (((size_t)s0) << 8) + cg);
    acc0.x += fmaxf(h0.x + e0.x, 0.f);
    acc0.y += fmaxf(h0.y + e0.y, 0.f);
    acc0.z += fmaxf(h0.z + e0.z, 0.f);
    acc0.w += fmaxf(h0.w + e0.w, 0.f);
  }
  acc0.x += acc1.x; acc0.y += acc1.y; acc0.z += acc1.z; acc0.w += acc1.w;

  const float f = 1.f + eps[layer];
  const float4 hv = *(const float4*)(h + (((size_t)n) << 8) + cg);
  float4 o;
  o.x = fmaf(f, hv.x, acc0.x);
  o.y = fmaf(f, hv.y, acc0.y);
  o.z = fmaf(f, hv.z, acc0.z);
  o.w = fmaf(f, hv.w, acc0.w);
  *(float4*)(g1 + (((size_t)n) << 8) + cg) = o;
}

// ---------------------------------------------------------------------------
// fp32 tiled GEMM (kept for tiny classifier GEMMs).
// ---------------------------------------------------------------------------
template <bool BT, bool RELU>
__global__ __launch_bounds__(256, 4) void gemm_kernel(
    const float* __restrict__ A, const float* __restrict__ B,
    const float* __restrict__ bias, float* __restrict__ Cmat,
    int M, int Nn, int K)
{
  __shared__ float As[8][132];
  __shared__ float Bs[8][132];
  const int tid = threadIdx.x;
  const int bm = blockIdx.y * 128;
  const int bn = blockIdx.x * 128;
  const int tm = (tid >> 4) << 3;
  const int tn = (tid & 15) << 3;
  float acc[8][8];
#pragma unroll
  for (int i = 0; i < 8; ++i)
#pragma unroll
    for (int j = 0; j < 8; ++j) acc[i][j] = 0.f;

  const int nk = (K + 7) >> 3;
  const bool k4 = (K & 3) == 0;
  for (int kc = 0; kc < nk; ++kc) {
    const int k0 = kc << 3;
    {
      const int r = tid >> 1;
      const int kk = (tid & 1) << 2;
      const int gm = bm + r;
      float va[4] = {0.f, 0.f, 0.f, 0.f};
      if (gm < M) {
        const size_t base = (size_t)gm * K + k0 + kk;
        if (k4 && (k0 + kk + 4 <= K)) {
          const float4 v = *(const float4*)(A + base);
          va[0] = v.x; va[1] = v.y; va[2] = v.z; va[3] = v.w;
        } else {
#pragma unroll
          for (int j = 0; j < 4; ++j)
            if (k0 + kk + j < K) va[j] = A[base + j];
        }
      }
      As[kk + 0][r] = va[0]; As[kk + 1][r] = va[1];
      As[kk + 2][r] = va[2]; As[kk + 3][r] = va[3];
    }
    if (!BT) {
      const int r = tid >> 5;
      const int cb = (tid & 31) << 2;
      float4 v = make_float4(0.f, 0.f, 0.f, 0.f);
      if (k0 + r < K) v = *(const float4*)(B + (size_t)(k0 + r) * Nn + bn + cb);
      *(float4*)&Bs[r][cb] = v;
    } else {
      const int r = tid >> 1;
      const int kk = (tid & 1) << 2;
      float vb[4] = {0.f, 0.f, 0.f, 0.f};
      if (bn + r < Nn) {
        const size_t base = (size_t)(bn + r) * K + k0 + kk;
        if (k4 && (k0 + kk + 4 <= K)) {
          const float4 v = *(const float4*)(B + base);
          vb[0] = v.x; vb[1] = v.y; vb[2] = v.z; vb[3] = v.w;
        } else {
#pragma unroll
          for (int j = 0; j < 4; ++j)
            if (k0 + kk + j < K) vb[j] = B[base + j];
        }
      }
      Bs[kk + 0][r] = vb[0]; Bs[kk + 1][r] = vb[1];
      Bs[kk + 2][r] = vb[2]; Bs[kk + 3][r] = vb[3];
    }
    __syncthreads();
#pragma unroll
    for (int k = 0; k < 8; ++k) {
      const float4 a0 = *(const float4*)&As[k][tm];
      const float4 a1 = *(const float4*)&As[k][tm + 4];
      const float4 b0 = *(const float4*)&Bs[k][tn];
      const float4 b1 = *(const float4*)&Bs[k][tn + 4];
      const float av[8] = {a0.x, a0.y, a0.z, a0.w, a1.x, a1.y, a1.z, a1.w};
      const float bv[8] = {b0.x, b0.y, b0.z, b0.w, b1.x, b1.y, b1.z, b1.w};
#pragma unroll
      for (int i = 0; i < 8; ++i)
#pragma unroll
        for (int j = 0; j < 8; ++j)
          acc[i][j] = fmaf(av[i], bv[j], acc[i][j]);
    }
    __syncthreads();
  }
#pragma unroll
  for (int i = 0; i < 8; ++i) {
    const int gm = bm + tm + i;
    if (gm >= M) continue;
    float* crow = Cmat + (size_t)gm * Nn + bn + tn;
#pragma unroll
    for (int j = 0; j < 8; ++j) {
      const int gn = bn + tn + j;
      if (gn >= Nn) continue;
      float v = acc[i][j] + (bias ? bias[gn] : 0.f);
      if (RELU) v = fmaxf(v, 0.f);
      crow[j] = v;
    }
  }
}

// ---------------------------------------------------------------------------
// CSR build: histogram of dst -> exclusive scan -> scatter edge ids.
// ---------------------------------------------------------------------------
__global__ __launch_bounds__(256) void hist_kernel(
    const int* __restrict__ dst, int* __restrict__ deg)
{
  const int e = blockIdx.x * 256 + threadIdx.x;
  atomicAdd(&deg[dst[e]], 1);
}

__global__ __launch_bounds__(256) void scan_kernel(
    const int* __restrict__ deg, int* __restrict__ row_ptr,
    int* __restrict__ fill)
{
  __shared__ int part[256];
  const int t = threadIdx.x;
  const int base = t << 8;
  int s = 0;
  for (int j = 0; j < 256; ++j) s += deg[base + j];
  part[t] = s;
  __syncthreads();
  for (int off = 1; off < 256; off <<= 1) {
    int v = (t >= off) ? part[t - off] : 0;
    __syncthreads();
    part[t] += v;
    __syncthreads();
  }
  int run = (t == 0) ? 0 : part[t - 1];
  for (int j = 0; j < 256; ++j) {
    row_ptr[base + j] = run;
    fill[base + j] = run;
    run += deg[base + j];
  }
  if (t == 255) row_ptr[65536] = run;
}

__global__ __launch_bounds__(256) void scatter_kernel(
    const int* __restrict__ dst, const int* __restrict__ src,
    int* __restrict__ fill, int* __restrict__ eid, int* __restrict__ ssrc)
{
  const int e = blockIdx.x * 256 + threadIdx.x;
  const int pos = atomicAdd(&fill[dst[e]], 1);
  eid[pos] = e;
  ssrc[pos] = src[e];
}

// ---------------------------------------------------------------------------
// MFMA attention, one block per (graph, head), 4 waves x 64 q-rows.
// Exact softmax over all 256 keys.
// ---------------------------------------------------------------------------
__global__ __launch_bounds__(256, 1) void mattn_kernel(
    const float* __restrict__ qkv, float* __restrict__ o)
{
  __shared__ __attribute__((aligned(16))) unsigned short Ks[256 * 72];
  __shared__ __attribute__((aligned(16))) unsigned short Vt[64 * 258];
  __shared__ __attribute__((aligned(16))) unsigned short Ps[4][64 * 72];
  const int tid = threadIdx.x;
  const int gh = blockIdx.x;
  const int g = gh >> 2;
  const int hh = gh & 3;
  const int lane = tid & 63;
  const int w = tid >> 6;
  const int lr = lane & 15;
  const int lq = lane >> 4;
  const float scale = 0.125f;

  // ---- stage K rows (bf16) and V^T (bf16) ----
  {
    const int key0 = tid >> 4;
    const int c0 = (tid & 15) << 2;
#pragma unroll
    for (int it = 0; it < 16; ++it) {
      const int key = it * 16 + key0;
      const float* base = qkv + ((size_t)(g * 256 + key)) * 768 + hh * 64 + c0;
      const float4 kv = *(const float4*)(base + 256);
      const float4 vv = *(const float4*)(base + 512);
      union { __hip_bfloat162 h2[2]; ushort4 u; } pk;
      pk.h2[0] = __float22bfloat162_rn(make_float2(kv.x, kv.y));
      pk.h2[1] = __float22bfloat162_rn(make_float2(kv.z, kv.w));
      *(ushort4*)&Ks[key * 72 + c0] = pk.u;
      Vt[(c0 + 0) * 258 + key] = bf16rn(vv.x);
      Vt[(c0 + 1) * 258 + key] = bf16rn(vv.y);
      Vt[(c0 + 2) * 258 + key] = bf16rn(vv.z);
      Vt[(c0 + 3) * 258 + key] = bf16rn(vv.w);
    }
  }

  // ---- Q fragments (pre-scaled by 1/8), kept in registers ----
  const int m0 = w * 64;
  bf16x8 qf[2][4];
#pragma unroll
  for (int ks = 0; ks < 2; ++ks)
#pragma unroll
    for (int mt = 0; mt < 4; ++mt) {
      const float* ap = qkv +
          ((size_t)(g * 256 + m0 + mt * 16 + lr)) * 768 + hh * 64 +
          ks * 32 + (lq << 3);
      float4 a = *(const float4*)ap;
      float4 b = *(const float4*)(ap + 4);
      a.x *= scale; a.y *= scale; a.z *= scale; a.w *= scale;
      b.x *= scale; b.y *= scale; b.z *= scale; b.w *= scale;
      qf[ks][mt] = pack_bf16_8(a, b);
    }
  __syncthreads();

  f32x4 oacc[4][4];
#pragma unroll
  for (int i = 0; i < 4; ++i)
#pragma unroll
    for (int j = 0; j < 4; ++j) oacc[i][j] = (f32x4){0.f, 0.f, 0.f, 0.f};
  float lpart[4][4];
#pragma unroll
  for (int i = 0; i < 4; ++i)
#pragma unroll
    for (int j = 0; j < 4; ++j) lpart[i][j] = 0.f;

  unsigned short* Pw = Ps[w];

  for (int kb = 0; kb < 4; ++kb) {
    // ---- S chunk = Q @ K^T (64 q x 64 keys) ----
    f32x4 sacc[4][4];
#pragma unroll
    for (int i = 0; i < 4; ++i)
#pragma unroll
      for (int j = 0; j < 4; ++j) sacc[i][j] = (f32x4){0.f, 0.f, 0.f, 0.f};
#pragma unroll
    for (int ks = 0; ks < 2; ++ks) {
      bf16x8 bfv[4];
#pragma unroll
      for (int nt = 0; nt < 4; ++nt) {
        union { uint4 u; bf16x8 b; } bu;
        bu.u = *(const uint4*)&Ks[(kb * 64 + nt * 16 + lr) * 72 +
                                  ks * 32 + (lq << 3)];
        bfv[nt] = bu.b;
      }
#pragma unroll
      for (int mt = 0; mt < 4; ++mt)
#pragma unroll
        for (int nt = 0; nt < 4; ++nt)
          sacc[mt][nt] = __builtin_amdgcn_mfma_f32_16x16x32_bf16(
              qf[ks][mt], bfv[nt], sacc[mt][nt], 0, 0, 0);
    }
    // ---- p = exp(s); accumulate row sums; write bf16 P chunk ----
#pragma unroll
    for (int mt = 0; mt < 4; ++mt)
#pragma unroll
      for (int nt = 0; nt < 4; ++nt) {
#pragma unroll
        for (int rr = 0; rr < 4; ++rr) {
          const float p = __expf(sacc[mt][nt][rr]);
          lpart[mt][rr] += p;
          Pw[(mt * 16 + (lq << 2) + rr) * 72 + nt * 16 + lr] = bf16rn(p);
        }
      }
    asm volatile("s_waitcnt lgkmcnt(0)" ::: "memory");
    __builtin_amdgcn_sched_barrier(0);
    // ---- O += P_chunk @ V_chunk ----
#pragma unroll
    for (int ks = 0; ks < 2; ++ks) {
      bf16x8 pa[4], vb[4];
#pragma unroll
      for (int mt = 0; mt < 4; ++mt) {
        union { uint4 u; bf16x8 b; } au;
        au.u = *(const uint4*)&Pw[(mt * 16 + lr) * 72 + ks * 32 + (lq << 3)];
        pa[mt] = au.b;
      }
#pragma unroll
      for (int nt = 0; nt < 4; ++nt) {
        const unsigned short* vp =
            &Vt[(nt * 16 + lr) * 258 + kb * 64 + ks * 32 + (lq << 3)];
        union { unsigned int u4[4]; bf16x8 b; } vu;
        vu.u4[0] = *(const unsigned int*)(vp + 0);
        vu.u4[1] = *(const unsigned int*)(vp + 2);
        vu.u4[2] = *(const unsigned int*)(vp + 4);
        vu.u4[3] = *(const unsigned int*)(vp + 6);
        vb[nt] = vu.b;
      }
#pragma unroll
      for (int mt = 0; mt < 4; ++mt)
#pragma unroll
        for (int nt = 0; nt < 4; ++nt)
          oacc[mt][nt] = __builtin_amdgcn_mfma_f32_16x16x32_bf16(
              pa[mt], vb[nt], oacc[mt][nt], 0, 0, 0);
    }
  }

  // ---- row sums -> 1/l (reduce across the 16 lr lanes) ----
#pragma unroll
  for (int mt = 0; mt < 4; ++mt)
#pragma unroll
    for (int rr = 0; rr < 4; ++rr) {
      float v = lpart[mt][rr];
      v += __shfl_xor(v, 1);
      v += __shfl_xor(v, 2);
      v += __shfl_xor(v, 4);
      v += __shfl_xor(v, 8);
      lpart[mt][rr] = 1.f / v;
    }

  // ---- normalize + store O ----
#pragma unroll
  for (int mt = 0; mt < 4; ++mt) {
#pragma unroll
    for (int nt = 0; nt < 4; ++nt) {
#pragma unroll
      for (int rr = 0; rr < 4; ++rr) {
        const int row = m0 + mt * 16 + (lq << 2) + rr;
        o[((size_t)(g * 256 + row)) * 256 + hh * 64 + nt * 16 + lr] =
            oacc[mt][nt][rr] * lpart[mt][rr];
      }
    }
  }
}

// ---------------------------------------------------------------------------
__global__ __launch_bounds__(256) void ln_kernel(
    const float* __restrict__ a, const float* __restrict__ res,
    const float* __restrict__ gam, const float* __restrict__ bet,
    float* __restrict__ out, int relu)
{
  __shared__ float2 red[256];
  const int t = threadIdx.x;
  const size_t base = (size_t)blockIdx.x * 256;
  float v = a[base + t];
  if (res) v += res[base + t];
  red[t] = make_float2(v, v * v);
  __syncthreads();
#pragma unroll
  for (int s = 128; s > 0; s >>= 1) {
    if (t < s) { red[t].x += red[t + s].x; red[t].y += red[t + s].y; }
    __syncthreads();
  }
  const float mu = red[0].x * (1.f / 256.f);
  const float var = red[0].y * (1.f / 256.f) - mu * mu;
  float r = (v - mu) * rsqrtf(var + 1e-5f) * gam[t] + bet[t];
  if (relu) r = fmaxf(r, 0.f);
  out[base + t] = r;
}

__global__ __launch_bounds__(256) void bn_stats_kernel(
    const float* __restrict__ y, float* __restrict__ stats)
{
  const int t = threadIdx.x;
  const size_t r0 = (size_t)blockIdx.x * 64;
  float s = 0.f, s2 = 0.f;
  for (int r = 0; r < 64; ++r) {
    const float v = y[(r0 + r) * 256 + t];
    s += v;
    s2 = fmaf(v, v, s2);
  }
  atomicAdd(&stats[t], s);
  atomicAdd(&stats[256 + t], s2);
}

__global__ __launch_bounds__(256) void bn_apply_kernel(
    float* __restrict__ y, const float* __restrict__ stats,
    const float* __restrict__ gam, const float* __restrict__ bet)
{
  const size_t i = ((size_t)blockIdx.x * 256 + threadIdx.x) << 2;
  const int c = (int)(i & 255);
  const float inv_n = 1.f / 65536.f;
  float4 v = *(float4*)(y + i);
  const float4 s4 = *(const float4*)(stats + c);
  const float4 q4 = *(const float4*)(stats + 256 + c);
  const float4 g4 = *(const float4*)(gam + c);
  const float4 b4 = *(const float4*)(bet + c);
  float mu, var, sc;
  mu = s4.x * inv_n; var = q4.x * inv_n - mu * mu; sc = g4.x * rsqrtf(var + 1e-5f);
  v.x = fmaxf((v.x - mu) * sc + b4.x, 0.f);
  mu = s4.y * inv_n; var = q4.y * inv_n - mu * mu; sc = g4.y * rsqrtf(var + 1e-5f);
  v.y = fmaxf((v.y - mu) * sc + b4.y, 0.f);
  mu = s4.z * inv_n; var = q4.z * inv_n - mu * mu; sc = g4.z * rsqrtf(var + 1e-5f);
  v.z = fmaxf((v.z - mu) * sc + b4.z, 0.f);
  mu = s4.w * inv_n; var = q4.w * inv_n - mu * mu; sc = g4.w * rsqrtf(var + 1e-5f);
  v.w = fmaxf((v.w - mu) * sc + b4.w, 0.f);
  *(float4*)(y + i) = v;
}

__global__ __launch_bounds__(256) void add_kernel(
    const float* __restrict__ a, const float* __restrict__ b,
    float* __restrict__ out)
{
  const size_t i = ((size_t)blockIdx.x * 256 + threadIdx.x) << 2;
  const float4 va = *(const float4*)(a + i);
  const float4 vb = *(const float4*)(b + i);
  float4 v;
  v.x = va.x + vb.x; v.y = va.y + vb.y; v.z = va.z + vb.z; v.w = va.w + vb.w;
  *(float4*)(out + i) = v;
}

__global__ __launch_bounds__(256) void pool_kernel(
    const float* __restrict__ h, const int* __restrict__ batch,
    float* __restrict__ sums, float* __restrict__ cnt)
{
  const int t = threadIdx.x;
  const int n0 = blockIdx.x * 256;
  float acc = 0.f, runc = 0.f;
  int cur = batch[n0];
  for (int r = 0; r < 256; ++r) {
    const int n = n0 + r;
    const int b = batch[n];
    if (b != cur) {
      atomicAdd(&sums[(size_t)cur * 256 + t], acc);
      if (t == 0) atomicAdd(&cnt[cur], runc);
      acc = 0.f; runc = 0.f; cur = b;
    }
    acc += h[(size_t)n * 256 + t];
    runc += 1.f;
  }
  atomicAdd(&sums[(size_t)cur * 256 + t], acc);
  if (t == 0) atomicAdd(&cnt[cur], runc);
}

__global__ __launch_bounds__(256) void gemb_kernel(
    const float* __restrict__ sums, const float* __restrict__ cnt,
    float* __restrict__ gemb)
{
  const int i = blockIdx.x * 256 + threadIdx.x;
  const int g = i >> 8;
  gemb[i] = sums[i] / fmaxf(cnt[g], 1.f);
}

__global__ __launch_bounds__(256) void head_kernel(
    const float* __restrict__ z2, const float* __restrict__ w3,
    const float* __restrict__ b3, float* __restrict__ out)
{
  __shared__ float w[128];
  const int t = threadIdx.x;
  if (t < 128) w[t] = w3[t];
  __syncthreads();
  float s = 0.f;
  const float* row = z2 + (size_t)t * 128;
#pragma unroll 4
  for (int d = 0; d < 128; ++d) s = fmaf(row[d], w[d], s);
  out[t] = s + b3[0];
}

// ---------------------------------------------------------------------------
extern "C" void kernel_launch(void* const* d_in, const int* in_sizes, int n_in,
                              void* d_out, int out_size, void* d_ws, size_t ws_size,
                              hipStream_t stream)
{
  const float* x          = (const float*)d_in[0];
  const int*   edge_index = (const int*)d_in[1];
  const int*   batch      = (const int*)d_in[2];
  const float* edge_attr  = (const float*)d_in[3];
  const float* ne_w   = (const float*)d_in[4];
  const float* ne_b   = (const float*)d_in[5];
  const float* ne_ln_g = (const float*)d_in[6];
  const float* ne_ln_b = (const float*)d_in[7];
  const float* ee_w   = (const float*)d_in[8];
  const float* ee_b   = (const float*)d_in[9];
  const float* eps    = (const float*)d_in[10];
  const float* elin_w = (const float*)d_in[11];
  const float* gin_w1 = (const float*)d_in[12];
  const float* gin_w2 = (const float*)d_in[13];
  const float* attn_in_w  = (const float*)d_in[14];
  const float* attn_out_w = (const float*)d_in[15];
  const float* mlp_w1 = (const float*)d_in[16];
  const float* mlp_w2 = (const float*)d_in[17];
  const float* elin_b = (const float*)d_in[18];
  const float* gin_b1 = (const float*)d_in[19];
  const float* gin_b2 = (const float*)d_in[20];
  const float* attn_in_b  = (const float*)d_in[21];
  const float* attn_out_b = (const float*)d_in[22];
  const float* mlp_b1 = (const float*)d_in[23];
  const float* mlp_b2 = (const float*)d_in[24];
  const float* gin_bn_g = (const float*)d_in[25];
  const float* ln1_g  = (const float*)d_in[26];
  const float* ln2_g  = (const float*)d_in[27];
  const float* ln3_g  = (const float*)d_in[28];
  const float* gin_bn_b = (const float*)d_in[29];
  const float* ln1_b  = (const float*)d_in[30];
  const float* ln2_b  = (const float*)d_in[31];
  const float* ln3_b  = (const float*)d_in[32];
  const float* cls_w1 = (const float*)d_in[33];
  const float* cls_b1 = (const float*)d_in[34];
  const float* cls_ln_g = (const float*)d_in[35];
  const float* cls_ln_b = (const float*)d_in[36];
  const float* cls_w2 = (const float*)d_in[37];
  const float* cls_b2 = (const float*)d_in[38];
  const float* cls_w3 = (const float*)d_in[39];
  const float* cls_b3 = (const float*)d_in[40];

  const int* src = edge_index;
  const int* dst = edge_index + N_EDGES;

  float* ws = (float*)d_ws;
  const size_t NC = (size_t)N_NODES * CH;       // 16,777,216
  float* h    = ws;
  float* bufA = ws + NC;
  float* bufB = ws + 2 * NC;
  float* bufC = ws + 3 * NC;
  float* bufQ = ws + 4 * NC;                    // qkv [N,768] / m1 [N,512] / EE pass buffer
  float* stats = bufQ + (size_t)N_NODES * 768;  // 4*512
  int* ideg  = (int*)(stats + 2048);            // 65536
  int* ifill = ideg + 65536;                    // 65536
  int* irow  = ifill + 65536;                   // 65537 (padded to 65544)
  int* ieid  = irow + 65544;                    // 524288
  int* issrc = ieid + 524288;                   // 524288 (src gathered in slot order)
  unsigned short* pan = (unsigned short*)(issrc + 524288);  // bf16 panels
  // encoder split-bf16 x buffer: reuses bufC+bufQ (dead before layer loop)
  unsigned short* xs = (unsigned short*)bufC;   // [65536][1568] bf16 = 205 MB
  // post-loop scratch reuses bufA (dead after last layer):
  float* sums = bufA;
  float* cnt  = bufA + 65536;
  float* gemb = bufA + 65792;
  float* z1   = bufA + 131328;
  float* z2   = bufA + 196864;

  const dim3 blk(256);
  const size_t PL = 720896;        // panel elems per layer (incl elin_w)
  unsigned short* panNE = pan + 4 * PL;  // [1568/8 groups][256][8] = 401,408

  // ---- CSR build + weight bf16 panelization (once) ----
  hipMemsetAsync(stats, 0, 2048 * sizeof(float), stream);
  hipMemsetAsync(ideg, 0, 65536 * sizeof(int), stream);
  hipMemsetAsync(panNE, 0, 401408 * sizeof(unsigned short), stream);
  hist_kernel<<<dim3(2048), blk, 0, stream>>>(dst, ideg);
  scan_kernel<<<dim3(1), blk, 0, stream>>>(ideg, irow, ifill);
  scatter_kernel<<<dim3(2048), blk, 0, stream>>>(dst, src, ifill, ieid, issrc);
  for (int l = 0; l < 4; ++l) {
    unsigned short* p = pan + l * PL;
    wcvt_kernel<<<dim3(256), blk, 0, stream>>>(gin_w1 + (size_t)l * 65536, p, 256, 256, 0);
    wcvt_kernel<<<dim3(256), blk, 0, stream>>>(gin_w2 + (size_t)l * 65536, p + 65536, 256, 256, 0);
    wcvt_kernel<<<dim3(768), blk, 0, stream>>>(attn_in_w + (size_t)l * 196608, p + 131072, 256, 768, 1);
    wcvt_kernel<<<dim3(256), blk, 0, stream>>>(attn_out_w + (size_t)l * 65536, p + 327680, 256, 256, 1);
    wcvt_kernel<<<dim3(512), blk, 0, stream>>>(mlp_w1 + (size_t)l * 131072, p + 393216, 256, 512, 0);
    wcvt_kernel<<<dim3(512), blk, 0, stream>>>(mlp_w2 + (size_t)l * 131072, p + 524288, 512, 256, 0);
    wcvt_kernel<<<dim3(256), blk, 0, stream>>>(elin_w + (size_t)l * 65536, p + 655360, 256, 256, 0);
  }
  // ne_w panel twice (K rows 0..770 and 784..1554): hi and lo halves share W
  wcvt_kernel<<<dim3(771), blk, 0, stream>>>(ne_w, panNE, 771, 256, 0);
  wcvt_kernel<<<dim3(771), blk, 0, stream>>>(ne_w, panNE + (size_t)98 * 256 * 8, 771, 256, 0);

  // ---- encoder: split-bf16 x, then MFMA GEMM (K=1568 = hi|lo) ----
  xcvt_kernel<<<dim3(25088), blk, 0, stream>>>(x, xs);
  mgemm_kernel<false, true><<<dim3(1, 1024), blk, 0, stream>>>(
      xs, panNE, ne_b, bufB, N_NODES, 256, 1568);
  ln_kernel<<<dim3(N_NODES), blk, 0, stream>>>(bufB, nullptr, ne_ln_g, ne_ln_b, h, 1);

  for (int l = 0; l < 4; ++l) {
    unsigned short* p = pan + l * PL;
    // ---- GINEConv: 4 node-range passes of (edge GEMM -> aggregate) ----
    for (int q = 0; q < 4; ++q) {
      eegemm_kernel<<<dim3(2, 1056), blk, 0, stream>>>(
          edge_attr, ieid, irow, q * 16384, ee_w, ee_b,
          p + 655360, elin_b + l * 256, bufQ);
      gscat2_kernel<<<dim3(4096), blk, 0, stream>>>(
          bufQ, issrc, irow, q * 16384, h, eps, l, bufA);
    }
    mgemm_kernel<false, false><<<dim3(1, 1024), blk, 0, stream>>>(
        bufA, p, gin_b1 + l * 256, bufB, N_NODES, 256, 256);
    bn_stats_kernel<<<dim3(1024), blk, 0, stream>>>(bufB, stats + l * 512);
    bn_apply_kernel<<<dim3(16384), blk, 0, stream>>>(
        bufB, stats + l * 512, gin_bn_g + l * 256, gin_bn_b + l * 256);
    mgemm_kernel<false, false><<<dim3(1, 1024), blk, 0, stream>>>(
        bufB, p + 65536, gin_b2 + l * 256, bufC, N_NODES, 256, 256);
    ln_kernel<<<dim3(N_NODES), blk, 0, stream>>>(
        bufC, h, ln1_g + l * 256, ln1_b + l * 256, bufC, 0);
    // ---- attention ----
    mgemm_kernel<false, false><<<dim3(3, 1024), blk, 0, stream>>>(
        h, p + 131072, attn_in_b + l * 768, bufQ, N_NODES, 768, 256);
    mattn_kernel<<<dim3(1024), blk, 0, stream>>>(bufQ, bufA);
    mgemm_kernel<false, false><<<dim3(1, 1024), blk, 0, stream>>>(
        bufA, p + 327680, attn_out_b + l * 256, bufB, N_NODES, 256, 256);
    ln_kernel<<<dim3(N_NODES), blk, 0, stream>>>(
        bufB, h, ln2_g + l * 256, ln2_b + l * 256, bufB, 0);
    // ---- FFN ----
    add_kernel<<<dim3(16384), blk, 0, stream>>>(bufC, bufB, bufB);
    mgemm_kernel<true, false><<<dim3(2, 1024), blk, 0, stream>>>(
        bufB, p + 393216, mlp_b1 + l * 512, bufQ, N_NODES, 512, 256);
    mgemm_kernel<false, false><<<dim3(1, 1024), blk, 0, stream>>>(
        bufQ, p + 524288, mlp_b2 + l * 256, bufC, N_NODES, 256, 512);
    ln_kernel<<<dim3(N_NODES), blk, 0, stream>>>(
        bufC, bufB, ln3_g + l * 256, ln3_b + l * 256, h, 0);
  }

  // ---- pooling + classifier ----
  hipMemsetAsync(sums, 0, 65792 * sizeof(float), stream);
  pool_kernel<<<dim3(256), blk, 0, stream>>>(h, batch, sums, cnt);
  gemb_kernel<<<dim3(256), blk, 0, stream>>>(sums, cnt, gemb);
  gemm_kernel<false, false><<<dim3(2, 2), blk, 0, stream>>>(
      gemb, cls_w1, cls_b1, z1, 256, 256, 256);
  ln_kernel<<<dim3(256), blk, 0, stream>>>(z1, nullptr, cls_ln_g, cls_ln_b, z1, 1);
  gemm_kernel<false, true><<<dim3(1, 2), blk, 0, stream>>>(
      z1, cls_w2, cls_b2, z2, 256, 128, 256);
  head_kernel<<<dim3(1), blk, 0, stream>>>(z2, cls_w3, cls_b3, (float*)d_out);
}

// Round 7
// 5063.033 us; speedup vs baseline: 2.7321x; 1.1929x over previous
//
#include <hip/hip_runtime.h>
#include <hip/hip_bf16.h>
#include <math.h>

#define N_NODES 65536
#define N_EDGES 524288
#define CH 256

#define FMA4(A4, S, W4) \
  A4.x = fmaf((S), (W4).x, A4.x); A4.y = fmaf((S), (W4).y, A4.y); \
  A4.z = fmaf((S), (W4).z, A4.z); A4.w = fmaf((S), (W4).w, A4.w)

typedef __bf16 bf16x8 __attribute__((ext_vector_type(8)));
typedef float f32x4 __attribute__((ext_vector_type(4)));

__device__ inline unsigned short bf16rn(float v) {
  unsigned int u = __float_as_uint(v);
  u = u + 0x7FFFu + ((u >> 16) & 1u);
  return (unsigned short)(u >> 16);
}

__device__ inline float bf2f(unsigned short u) {
  return __uint_as_float(((unsigned int)u) << 16);
}

__device__ inline ushort4 pack_bf16_4(const float4 a) {
  ushort4 r;
  r.x = bf16rn(a.x); r.y = bf16rn(a.y);
  r.z = bf16rn(a.z); r.w = bf16rn(a.w);
  return r;
}

__device__ inline bf16x8 pack_bf16_8(const float4 a, const float4 b) {
  union { __hip_bfloat162 h2[4]; bf16x8 v; } r;
  r.h2[0] = __float22bfloat162_rn(make_float2(a.x, a.y));
  r.h2[1] = __float22bfloat162_rn(make_float2(a.z, a.w));
  r.h2[2] = __float22bfloat162_rn(make_float2(b.x, b.y));
  r.h2[3] = __float22bfloat162_rn(make_float2(b.z, b.w));
  return r.v;
}

// ---------------------------------------------------------------------------
// Weight pre-convert: fp32 W -> bf16 k-panel layout P[(k>>3)*N + n][k&7].
// ---------------------------------------------------------------------------
__global__ __launch_bounds__(256) void wcvt_kernel(
    const float* __restrict__ W, unsigned short* __restrict__ P,
    int K, int Nn, int transposed)
{
  const int idx = blockIdx.x * 256 + threadIdx.x;
  const int k = idx / Nn;
  const int n = idx - k * Nn;
  const float v = transposed ? W[(size_t)n * K + k] : W[(size_t)k * Nn + n];
  P[(((size_t)(k >> 3)) * Nn + n) * 8 + (k & 7)] = bf16rn(v);
}

// ---------------------------------------------------------------------------
// xcvt: x fp32 [65536,771] -> xs bf16 [65536,1568] = [hi(784-pad) | lo(784)].
// ---------------------------------------------------------------------------
__global__ __launch_bounds__(256) void xcvt_kernel(
    const float* __restrict__ x, unsigned short* __restrict__ xs)
{
  const int t = blockIdx.x * 256 + threadIdx.x;  // 65536*98 total
  const int row = t / 98;
  const int c = t - row * 98;
  const int k0 = c << 3;
  unsigned short hi[8], lo[8];
#pragma unroll
  for (int j = 0; j < 8; ++j) {
    const int k = k0 + j;
    const float v = (k < 771) ? x[(size_t)row * 771 + k] : 0.f;
    const unsigned short h16 = bf16rn(v);
    const float hf = __uint_as_float(((unsigned int)h16) << 16);
    hi[j] = h16;
    lo[j] = bf16rn(v - hf);
  }
  unsigned short* base = xs + (size_t)row * 1568 + k0;
  *(uint4*)base = *(const uint4*)hi;
  *(uint4*)(base + 784) = *(const uint4*)lo;
}

// ---------------------------------------------------------------------------
// LDS-free bf16 MFMA GEMM: C[M,N] = A[M,K] @ Bp + bias (+relu).
// Block = 4 waves arranged 1x4: 64 rows x 256 cols. ABF16: A stored bf16;
// CBF16: C written bf16 (round AFTER bias/relu in fp32).
// ---------------------------------------------------------------------------
template <bool RELU, bool ABF16, bool CBF16>
__global__ __launch_bounds__(256, 3) void mgemm_kernel(
    const void* __restrict__ Av, const unsigned short* __restrict__ Bp,
    const float* __restrict__ bias, void* __restrict__ Cv,
    int M, int Nn, int K)
{
  const int tid = threadIdx.x;
  const int lane = tid & 63;
  const int w = tid >> 6;
  const int m_base = blockIdx.y * 64;
  const int n_base = blockIdx.x * 256 + w * 64;
  const int lr = lane & 15;
  const int lq = lane >> 4;
  f32x4 acc[4][4];
#pragma unroll
  for (int i = 0; i < 4; ++i)
#pragma unroll
    for (int j = 0; j < 4; ++j) acc[i][j] = (f32x4){0.f, 0.f, 0.f, 0.f};

  for (int k0 = 0; k0 < K; k0 += 32) {
    const int ka = k0 + (lq << 3);
    bf16x8 af[4], bfv[4];
#pragma unroll
    for (int mt = 0; mt < 4; ++mt) {
      if (ABF16) {
        const unsigned short* ap =
            (const unsigned short*)Av + (size_t)(m_base + mt * 16 + lr) * K + ka;
        union { uint4 u; bf16x8 b; } au;
        au.u = *(const uint4*)ap;
        af[mt] = au.b;
      } else {
        const float* ap = (const float*)Av + (size_t)(m_base + mt * 16 + lr) * K + ka;
        af[mt] = pack_bf16_8(*(const float4*)ap, *(const float4*)(ap + 4));
      }
    }
#pragma unroll
    for (int nt = 0; nt < 4; ++nt) {
      const size_t off =
          (((size_t)(ka >> 3)) * Nn + (n_base + nt * 16 + lr)) << 3;
      union { uint4 u; bf16x8 b; } bu;
      bu.u = *(const uint4*)(Bp + off);
      bfv[nt] = bu.b;
    }
#pragma unroll
    for (int mt = 0; mt < 4; ++mt)
#pragma unroll
      for (int nt = 0; nt < 4; ++nt)
        acc[mt][nt] = __builtin_amdgcn_mfma_f32_16x16x32_bf16(
            af[mt], bfv[nt], acc[mt][nt], 0, 0, 0);
  }
#pragma unroll
  for (int nt = 0; nt < 4; ++nt) {
    const int col = n_base + nt * 16 + lr;
    const float bv = bias[col];
#pragma unroll
    for (int mt = 0; mt < 4; ++mt) {
      const int row0 = m_base + mt * 16 + (lq << 2);
#pragma unroll
      for (int r = 0; r < 4; ++r) {
        float v = acc[mt][nt][r] + bv;
        if (RELU) v = fmaxf(v, 0.f);
        if (CBF16)
          ((unsigned short*)Cv)[(size_t)(row0 + r) * Nn + col] = bf16rn(v);
        else
          ((float*)Cv)[(size_t)(row0 + r) * Nn + col] = v;
      }
    }
  }
}

// ---------------------------------------------------------------------------
// eegemm: EE[slot,:] = relu(edge_attr[eid[slot]] @ ee_w + ee_b) @ elin_w
//         + elin_b (bf16 output), sorted slots (pass-local).
// ---------------------------------------------------------------------------
__global__ __launch_bounds__(256, 3) void eegemm_kernel(
    const float* __restrict__ edge_attr,
    const int* __restrict__ eid_sorted,
    const int* __restrict__ row_ptr, int node_base,
    const float* __restrict__ ee_w, const float* __restrict__ ee_b,
    const unsigned short* __restrict__ elin_p, const float* __restrict__ elin_b,
    unsigned short* __restrict__ EE)
{
  __shared__ float wenc[4][256];
  __shared__ float benc[256];
  const int tid = threadIdx.x;
  const int slot_base = row_ptr[node_base];
  const int slot_end = row_ptr[node_base + 16384];
  const int m_rel = blockIdx.y * 128;
  if (slot_base + m_rel >= slot_end) return;  // block-uniform exit

  ((float4*)wenc)[tid] = ((const float4*)ee_w)[tid];
  if (tid < 64) ((float4*)benc)[tid] = ((const float4*)ee_b)[tid];
  __syncthreads();

  const int lane = tid & 63;
  const int w = tid >> 6;
  const int m_base = m_rel + (w >> 1) * 64;
  const int n_base = blockIdx.x * 128 + (w & 1) * 64;
  const int lr = lane & 15;
  const int lq = lane >> 4;

  float4 ea_r[4];
#pragma unroll
  for (int mt = 0; mt < 4; ++mt) {
    const int abs_slot = slot_base + m_base + mt * 16 + lr;
    if (abs_slot < slot_end) {
      const int e = eid_sorted[abs_slot];
      ea_r[mt] = *(const float4*)(edge_attr + ((size_t)e << 2));
    } else {
      ea_r[mt] = make_float4(0.f, 0.f, 0.f, 0.f);
    }
  }

  f32x4 acc[4][4];
#pragma unroll
  for (int i = 0; i < 4; ++i)
#pragma unroll
    for (int j = 0; j < 4; ++j) acc[i][j] = (f32x4){0.f, 0.f, 0.f, 0.f};

  for (int k0 = 0; k0 < 256; k0 += 32) {
    const int ka = k0 + (lq << 3);
    const float4 b0 = *(const float4*)&benc[ka];
    const float4 b1 = *(const float4*)&benc[ka + 4];
    float4 w0[4], w1[4];
#pragma unroll
    for (int j = 0; j < 4; ++j) {
      w0[j] = *(const float4*)&wenc[j][ka];
      w1[j] = *(const float4*)&wenc[j][ka + 4];
    }
    bf16x8 af[4], bfv[4];
#pragma unroll
    for (int mt = 0; mt < 4; ++mt) {
      float4 v0 = b0, v1 = b1;
      FMA4(v0, ea_r[mt].x, w0[0]); FMA4(v1, ea_r[mt].x, w1[0]);
      FMA4(v0, ea_r[mt].y, w0[1]); FMA4(v1, ea_r[mt].y, w1[1]);
      FMA4(v0, ea_r[mt].z, w0[2]); FMA4(v1, ea_r[mt].z, w1[2]);
      FMA4(v0, ea_r[mt].w, w0[3]); FMA4(v1, ea_r[mt].w, w1[3]);
      v0.x = fmaxf(v0.x, 0.f); v0.y = fmaxf(v0.y, 0.f);
      v0.z = fmaxf(v0.z, 0.f); v0.w = fmaxf(v0.w, 0.f);
      v1.x = fmaxf(v1.x, 0.f); v1.y = fmaxf(v1.y, 0.f);
      v1.z = fmaxf(v1.z, 0.f); v1.w = fmaxf(v1.w, 0.f);
      af[mt] = pack_bf16_8(v0, v1);
    }
#pragma unroll
    for (int nt = 0; nt < 4; ++nt) {
      const size_t off =
          (((size_t)(ka >> 3)) * 256 + (n_base + nt * 16 + lr)) << 3;
      union { uint4 u; bf16x8 b; } bu;
      bu.u = *(const uint4*)(elin_p + off);
      bfv[nt] = bu.b;
    }
#pragma unroll
    for (int mt = 0; mt < 4; ++mt)
#pragma unroll
      for (int nt = 0; nt < 4; ++nt)
        acc[mt][nt] = __builtin_amdgcn_mfma_f32_16x16x32_bf16(
            af[mt], bfv[nt], acc[mt][nt], 0, 0, 0);
  }

#pragma unroll
  for (int nt = 0; nt < 4; ++nt) {
    const int col = n_base + nt * 16 + lr;
    const float bv = elin_b[col];
#pragma unroll
    for (int mt = 0; mt < 4; ++mt) {
      const int row0 = m_base + mt * 16 + (lq << 2);
#pragma unroll
      for (int r = 0; r < 4; ++r) {
        if (slot_base + row0 + r < slot_end)
          EE[(size_t)(row0 + r) * 256 + col] = bf16rn(acc[mt][nt][r] + bv);
      }
    }
  }
}

// ---------------------------------------------------------------------------
// gscat2: atomic-free CSR aggregate. One WAVE per dst node (4 nodes/block);
// lane owns 4 columns; walks the node's dst-sorted slot range accumulating
// relu(h[src] + EE[slot]) in fp32 registers. Output bf16 (consumer = GEMM).
// ---------------------------------------------------------------------------
__global__ __launch_bounds__(256, 8) void gscat2_kernel(
    const unsigned short* __restrict__ EE,
    const int* __restrict__ src_sorted,
    const int* __restrict__ row_ptr, int node_base,
    const float* __restrict__ h, const float* __restrict__ eps, int layer,
    unsigned short* __restrict__ g1b)
{
  const int tid = threadIdx.x;
  const int w = tid >> 6;
  const int lane = tid & 63;
  const int n = node_base + (blockIdx.x << 2) + w;
  const int cg = lane << 2;
  const int slot_base = row_ptr[node_base];
  const int row_start = row_ptr[n];
  const int row_end = row_ptr[n + 1];

  float4 acc0 = make_float4(0.f, 0.f, 0.f, 0.f);
  float4 acc1 = make_float4(0.f, 0.f, 0.f, 0.f);
  int slot = row_start;
  for (; slot + 2 <= row_end; slot += 2) {
    const int s0 = src_sorted[slot];
    const int s1 = src_sorted[slot + 1];
    const ushort4 eu0 = *(const ushort4*)(EE + (size_t)(slot - slot_base) * 256 + cg);
    const ushort4 eu1 = *(const ushort4*)(EE + (size_t)(slot + 1 - slot_base) * 256 + cg);
    const float4 h0 = *(const float4*)(h + (((size_t)s0) << 8) + cg);
    const float4 h1 = *(const float4*)(h + (((size_t)s1) << 8) + cg);
    acc0.x += fmaxf(h0.x + bf2f(eu0.x), 0.f);
    acc0.y += fmaxf(h0.y + bf2f(eu0.y), 0.f);
    acc0.z += fmaxf(h0.z + bf2f(eu0.z), 0.f);
    acc0.w += fmaxf(h0.w + bf2f(eu0.w), 0.f);
    acc1.x += fmaxf(h1.x + bf2f(eu1.x), 0.f);
    acc1.y += fmaxf(h1.y + bf2f(eu1.y), 0.f);
    acc1.z += fmaxf(h1.z + bf2f(eu1.z), 0.f);
    acc1.w += fmaxf(h1.w + bf2f(eu1.w), 0.f);
  }
  if (slot < row_end) {
    const int s0 = src_sorted[slot];
    const ushort4 eu0 = *(const ushort4*)(EE + (size_t)(slot - slot_base) * 256 + cg);
    const float4 h0 = *(const float4*)(h + (((size_t)s0) << 8) + cg);
    acc0.x += fmaxf(h0.x + bf2f(eu0.x), 0.f);
    acc0.y += fmaxf(h0.y + bf2f(eu0.y), 0.f);
    acc0.z += fmaxf(h0.z + bf2f(eu0.z), 0.f);
    acc0.w += fmaxf(h0.w + bf2f(eu0.w), 0.f);
  }
  acc0.x += acc1.x; acc0.y += acc1.y; acc0.z += acc1.z; acc0.w += acc1.w;

  const float f = 1.f + eps[layer];
  const float4 hv = *(const float4*)(h + (((size_t)n) << 8) + cg);
  float4 o;
  o.x = fmaf(f, hv.x, acc0.x);
  o.y = fmaf(f, hv.y, acc0.y);
  o.z = fmaf(f, hv.z, acc0.z);
  o.w = fmaf(f, hv.w, acc0.w);
  *(ushort4*)(g1b + (((size_t)n) << 8) + cg) = pack_bf16_4(o);
}

// ---------------------------------------------------------------------------
// fp32 tiled GEMM (kept for tiny classifier GEMMs).
// ---------------------------------------------------------------------------
template <bool BT, bool RELU>
__global__ __launch_bounds__(256, 4) void gemm_kernel(
    const float* __restrict__ A, const float* __restrict__ B,
    const float* __restrict__ bias, float* __restrict__ Cmat,
    int M, int Nn, int K)
{
  __shared__ float As[8][132];
  __shared__ float Bs[8][132];
  const int tid = threadIdx.x;
  const int bm = blockIdx.y * 128;
  const int bn = blockIdx.x * 128;
  const int tm = (tid >> 4) << 3;
  const int tn = (tid & 15) << 3;
  float acc[8][8];
#pragma unroll
  for (int i = 0; i < 8; ++i)
#pragma unroll
    for (int j = 0; j < 8; ++j) acc[i][j] = 0.f;

  const int nk = (K + 7) >> 3;
  const bool k4 = (K & 3) == 0;
  for (int kc = 0; kc < nk; ++kc) {
    const int k0 = kc << 3;
    {
      const int r = tid >> 1;
      const int kk = (tid & 1) << 2;
      const int gm = bm + r;
      float va[4] = {0.f, 0.f, 0.f, 0.f};
      if (gm < M) {
        const size_t base = (size_t)gm * K + k0 + kk;
        if (k4 && (k0 + kk + 4 <= K)) {
          const float4 v = *(const float4*)(A + base);
          va[0] = v.x; va[1] = v.y; va[2] = v.z; va[3] = v.w;
        } else {
#pragma unroll
          for (int j = 0; j < 4; ++j)
            if (k0 + kk + j < K) va[j] = A[base + j];
        }
      }
      As[kk + 0][r] = va[0]; As[kk + 1][r] = va[1];
      As[kk + 2][r] = va[2]; As[kk + 3][r] = va[3];
    }
    if (!BT) {
      const int r = tid >> 5;
      const int cb = (tid & 31) << 2;
      float4 v = make_float4(0.f, 0.f, 0.f, 0.f);
      if (k0 + r < K) v = *(const float4*)(B + (size_t)(k0 + r) * Nn + bn + cb);
      *(float4*)&Bs[r][cb] = v;
    } else {
      const int r = tid >> 1;
      const int kk = (tid & 1) << 2;
      float vb[4] = {0.f, 0.f, 0.f, 0.f};
      if (bn + r < Nn) {
        const size_t base = (size_t)(bn + r) * K + k0 + kk;
        if (k4 && (k0 + kk + 4 <= K)) {
          const float4 v = *(const float4*)(B + base);
          vb[0] = v.x; vb[1] = v.y; vb[2] = v.z; vb[3] = v.w;
        } else {
#pragma unroll
          for (int j = 0; j < 4; ++j)
            if (k0 + kk + j < K) vb[j] = B[base + j];
        }
      }
      Bs[kk + 0][r] = vb[0]; Bs[kk + 1][r] = vb[1];
      Bs[kk + 2][r] = vb[2]; Bs[kk + 3][r] = vb[3];
    }
    __syncthreads();
#pragma unroll
    for (int k = 0; k < 8; ++k) {
      const float4 a0 = *(const float4*)&As[k][tm];
      const float4 a1 = *(const float4*)&As[k][tm + 4];
      const float4 b0 = *(const float4*)&Bs[k][tn];
      const float4 b1 = *(const float4*)&Bs[k][tn + 4];
      const float av[8] = {a0.x, a0.y, a0.z, a0.w, a1.x, a1.y, a1.z, a1.w};
      const float bv[8] = {b0.x, b0.y, b0.z, b0.w, b1.x, b1.y, b1.z, b1.w};
#pragma unroll
      for (int i = 0; i < 8; ++i)
#pragma unroll
        for (int j = 0; j < 8; ++j)
          acc[i][j] = fmaf(av[i], bv[j], acc[i][j]);
    }
    __syncthreads();
  }
#pragma unroll
  for (int i = 0; i < 8; ++i) {
    const int gm = bm + tm + i;
    if (gm >= M) continue;
    float* crow = Cmat + (size_t)gm * Nn + bn + tn;
#pragma unroll
    for (int j = 0; j < 8; ++j) {
      const int gn = bn + tn + j;
      if (gn >= Nn) continue;
      float v = acc[i][j] + (bias ? bias[gn] : 0.f);
      if (RELU) v = fmaxf(v, 0.f);
      crow[j] = v;
    }
  }
}

// ---------------------------------------------------------------------------
// CSR build: histogram of dst -> exclusive scan -> scatter edge ids.
// ---------------------------------------------------------------------------
__global__ __launch_bounds__(256) void hist_kernel(
    const int* __restrict__ dst, int* __restrict__ deg)
{
  const int e = blockIdx.x * 256 + threadIdx.x;
  atomicAdd(&deg[dst[e]], 1);
}

__global__ __launch_bounds__(256) void scan_kernel(
    const int* __restrict__ deg, int* __restrict__ row_ptr,
    int* __restrict__ fill)
{
  __shared__ int part[256];
  const int t = threadIdx.x;
  const int base = t << 8;
  int s = 0;
  for (int j = 0; j < 256; ++j) s += deg[base + j];
  part[t] = s;
  __syncthreads();
  for (int off = 1; off < 256; off <<= 1) {
    int v = (t >= off) ? part[t - off] : 0;
    __syncthreads();
    part[t] += v;
    __syncthreads();
  }
  int run = (t == 0) ? 0 : part[t - 1];
  for (int j = 0; j < 256; ++j) {
    row_ptr[base + j] = run;
    fill[base + j] = run;
    run += deg[base + j];
  }
  if (t == 255) row_ptr[65536] = run;
}

__global__ __launch_bounds__(256) void scatter_kernel(
    const int* __restrict__ dst, const int* __restrict__ src,
    int* __restrict__ fill, int* __restrict__ eid, int* __restrict__ ssrc)
{
  const int e = blockIdx.x * 256 + threadIdx.x;
  const int pos = atomicAdd(&fill[dst[e]], 1);
  eid[pos] = e;
  ssrc[pos] = src[e];
}

// ---------------------------------------------------------------------------
// MFMA attention, one block per (graph, head), 4 waves x 64 q-rows.
// qkv is bf16: K/V staged by copy, Q frags loaded directly; the 1/8 scale
// is applied post-MFMA inside exp (exact: power of two). O written bf16.
// ---------------------------------------------------------------------------
__global__ __launch_bounds__(256, 1) void mattn_kernel(
    const unsigned short* __restrict__ qkv, unsigned short* __restrict__ o)
{
  __shared__ __attribute__((aligned(16))) unsigned short Ks[256 * 72];
  __shared__ __attribute__((aligned(16))) unsigned short Vt[64 * 258];
  __shared__ __attribute__((aligned(16))) unsigned short Ps[4][64 * 72];
  const int tid = threadIdx.x;
  const int gh = blockIdx.x;
  const int g = gh >> 2;
  const int hh = gh & 3;
  const int lane = tid & 63;
  const int w = tid >> 6;
  const int lr = lane & 15;
  const int lq = lane >> 4;

  // ---- stage K rows and V^T (bf16 copies) ----
  {
    const int key0 = tid >> 4;
    const int c0 = (tid & 15) << 2;
#pragma unroll
    for (int it = 0; it < 16; ++it) {
      const int key = it * 16 + key0;
      const unsigned short* base =
          qkv + ((size_t)(g * 256 + key)) * 768 + hh * 64 + c0;
      const ushort4 kv = *(const ushort4*)(base + 256);
      const ushort4 vv = *(const ushort4*)(base + 512);
      *(ushort4*)&Ks[key * 72 + c0] = kv;
      Vt[(c0 + 0) * 258 + key] = vv.x;
      Vt[(c0 + 1) * 258 + key] = vv.y;
      Vt[(c0 + 2) * 258 + key] = vv.z;
      Vt[(c0 + 3) * 258 + key] = vv.w;
    }
  }

  // ---- Q fragments straight from global bf16 ----
  const int m0 = w * 64;
  bf16x8 qf[2][4];
#pragma unroll
  for (int ks = 0; ks < 2; ++ks)
#pragma unroll
    for (int mt = 0; mt < 4; ++mt) {
      const unsigned short* ap = qkv +
          ((size_t)(g * 256 + m0 + mt * 16 + lr)) * 768 + hh * 64 +
          ks * 32 + (lq << 3);
      union { uint4 u; bf16x8 b; } au;
      au.u = *(const uint4*)ap;
      qf[ks][mt] = au.b;
    }
  __syncthreads();

  f32x4 oacc[4][4];
#pragma unroll
  for (int i = 0; i < 4; ++i)
#pragma unroll
    for (int j = 0; j < 4; ++j) oacc[i][j] = (f32x4){0.f, 0.f, 0.f, 0.f};
  float lpart[4][4];
#pragma unroll
  for (int i = 0; i < 4; ++i)
#pragma unroll
    for (int j = 0; j < 4; ++j) lpart[i][j] = 0.f;

  unsigned short* Pw = Ps[w];

  for (int kb = 0; kb < 4; ++kb) {
    // ---- S chunk = Q @ K^T (64 q x 64 keys) ----
    f32x4 sacc[4][4];
#pragma unroll
    for (int i = 0; i < 4; ++i)
#pragma unroll
      for (int j = 0; j < 4; ++j) sacc[i][j] = (f32x4){0.f, 0.f, 0.f, 0.f};
#pragma unroll
    for (int ks = 0; ks < 2; ++ks) {
      bf16x8 bfv[4];
#pragma unroll
      for (int nt = 0; nt < 4; ++nt) {
        union { uint4 u; bf16x8 b; } bu;
        bu.u = *(const uint4*)&Ks[(kb * 64 + nt * 16 + lr) * 72 +
                                  ks * 32 + (lq << 3)];
        bfv[nt] = bu.b;
      }
#pragma unroll
      for (int mt = 0; mt < 4; ++mt)
#pragma unroll
        for (int nt = 0; nt < 4; ++nt)
          sacc[mt][nt] = __builtin_amdgcn_mfma_f32_16x16x32_bf16(
              qf[ks][mt], bfv[nt], sacc[mt][nt], 0, 0, 0);
    }
    // ---- p = exp(s/8); accumulate row sums; write bf16 P chunk ----
#pragma unroll
    for (int mt = 0; mt < 4; ++mt)
#pragma unroll
      for (int nt = 0; nt < 4; ++nt) {
#pragma unroll
        for (int rr = 0; rr < 4; ++rr) {
          const float p = __expf(sacc[mt][nt][rr] * 0.125f);
          lpart[mt][rr] += p;
          Pw[(mt * 16 + (lq << 2) + rr) * 72 + nt * 16 + lr] = bf16rn(p);
        }
      }
    asm volatile("s_waitcnt lgkmcnt(0)" ::: "memory");
    __builtin_amdgcn_sched_barrier(0);
    // ---- O += P_chunk @ V_chunk ----
#pragma unroll
    for (int ks = 0; ks < 2; ++ks) {
      bf16x8 pa[4], vb[4];
#pragma unroll
      for (int mt = 0; mt < 4; ++mt) {
        union { uint4 u; bf16x8 b; } au;
        au.u = *(const uint4*)&Pw[(mt * 16 + lr) * 72 + ks * 32 + (lq << 3)];
        pa[mt] = au.b;
      }
#pragma unroll
      for (int nt = 0; nt < 4; ++nt) {
        const unsigned short* vp =
            &Vt[(nt * 16 + lr) * 258 + kb * 64 + ks * 32 + (lq << 3)];
        union { unsigned int u4[4]; bf16x8 b; } vu;
        vu.u4[0] = *(const unsigned int*)(vp + 0);
        vu.u4[1] = *(const unsigned int*)(vp + 2);
        vu.u4[2] = *(const unsigned int*)(vp + 4);
        vu.u4[3] = *(const unsigned int*)(vp + 6);
        vb[nt] = vu.b;
      }
#pragma unroll
      for (int mt = 0; mt < 4; ++mt)
#pragma unroll
        for (int nt = 0; nt < 4; ++nt)
          oacc[mt][nt] = __builtin_amdgcn_mfma_f32_16x16x32_bf16(
              pa[mt], vb[nt], oacc[mt][nt], 0, 0, 0);
    }
  }

  // ---- row sums -> 1/l (reduce across the 16 lr lanes) ----
#pragma unroll
  for (int mt = 0; mt < 4; ++mt)
#pragma unroll
    for (int rr = 0; rr < 4; ++rr) {
      float v = lpart[mt][rr];
      v += __shfl_xor(v, 1);
      v += __shfl_xor(v, 2);
      v += __shfl_xor(v, 4);
      v += __shfl_xor(v, 8);
      lpart[mt][rr] = 1.f / v;
    }

  // ---- normalize + store O (bf16) ----
#pragma unroll
  for (int mt = 0; mt < 4; ++mt) {
#pragma unroll
    for (int nt = 0; nt < 4; ++nt) {
#pragma unroll
      for (int rr = 0; rr < 4; ++rr) {
        const int row = m0 + mt * 16 + (lq << 2) + rr;
        o[((size_t)(g * 256 + row)) * 256 + hh * 64 + nt * 16 + lr] =
            bf16rn(oacc[mt][nt][rr] * lpart[mt][rr]);
      }
    }
  }
}

// ---------------------------------------------------------------------------
__global__ __launch_bounds__(256) void ln_kernel(
    const float* __restrict__ a, const float* __restrict__ res,
    const float* __restrict__ gam, const float* __restrict__ bet,
    float* __restrict__ out, int relu, unsigned short* __restrict__ outb)
{
  __shared__ float2 red[256];
  const int t = threadIdx.x;
  const size_t base = (size_t)blockIdx.x * 256;
  float v = a[base + t];
  if (res) v += res[base + t];
  red[t] = make_float2(v, v * v);
  __syncthreads();
#pragma unroll
  for (int s = 128; s > 0; s >>= 1) {
    if (t < s) { red[t].x += red[t + s].x; red[t].y += red[t + s].y; }
    __syncthreads();
  }
  const float mu = red[0].x * (1.f / 256.f);
  const float var = red[0].y * (1.f / 256.f) - mu * mu;
  float r = (v - mu) * rsqrtf(var + 1e-5f) * gam[t] + bet[t];
  if (relu) r = fmaxf(r, 0.f);
  out[base + t] = r;
  if (outb) outb[base + t] = bf16rn(r);
}

__global__ __launch_bounds__(256) void bn_stats_kernel(
    const float* __restrict__ y, float* __restrict__ stats)
{
  const int t = threadIdx.x;
  const size_t r0 = (size_t)blockIdx.x * 64;
  float s = 0.f, s2 = 0.f;
  for (int r = 0; r < 64; ++r) {
    const float v = y[(r0 + r) * 256 + t];
    s += v;
    s2 = fmaf(v, v, s2);
  }
  atomicAdd(&stats[t], s);
  atomicAdd(&stats[256 + t], s2);
}

// bn_apply: read fp32 y, write bf16 (consumer = gin2 GEMM).
__global__ __launch_bounds__(256) void bn_apply_kernel(
    const float* __restrict__ y, const float* __restrict__ stats,
    const float* __restrict__ gam, const float* __restrict__ bet,
    unsigned short* __restrict__ yb)
{
  const size_t i = ((size_t)blockIdx.x * 256 + threadIdx.x) << 2;
  const int c = (int)(i & 255);
  const float inv_n = 1.f / 65536.f;
  float4 v = *(const float4*)(y + i);
  const float4 s4 = *(const float4*)(stats + c);
  const float4 q4 = *(const float4*)(stats + 256 + c);
  const float4 g4 = *(const float4*)(gam + c);
  const float4 b4 = *(const float4*)(bet + c);
  float mu, var, sc;
  mu = s4.x * inv_n; var = q4.x * inv_n - mu * mu; sc = g4.x * rsqrtf(var + 1e-5f);
  v.x = fmaxf((v.x - mu) * sc + b4.x, 0.f);
  mu = s4.y * inv_n; var = q4.y * inv_n - mu * mu; sc = g4.y * rsqrtf(var + 1e-5f);
  v.y = fmaxf((v.y - mu) * sc + b4.y, 0.f);
  mu = s4.z * inv_n; var = q4.z * inv_n - mu * mu; sc = g4.z * rsqrtf(var + 1e-5f);
  v.z = fmaxf((v.z - mu) * sc + b4.z, 0.f);
  mu = s4.w * inv_n; var = q4.w * inv_n - mu * mu; sc = g4.w * rsqrtf(var + 1e-5f);
  v.w = fmaxf((v.w - mu) * sc + b4.w, 0.f);
  *(ushort4*)(yb + i) = pack_bf16_4(v);
}

// add: fp32 out (ln3 residual) + bf16 out (mlp1 A).
__global__ __launch_bounds__(256) void add_kernel(
    const float* __restrict__ a, const float* __restrict__ b,
    float* __restrict__ out, unsigned short* __restrict__ outb)
{
  const size_t i = ((size_t)blockIdx.x * 256 + threadIdx.x) << 2;
  const float4 va = *(const float4*)(a + i);
  const float4 vb = *(const float4*)(b + i);
  float4 v;
  v.x = va.x + vb.x; v.y = va.y + vb.y; v.z = va.z + vb.z; v.w = va.w + vb.w;
  *(float4*)(out + i) = v;
  *(ushort4*)(outb + i) = pack_bf16_4(v);
}

__global__ __launch_bounds__(256) void pool_kernel(
    const float* __restrict__ h, const int* __restrict__ batch,
    float* __restrict__ sums, float* __restrict__ cnt)
{
  const int t = threadIdx.x;
  const int n0 = blockIdx.x * 256;
  float acc = 0.f, runc = 0.f;
  int cur = batch[n0];
  for (int r = 0; r < 256; ++r) {
    const int n = n0 + r;
    const int b = batch[n];
    if (b != cur) {
      atomicAdd(&sums[(size_t)cur * 256 + t], acc);
      if (t == 0) atomicAdd(&cnt[cur], runc);
      acc = 0.f; runc = 0.f; cur = b;
    }
    acc += h[(size_t)n * 256 + t];
    runc += 1.f;
  }
  atomicAdd(&sums[(size_t)cur * 256 + t], acc);
  if (t == 0) atomicAdd(&cnt[cur], runc);
}

__global__ __launch_bounds__(256) void gemb_kernel(
    const float* __restrict__ sums, const float* __restrict__ cnt,
    float* __restrict__ gemb)
{
  const int i = blockIdx.x * 256 + threadIdx.x;
  const int g = i >> 8;
  gemb[i] = sums[i] / fmaxf(cnt[g], 1.f);
}

__global__ __launch_bounds__(256) void head_kernel(
    const float* __restrict__ z2, const float* __restrict__ w3,
    const float* __restrict__ b3, float* __restrict__ out)
{
  __shared__ float w[128];
  const int t = threadIdx.x;
  if (t < 128) w[t] = w3[t];
  __syncthreads();
  float s = 0.f;
  const float* row = z2 + (size_t)t * 128;
#pragma unroll 4
  for (int d = 0; d < 128; ++d) s = fmaf(row[d], w[d], s);
  out[t] = s + b3[0];
}

// ---------------------------------------------------------------------------
extern "C" void kernel_launch(void* const* d_in, const int* in_sizes, int n_in,
                              void* d_out, int out_size, void* d_ws, size_t ws_size,
                              hipStream_t stream)
{
  const float* x          = (const float*)d_in[0];
  const int*   edge_index = (const int*)d_in[1];
  const int*   batch      = (const int*)d_in[2];
  const float* edge_attr  = (const float*)d_in[3];
  const float* ne_w   = (const float*)d_in[4];
  const float* ne_b   = (const float*)d_in[5];
  const float* ne_ln_g = (const float*)d_in[6];
  const float* ne_ln_b = (const float*)d_in[7];
  const float* ee_w   = (const float*)d_in[8];
  const float* ee_b   = (const float*)d_in[9];
  const float* eps    = (const float*)d_in[10];
  const float* elin_w = (const float*)d_in[11];
  const float* gin_w1 = (const float*)d_in[12];
  const float* gin_w2 = (const float*)d_in[13];
  const float* attn_in_w  = (const float*)d_in[14];
  const float* attn_out_w = (const float*)d_in[15];
  const float* mlp_w1 = (const float*)d_in[16];
  const float* mlp_w2 = (const float*)d_in[17];
  const float* elin_b = (const float*)d_in[18];
  const float* gin_b1 = (const float*)d_in[19];
  const float* gin_b2 = (const float*)d_in[20];
  const float* attn_in_b  = (const float*)d_in[21];
  const float* attn_out_b = (const float*)d_in[22];
  const float* mlp_b1 = (const float*)d_in[23];
  const float* mlp_b2 = (const float*)d_in[24];
  const float* gin_bn_g = (const float*)d_in[25];
  const float* ln1_g  = (const float*)d_in[26];
  const float* ln2_g  = (const float*)d_in[27];
  const float* ln3_g  = (const float*)d_in[28];
  const float* gin_bn_b = (const float*)d_in[29];
  const float* ln1_b  = (const float*)d_in[30];
  const float* ln2_b  = (const float*)d_in[31];
  const float* ln3_b  = (const float*)d_in[32];
  const float* cls_w1 = (const float*)d_in[33];
  const float* cls_b1 = (const float*)d_in[34];
  const float* cls_ln_g = (const float*)d_in[35];
  const float* cls_ln_b = (const float*)d_in[36];
  const float* cls_w2 = (const float*)d_in[37];
  const float* cls_b2 = (const float*)d_in[38];
  const float* cls_w3 = (const float*)d_in[39];
  const float* cls_b3 = (const float*)d_in[40];

  const int* src = edge_index;
  const int* dst = edge_index + N_EDGES;

  float* ws = (float*)d_ws;
  const size_t NC = (size_t)N_NODES * CH;       // 16,777,216
  float* h    = ws;
  float* bufA = ws + NC;
  float* bufB = ws + 2 * NC;
  float* bufC = ws + 3 * NC;
  float* bufQ = ws + 4 * NC;                    // 192 MiB region (ends at stats)
  float* stats = bufQ + (size_t)N_NODES * 768;  // 4*512
  int* ideg  = (int*)(stats + 2048);            // 65536
  int* ifill = ideg + 65536;                    // 65536
  int* irow  = ifill + 65536;                   // 65537 (padded to 65544)
  int* ieid  = irow + 65544;                    // 524288
  int* issrc = ieid + 524288;                   // 524288 (src gathered in slot order)
  unsigned short* pan = (unsigned short*)(issrc + 524288);  // bf16 panels
  // bf16 activation aliases (all within bufQ's 192 MiB):
  unsigned short* abuf = (unsigned short*)bufA;        // bf16 scratch (seq. reuse)
  unsigned short* EEb  = (unsigned short*)bufQ;        // EE per pass (<=70 MiB)
  unsigned short* qkvb = (unsigned short*)bufQ;        // qkv bf16 (96 MiB)
  unsigned short* m1b  = (unsigned short*)bufQ;        // mlp1 out bf16 (64 MiB)
  // hb at byte offset 96 MiB into bufQ (= 24 Mi floats): [96,128) MiB,
  // disjoint from qkvb/EEb/m1b (all < 96 MiB) and from stats (at 192 MiB).
  // (Round-6 bug: 164 MiB offset overran bufQ and clobbered irow/ieid.)
  unsigned short* hb   = (unsigned short*)(bufQ + (size_t)24 * 1024 * 1024);
  // encoder split-bf16 x buffer: spans bufC + bufQ head (dead pre-loop)
  unsigned short* xs = (unsigned short*)bufC;   // [65536][1568] bf16 = 205 MB
  // post-loop scratch reuses bufA (dead after last layer):
  float* sums = bufA;
  float* cnt  = bufA + 65536;
  float* gemb = bufA + 65792;
  float* z1   = bufA + 131328;
  float* z2   = bufA + 196864;

  const dim3 blk(256);
  const size_t PL = 720896;        // panel elems per layer (incl elin_w)
  unsigned short* panNE = pan + 4 * PL;  // [1568/8 groups][256][8] = 401,408

  // ---- CSR build + weight bf16 panelization (once) ----
  hipMemsetAsync(stats, 0, 2048 * sizeof(float), stream);
  hipMemsetAsync(ideg, 0, 65536 * sizeof(int), stream);
  hipMemsetAsync(panNE, 0, 401408 * sizeof(unsigned short), stream);
  hist_kernel<<<dim3(2048), blk, 0, stream>>>(dst, ideg);
  scan_kernel<<<dim3(1), blk, 0, stream>>>(ideg, irow, ifill);
  scatter_kernel<<<dim3(2048), blk, 0, stream>>>(dst, src, ifill, ieid, issrc);
  for (int l = 0; l < 4; ++l) {
    unsigned short* p = pan + l * PL;
    wcvt_kernel<<<dim3(256), blk, 0, stream>>>(gin_w1 + (size_t)l * 65536, p, 256, 256, 0);
    wcvt_kernel<<<dim3(256), blk, 0, stream>>>(gin_w2 + (size_t)l * 65536, p + 65536, 256, 256, 0);
    wcvt_kernel<<<dim3(768), blk, 0, stream>>>(attn_in_w + (size_t)l * 196608, p + 131072, 256, 768, 1);
    wcvt_kernel<<<dim3(256), blk, 0, stream>>>(attn_out_w + (size_t)l * 65536, p + 327680, 256, 256, 1);
    wcvt_kernel<<<dim3(512), blk, 0, stream>>>(mlp_w1 + (size_t)l * 131072, p + 393216, 256, 512, 0);
    wcvt_kernel<<<dim3(512), blk, 0, stream>>>(mlp_w2 + (size_t)l * 131072, p + 524288, 512, 256, 0);
    wcvt_kernel<<<dim3(256), blk, 0, stream>>>(elin_w + (size_t)l * 65536, p + 655360, 256, 256, 0);
  }
  // ne_w panel twice (K rows 0..770 and 784..1554): hi and lo halves share W
  wcvt_kernel<<<dim3(771), blk, 0, stream>>>(ne_w, panNE, 771, 256, 0);
  wcvt_kernel<<<dim3(771), blk, 0, stream>>>(ne_w, panNE + (size_t)98 * 256 * 8, 771, 256, 0);

  // ---- encoder: split-bf16 x, then MFMA GEMM (K=1568 = hi|lo) ----
  xcvt_kernel<<<dim3(25088), blk, 0, stream>>>(x, xs);
  mgemm_kernel<false, true, false><<<dim3(1, 1024), blk, 0, stream>>>(
      xs, panNE, ne_b, bufB, N_NODES, 256, 1568);
  ln_kernel<<<dim3(N_NODES), blk, 0, stream>>>(bufB, nullptr, ne_ln_g, ne_ln_b, h, 1, hb);

  for (int l = 0; l < 4; ++l) {
    unsigned short* p = pan + l * PL;
    // ---- GINEConv: 4 node-range passes of (edge GEMM -> aggregate) ----
    for (int q = 0; q < 4; ++q) {
      eegemm_kernel<<<dim3(2, 1056), blk, 0, stream>>>(
          edge_attr, ieid, irow, q * 16384, ee_w, ee_b,
          p + 655360, elin_b + l * 256, EEb);
      gscat2_kernel<<<dim3(4096), blk, 0, stream>>>(
          EEb, issrc, irow, q * 16384, h, eps, l, abuf);
    }
    mgemm_kernel<false, true, false><<<dim3(1, 1024), blk, 0, stream>>>(
        abuf, p, gin_b1 + l * 256, bufB, N_NODES, 256, 256);
    bn_stats_kernel<<<dim3(1024), blk, 0, stream>>>(bufB, stats + l * 512);
    bn_apply_kernel<<<dim3(16384), blk, 0, stream>>>(
        bufB, stats + l * 512, gin_bn_g + l * 256, gin_bn_b + l * 256, abuf);
    mgemm_kernel<false, true, false><<<dim3(1, 1024), blk, 0, stream>>>(
        abuf, p + 65536, gin_b2 + l * 256, bufC, N_NODES, 256, 256);
    ln_kernel<<<dim3(N_NODES), blk, 0, stream>>>(
        bufC, h, ln1_g + l * 256, ln1_b + l * 256, bufC, 0, nullptr);
    // ---- attention ----
    mgemm_kernel<false, true, true><<<dim3(3, 1024), blk, 0, stream>>>(
        hb, p + 131072, attn_in_b + l * 768, qkvb, N_NODES, 768, 256);
    mattn_kernel<<<dim3(1024), blk, 0, stream>>>(qkvb, abuf);
    mgemm_kernel<false, true, false><<<dim3(1, 1024), blk, 0, stream>>>(
        abuf, p + 327680, attn_out_b + l * 256, bufB, N_NODES, 256, 256);
    ln_kernel<<<dim3(N_NODES), blk, 0, stream>>>(
        bufB, h, ln2_g + l * 256, ln2_b + l * 256, bufB, 0, nullptr);
    // ---- FFN ----
    add_kernel<<<dim3(16384), blk, 0, stream>>>(bufC, bufB, bufB, abuf);
    mgemm_kernel<true, true, true><<<dim3(2, 1024), blk, 0, stream>>>(
        abuf, p + 393216, mlp_b1 + l * 512, m1b, N_NODES, 512, 256);
    mgemm_kernel<false, true, false><<<dim3(1, 1024), blk, 0, stream>>>(
        m1b, p + 524288, mlp_b2 + l * 256, bufC, N_NODES, 256, 512);
    ln_kernel<<<dim3(N_NODES), blk, 0, stream>>>(
        bufC, bufB, ln3_g + l * 256, ln3_b + l * 256, h, 0, hb);
  }

  // ---- pooling + classifier ----
  hipMemsetAsync(sums, 0, 65792 * sizeof(float), stream);
  pool_kernel<<<dim3(256), blk, 0, stream>>>(h, batch, sums, cnt);
  gemb_kernel<<<dim3(256), blk, 0, stream>>>(sums, cnt, gemb);
  gemm_kernel<false, false><<<dim3(2, 2), blk, 0, stream>>>(
      gemb, cls_w1, cls_b1, z1, 256, 256, 256);
  ln_kernel<<<dim3(256), blk, 0, stream>>>(z1, nullptr, cls_ln_g, cls_ln_b, z1, 1, nullptr);
  gemm_kernel<false, true><<<dim3(1, 2), blk, 0, stream>>>(
      z1, cls_w2, cls_b2, z2, 256, 128, 256);
  head_kernel<<<dim3(1), blk, 0, stream>>>(z2, cls_w3, cls_b3, (float*)d_out);
}